// Round 15
// baseline (438.580 us; speedup 1.0000x reference)
//
#include <hip/hip_runtime.h>

#define MEM_N 262144
#define DIM 256
#define NBATCH 256
#define OCAP 4096
#define ROWCAP 2048
#define KSEL_SCORES 320
#define BPAGE 528  // u16 per LDS page (1056B): 8-bank skew between kq pages

typedef __attribute__((ext_vector_type(8))) short short8;
typedef __attribute__((ext_vector_type(4))) float f32x4;
typedef unsigned long long u64;
typedef unsigned short u16;

struct __attribute__((packed)) f4u { float x, y, z, w; };

__device__ __forceinline__ u16 bf16_rne(float f) {
  unsigned u = __builtin_bit_cast(unsigned, f);
  u += 0x7FFFu + ((u >> 16) & 1u);
  return (u16)(u >> 16);
}
__device__ __forceinline__ float bf16_f32(u16 h) {
  unsigned u = ((unsigned)h) << 16;
  return __builtin_bit_cast(float, u);
}
__device__ __forceinline__ u16 bf16_floor(float f) {
  unsigned u = __builtin_bit_cast(unsigned, f);
  u16 h = (u16)(u >> 16);
  if ((u & 0x80000000u) && (u & 0xFFFFu)) h++;
  return h;
}
__device__ __forceinline__ unsigned flip32(float f) {
  unsigned u = __builtin_bit_cast(unsigned, f);
  return u ^ ((unsigned)((int)u >> 31) | 0x80000000u);
}
__device__ __forceinline__ float unflip32(unsigned k) {
  unsigned u = (k & 0x80000000u) ? (k ^ 0x80000000u) : ~k;
  return __builtin_bit_cast(float, u);
}
__device__ __forceinline__ u16 flip16(u16 b) {
  return (b & 0x8000u) ? (u16)~b : (u16)(b | 0x8000u);
}
__device__ __forceinline__ u16 unflip16(u16 f) {
  return (f & 0x8000u) ? (u16)(f ^ 0x8000u) : (u16)~f;
}

// ---------------- query = normalize(x @ W^T + b), + packed-A emit ----------------
__global__ __launch_bounds__(256) void k_query(
    const float* __restrict__ x, const float* __restrict__ W,
    const float* __restrict__ b, float* __restrict__ q,
    u16* __restrict__ ap_hi, u16* __restrict__ ap_lo, int* __restrict__ row_cnt,
    int* __restrict__ ocnt) {
  __shared__ float Wt[256][36];
  __shared__ float xs[256];
  __shared__ float red[256];
  const int r = blockIdx.x, t = threadIdx.x;
  if (t == 0) row_cnt[r] = 0;
  if (r == 0 && t == 0) *ocnt = 0;
  xs[t] = x[r * DIM + t];
  float acc = b[t];
  for (int k0 = 0; k0 < DIM; k0 += 32) {
    __syncthreads();
#pragma unroll
    for (int i = 0; i < 8; i++) {
      int f = i * 256 + t;
      int j = f >> 3, c = (f & 7) * 4;
      *(float4*)&Wt[j][c] = *(const float4*)&W[j * DIM + k0 + c];
    }
    __syncthreads();
#pragma unroll
    for (int c = 0; c < 32; c++) acc = fmaf(xs[k0 + c], Wt[t][c], acc);
  }
  red[t] = acc * acc;
  __syncthreads();
  for (int s = 128; s > 0; s >>= 1) {
    if (t < s) red[t] += red[t + s];
    __syncthreads();
  }
  float nrm = fmaxf(sqrtf(red[0]), 1e-12f);
  float qv = acc / nrm;
  q[r * DIM + t] = qv;
  u16 h = bf16_rne(qv);
  u16 lo = bf16_rne(qv - bf16_f32(h));
  // packed MFMA A-fragment layout: [r16][kstep][lane][j]
  int r16 = r >> 4, s = t >> 5, hi = (t >> 3) & 3, j = t & 7;
  int l = hi * 16 + (r & 15);
  size_t off = ((size_t)(r16 * 8 + s) * 64 + l) * 8 + j;
  ap_hi[off] = h;
  ap_lo[off] = lo;
}

// --- k_gemm: MFMA -> rowmax ONLY (no score stores) + keys copy from registers.
//     N=128/block, 8 waves (4M x 2N), single skewed B buffer, 3 barriers. ---
__global__ __launch_bounds__(512, 4) void k_gemm(
    const u16* __restrict__ ap_hi, const u16* __restrict__ ap_lo,
    const float* __restrict__ keys, float* __restrict__ keys_out,
    u16* __restrict__ rowmax) {
  __shared__ u16 Bf[2 * 16 * BPAGE];  // 2 colblk x 16 kq-pages x 528 u16 = 33 KB
  const int t = threadIdx.x;
  const int cb = blockIdx.x;  // 128-col tile
  const int slot0 = cb * 128;
  const int w = t >> 6, l = t & 63;
  const int wm = w & 3, wn = w >> 2;
  const int lrow = l & 15, lq = l >> 4;
  const int srow = t >> 2, sk = t & 3;
  const float* kp = keys + (size_t)(slot0 + srow) * DIM + sk * 8;
  float* op = keys_out + ((size_t)(slot0 + srow) * DIM + sk * 8);
  const int sbase = (srow >> 6) * (16 * BPAGE);
  const int scol = srow & 63;

  f32x4 acc[4][4];
#pragma unroll
  for (int i = 0; i < 4; ++i)
#pragma unroll
    for (int j = 0; j < 4; ++j) acc[i][j] = f32x4{0.f, 0.f, 0.f, 0.f};

  // load + stage half 0 (k 0..127), then copy-out half 0
  {
    float4 va[4][2];
#pragma unroll
    for (int j = 0; j < 4; j++) {
      va[j][0] = *(const float4*)(kp + j * 32);
      va[j][1] = *(const float4*)(kp + j * 32 + 4);
    }
#pragma unroll
    for (int j = 0; j < 4; j++) {
      float f0[8] = {va[j][0].x, va[j][0].y, va[j][0].z, va[j][0].w,
                     va[j][1].x, va[j][1].y, va[j][1].z, va[j][1].w};
      uint4 pk;
      unsigned* pw = (unsigned*)&pk;
#pragma unroll
      for (int i = 0; i < 4; i++)
        pw[i] = (unsigned)bf16_rne(f0[2 * i]) | ((unsigned)bf16_rne(f0[2 * i + 1]) << 16);
      *(uint4*)&Bf[sbase + (j * 4 + sk) * BPAGE + scol * 8] = pk;
    }
#pragma unroll
    for (int j = 0; j < 4; j++) {
      *(f4u*)(op + j * 32) = f4u{va[j][0].x, va[j][0].y, va[j][0].z, va[j][0].w};
      *(f4u*)(op + j * 32 + 4) = f4u{va[j][1].x, va[j][1].y, va[j][1].z, va[j][1].w};
    }
  }
  __syncthreads();
  // MFMA half 0
#pragma unroll
  for (int ksl = 0; ksl < 4; ksl++) {
    short8 bh[4], ah[4], al[4];
#pragma unroll
    for (int nf = 0; nf < 4; nf++)
      bh[nf] = *(const short8*)(&Bf[wn * (16 * BPAGE) + (ksl * 4 + lq) * BPAGE + (nf * 16 + lrow) * 8]);
#pragma unroll
    for (int mf = 0; mf < 4; mf++) {
      size_t ab = ((size_t)((wm * 4 + mf) * 8 + ksl) * 64 + l) * 8;
      ah[mf] = *(const short8*)(ap_hi + ab);
      al[mf] = *(const short8*)(ap_lo + ab);
    }
#pragma unroll
    for (int mf = 0; mf < 4; mf++)
#pragma unroll
      for (int nf = 0; nf < 4; nf++) {
        acc[mf][nf] = __builtin_amdgcn_mfma_f32_16x16x32_bf16(al[mf], bh[nf], acc[mf][nf], 0, 0, 0);
        acc[mf][nf] = __builtin_amdgcn_mfma_f32_16x16x32_bf16(ah[mf], bh[nf], acc[mf][nf], 0, 0, 0);
      }
  }
  // load half 1 (k 128..255) + copy-out half 1
  float4 vb[4][2];
#pragma unroll
  for (int j = 0; j < 4; j++) {
    vb[j][0] = *(const float4*)(kp + 128 + j * 32);
    vb[j][1] = *(const float4*)(kp + 128 + j * 32 + 4);
  }
#pragma unroll
  for (int j = 0; j < 4; j++) {
    *(f4u*)(op + 128 + j * 32) = f4u{vb[j][0].x, vb[j][0].y, vb[j][0].z, vb[j][0].w};
    if (j == 3 && cb == 2047 && t == 511) {
      // last float (flat N-1) aliases rowmax[0..1]; patched in k_topk2
      op[128 + 3 * 32 + 4] = vb[3][1].x;
      op[128 + 3 * 32 + 5] = vb[3][1].y;
      op[128 + 3 * 32 + 6] = vb[3][1].z;
    } else {
      *(f4u*)(op + 128 + j * 32 + 4) = f4u{vb[j][1].x, vb[j][1].y, vb[j][1].z, vb[j][1].w};
    }
  }
  __syncthreads();  // all reads of half-0 done
  // stage half 1 into same buffer
#pragma unroll
  for (int j = 0; j < 4; j++) {
    float f0[8] = {vb[j][0].x, vb[j][0].y, vb[j][0].z, vb[j][0].w,
                   vb[j][1].x, vb[j][1].y, vb[j][1].z, vb[j][1].w};
    uint4 pk;
    unsigned* pw = (unsigned*)&pk;
#pragma unroll
    for (int i = 0; i < 4; i++)
      pw[i] = (unsigned)bf16_rne(f0[2 * i]) | ((unsigned)bf16_rne(f0[2 * i + 1]) << 16);
    *(uint4*)&Bf[sbase + (j * 4 + sk) * BPAGE + scol * 8] = pk;
  }
  __syncthreads();
  // MFMA half 1
#pragma unroll
  for (int ksl = 0; ksl < 4; ksl++) {
    short8 bh[4], ah[4], al[4];
#pragma unroll
    for (int nf = 0; nf < 4; nf++)
      bh[nf] = *(const short8*)(&Bf[wn * (16 * BPAGE) + (ksl * 4 + lq) * BPAGE + (nf * 16 + lrow) * 8]);
#pragma unroll
    for (int mf = 0; mf < 4; mf++) {
      size_t ab = ((size_t)((wm * 4 + mf) * 8 + 4 + ksl) * 64 + l) * 8;
      ah[mf] = *(const short8*)(ap_hi + ab);
      al[mf] = *(const short8*)(ap_lo + ab);
    }
#pragma unroll
    for (int mf = 0; mf < 4; mf++)
#pragma unroll
      for (int nf = 0; nf < 4; nf++) {
        acc[mf][nf] = __builtin_amdgcn_mfma_f32_16x16x32_bf16(al[mf], bh[nf], acc[mf][nf], 0, 0, 0);
        acc[mf][nf] = __builtin_amdgcn_mfma_f32_16x16x32_bf16(ah[mf], bh[nf], acc[mf][nf], 0, 0, 0);
      }
  }

  // rowmax over this wave's 64 columns, per row (16-lane group reduce)
#pragma unroll
  for (int mf = 0; mf < 4; mf++)
#pragma unroll
    for (int j = 0; j < 4; j++) {
      float m = fmaxf(fmaxf(acc[mf][0][j], acc[mf][1][j]),
                      fmaxf(acc[mf][2][j], acc[mf][3][j]));
#pragma unroll
      for (int mk = 1; mk <= 8; mk <<= 1) m = fmaxf(m, __shfl_xor(m, mk));
      if ((l & 15) == 0) {
        int row = wm * 64 + mf * 16 + lq * 4 + j;
        rowmax[(size_t)row * 4096 + cb * 2 + wn] = bf16_floor(m);
      }
    }
}

// ---- cutoff = exact ksel-th largest of 4096 bf16 group-maxima (per block-row) ----
__global__ __launch_bounds__(256) void k_cut(
    const u16* __restrict__ rowmax, float* __restrict__ cut_row, int ksel) {
  __shared__ int h[256];
  __shared__ int Bsh, Lsh;
  const int r = blockIdx.x, t = threadIdx.x;
  const u16* rm = rowmax + (size_t)r * 4096;
  uint4 a0 = *(const uint4*)(rm + t * 16);
  uint4 a1 = *(const uint4*)(rm + t * 16 + 8);
  u16 f[16];
  unsigned aw[8] = {a0.x, a0.y, a0.z, a0.w, a1.x, a1.y, a1.z, a1.w};
#pragma unroll
  for (int i = 0; i < 8; i++) {
    f[2 * i] = flip16((u16)(aw[i] & 0xFFFFu));
    f[2 * i + 1] = flip16((u16)(aw[i] >> 16));
  }
  h[t] = 0;
  __syncthreads();
#pragma unroll
  for (int i = 0; i < 16; i++) atomicAdd(&h[f[i] >> 8], 1);
  __syncthreads();
  for (int off = 1; off < 256; off <<= 1) {
    int v = (t + off < 256) ? h[t + off] : 0;
    __syncthreads();
    h[t] += v;
    __syncthreads();
  }
  if (h[t] >= ksel && (t == 255 || h[t + 1] < ksel)) Bsh = t;
  __syncthreads();
  const int B = Bsh;
  const int above = (B == 255) ? 0 : h[B + 1];
  __syncthreads();
  h[t] = 0;
  __syncthreads();
#pragma unroll
  for (int i = 0; i < 16; i++)
    if ((f[i] >> 8) == B) atomicAdd(&h[f[i] & 255], 1);
  __syncthreads();
  for (int off = 1; off < 256; off <<= 1) {
    int v = (t + off < 256) ? h[t + off] : 0;
    __syncthreads();
    h[t] += v;
    __syncthreads();
  }
  if (above + h[t] >= ksel && (t == 255 || above + h[t + 1] < ksel)) Lsh = t;
  __syncthreads();
  if (t == 0) {
    u16 fs = (u16)((B << 8) | Lsh);
    cut_row[r] = bf16_f32(unflip16(fs));
  }
}

// ---------------- sort helper ----------------
__device__ void bitonic_desc(u64* a, int N, int t) {
  for (int k = 2; k <= N; k <<= 1) {
    for (int j = k >> 1; j > 0; j >>= 1) {
      for (int i = t; i < N; i += 256) {
        int p = i ^ j;
        if (p > i) {
          u64 xv = a[i], yv = a[p];
          bool up = ((i & k) == 0);
          if (up ? (xv < yv) : (xv > yv)) { a[i] = yv; a[p] = xv; }
        }
      }
      __syncthreads();
    }
  }
}

// ---- rescore: recompute survivor blocks' scores (bitwise == gemm) + filter ----
// One block per 64-col keyblock. Surviving rows gathered from strided rowmax;
// B staged identically to gemm; A-fragments gathered per row; same MFMA chain
// (al then ah, ksl 0..7) => bitwise-identical f32 scores.
__global__ __launch_bounds__(256) void k_rescore(
    const u16* __restrict__ ap_hi, const u16* __restrict__ ap_lo,
    const float* __restrict__ keys, const float* __restrict__ cut_row,
    const u16* __restrict__ rowmax, u64* __restrict__ cand_row,
    int* __restrict__ row_cnt) {
  __shared__ u16 B0[16 * BPAGE];
  __shared__ u16 B1[16 * BPAGE];
  __shared__ int slist[256];
  __shared__ float cutv[256];
  __shared__ int nsurv;
  const int cb = blockIdx.x;  // 64-col block, 0..4095
  const int t = threadIdx.x;
  if (t == 0) nsurv = 0;
  cutv[t] = cut_row[t];
  __syncthreads();
  // survivor rows (row t): floored blockmax >= cut  <= necessary condition
  u16 rm = rowmax[(size_t)t * 4096 + cb];
  if (bf16_f32(rm) >= cutv[t]) {
    int p = atomicAdd(&nsurv, 1);
    slist[p] = t;
  }
  __syncthreads();
  const int ns = nsurv;
  if (ns == 0) return;

  // stage keys block cb (64 rows x 256 k) as bf16, both halves (gemm layout)
  const int srow = t >> 2, sk = t & 3;
  const float* kp = keys + ((size_t)(cb * 64 + srow)) * DIM + sk * 8;
#pragma unroll
  for (int half = 0; half < 2; half++) {
    u16* Bx = half ? B1 : B0;
#pragma unroll
    for (int j = 0; j < 4; j++) {
      float4 v0 = *(const float4*)(kp + half * 128 + j * 32);
      float4 v1 = *(const float4*)(kp + half * 128 + j * 32 + 4);
      float f0[8] = {v0.x, v0.y, v0.z, v0.w, v1.x, v1.y, v1.z, v1.w};
      uint4 pk;
      unsigned* pw = (unsigned*)&pk;
#pragma unroll
      for (int i = 0; i < 4; i++)
        pw[i] = (unsigned)bf16_rne(f0[2 * i]) | ((unsigned)bf16_rne(f0[2 * i + 1]) << 16);
      *(uint4*)&Bx[(j * 4 + sk) * BPAGE + srow * 8] = pk;
    }
  }
  __syncthreads();

  const int w = t >> 6;  // wave -> nf group (16 cols)
  const int l = t & 63;
  const int lrow = l & 15, lq = l >> 4;
  const int col = cb * 64 + w * 16 + lrow;
  const float* cutg = cut_row;

  for (int g = 0; g * 16 < ns; g++) {
    int slot = g * 16 + lrow;
    int ridx = slist[slot < ns ? slot : 0];
    f32x4 acc = f32x4{0.f, 0.f, 0.f, 0.f};
#pragma unroll
    for (int ksl = 0; ksl < 8; ksl++) {
      const u16* Bx = (ksl < 4) ? B0 : B1;
      short8 bh = *(const short8*)(&Bx[((ksl & 3) * 4 + lq) * BPAGE + (w * 16 + lrow) * 8]);
      size_t ab = (((size_t)(ridx >> 4) * 8 + ksl) * 64 + lq * 16 + (ridx & 15)) * 8;
      short8 ah = *(const short8*)(ap_hi + ab);
      short8 al = *(const short8*)(ap_lo + ab);
      acc = __builtin_amdgcn_mfma_f32_16x16x32_bf16(al, bh, acc, 0, 0, 0);
      acc = __builtin_amdgcn_mfma_f32_16x16x32_bf16(ah, bh, acc, 0, 0, 0);
    }
#pragma unroll
    for (int j = 0; j < 4; j++) {
      int oslot = g * 16 + lq * 4 + j;
      if (oslot < ns) {
        int R = slist[oslot];
        float sc = acc[j];
        if (sc >= cutg[R]) {
          u64 key = (((u64)flip32(sc)) << 32) | (unsigned)(~(unsigned)col);
          int pos = atomicAdd(&row_cnt[R], 1);
          if (pos < ROWCAP) cand_row[(size_t)R * ROWCAP + pos] = key;
        }
      }
    }
  }
}

// ---- top-k finalize: sort + softmax + loss + yhat + reset + correct-update ----
__global__ __launch_bounds__(256) void k_topk2(
    const u64* __restrict__ cand_row, const int* __restrict__ row_cnt,
    const int* __restrict__ values, const int* __restrict__ yv,
    const float* __restrict__ keys, const float* __restrict__ q,
    float* __restrict__ out, float* __restrict__ loss_arr,
    int* __restrict__ corr, float* __restrict__ age_out,
    float* __restrict__ keys_out) {
  __shared__ u64 buf[ROWCAP];
  __shared__ float red[256];
  const int r = blockIdx.x, t = threadIdx.x;
  if (r == 255 && t == 32) {
    const long long N = (long long)MEM_N * DIM;
    keys_out[N - 1] = keys[N - 1];  // safe: rescore's rowmax reads are done
  }
  int cnt = row_cnt[r];
  cnt = cnt < ROWCAP ? cnt : ROWCAP;
  int S = 256;
  while (S < cnt) S <<= 1;
  const u64* src = cand_row + (size_t)r * ROWCAP;
  for (int i = t; i < S; i += 256) buf[i] = (i < cnt) ? src[i] : 0ULL;
  __syncthreads();
  bitonic_desc(buf, S, t);

  u64 mykey = buf[t];
  int midx = (int)(~(unsigned)(mykey & 0xFFFFFFFFull));
  float msc = unflip32((unsigned)(mykey >> 32));
  int yr = yv[r];
  float mask = (values[midx] == yr) ? 1.0f : 0.0f;
  float mtop = unflip32((unsigned)(buf[0] >> 32));
  int i0 = (int)(~(unsigned)(buf[0] & 0xFFFFFFFFull));
  int vi0 = values[i0];
  bool correct = (vi0 == yr);

  float e = expf(msc - mtop);  // TEMP == 1.0
  red[t] = e; __syncthreads();
  for (int s = 128; s > 0; s >>= 1) { if (t < s) red[t] += red[t + s]; __syncthreads(); }
  float denom = red[0]; __syncthreads();
  out[256 + r * 256 + t] = e / denom;

  red[t] = msc * mask; __syncthreads();
  for (int s = 128; s > 0; s >>= 1) { if (t < s) red[t] = fmaxf(red[t], red[t + s]); __syncthreads(); }
  float posr = red[0]; __syncthreads();

  red[t] = msc * (1.0f - mask); __syncthreads();
  for (int s = 128; s > 0; s >>= 1) { if (t < s) red[t] = fmaxf(red[t], red[t + s]); __syncthreads(); }
  float negr = red[0]; __syncthreads();

  red[t] = mask; __syncthreads();
  for (int s = 128; s > 0; s >>= 1) { if (t < s) red[t] += red[t + s]; __syncthreads(); }
  float hp = (red[0] > 0.0f) ? 1.0f : 0.0f;
  __syncthreads();

  if (t == 0) {
    float pos = posr * hp;
    loss_arr[r] = fmaxf(negr - pos + 0.1f, 0.0f);
    out[r] = (float)vi0;
    corr[r] = correct ? 1 : 0;
  }
  if (correct) {
    if (t == 0) age_out[i0] = 0.0f;
    float v = keys[(size_t)i0 * DIM + t] + q[r * DIM + t];
    red[t] = v * v; __syncthreads();
    for (int s = 128; s > 0; s >>= 1) { if (t < s) red[t] += red[t + s]; __syncthreads(); }
    float nrm = fmaxf(sqrtf(red[0]), 1e-12f);
    keys_out[(size_t)i0 * DIM + t] = v / nrm;
  }
}

// ---------------- age/values init ----------------
__global__ __launch_bounds__(256) void k_age(
    const float* __restrict__ age, const int* __restrict__ values,
    float* __restrict__ age_out, float* __restrict__ vals_out) {
  int i = blockIdx.x * 256 + threadIdx.x;
  age_out[i] = age[i] + 1.0f;
  vals_out[i] = (float)values[i];
}

// ---- oldest path stage 1: 64-elt group maxima of age_noisy (bf16 floored) ----
__global__ __launch_bounds__(256) void k_oldmax(
    const float* __restrict__ age_out, const float* __restrict__ un,
    u16* __restrict__ old_max) {
  const int t = threadIdx.x, bid = blockIdx.x;
  int g = bid * 1024 + t * 4;
  float4 a = *(const float4*)(age_out + g);
  float4 n4 = *(const float4*)(un + g);
  float m = a.x + (2.0f * n4.x - 1.0f) * 8.0f;
  m = fmaxf(m, a.y + (2.0f * n4.y - 1.0f) * 8.0f);
  m = fmaxf(m, a.z + (2.0f * n4.z - 1.0f) * 8.0f);
  m = fmaxf(m, a.w + (2.0f * n4.w - 1.0f) * 8.0f);
#pragma unroll
  for (int mk = 1; mk <= 8; mk <<= 1) m = fmaxf(m, __shfl_xor(m, mk));
  if ((t & 15) == 0) old_max[bid * 16 + (t >> 4)] = bf16_floor(m);
}

// ---- oldest path stage 2: filtered sweep of age_noisy ----
__global__ __launch_bounds__(256) void k_oldsweep(
    const float* __restrict__ age_out, const float* __restrict__ un,
    const float* __restrict__ old_cut, u64* __restrict__ obuf,
    int* __restrict__ ocnt) {
  const int t = threadIdx.x, bid = blockIdx.x;
  int g = bid * 1024 + t * 4;
  const float cut = *old_cut;
  float4 a = *(const float4*)(age_out + g);
  float4 n4 = *(const float4*)(un + g);
  float av[4] = {a.x, a.y, a.z, a.w};
  float nv[4] = {n4.x, n4.y, n4.z, n4.w};
#pragma unroll
  for (int e = 0; e < 4; e++) {
    float v = av[e] + (2.0f * nv[e] - 1.0f) * 8.0f;
    if (v >= cut) {
      u64 k = (((u64)flip32(v)) << 32) | (unsigned)(~(unsigned)(g + e));
      int p = atomicAdd(ocnt, 1);
      if (p < OCAP) obuf[p] = k;
    }
  }
}

// ---- oldest path stage 3: sort survivors, dest assignment, loss mean ----
__global__ __launch_bounds__(256) void k_oldB(
    const u64* __restrict__ obuf, const int* __restrict__ ocnt,
    const int* __restrict__ corr, const float* __restrict__ loss_arr,
    int* __restrict__ dest, float* __restrict__ out_loss) {
  __shared__ u64 cand[OCAP];
  __shared__ int olds[256];
  __shared__ int pre[256];
  __shared__ float red[256];
  const int t = threadIdx.x;
  int n = *ocnt;
  n = n < OCAP ? n : OCAP;
  int S = 256;
  while (S < n) S <<= 1;
  for (int i = t; i < S; i += 256) cand[i] = (i < n) ? obuf[i] : 0ULL;
  __syncthreads();
  bitonic_desc(cand, S, t);
  olds[t] = (int)(~(unsigned)(cand[t] & 0xFFFFFFFFull));
  int inc = corr[t] ? 0 : 1;
  pre[t] = inc;
  __syncthreads();
  for (int off = 1; off < 256; off <<= 1) {
    int v = (t >= off) ? pre[t - off] : 0;
    __syncthreads();
    pre[t] += v;
    __syncthreads();
  }
  int rank = pre[t] - 1;
  dest[t] = inc ? olds[rank] : -1;
  red[t] = loss_arr[t]; __syncthreads();
  for (int s = 128; s > 0; s >>= 1) { if (t < s) red[t] += red[t + s]; __syncthreads(); }
  if (t == 0) *out_loss = red[0] * (1.0f / 256.0f);
}

// ---------------- incorrect-row scatter ----------------
__global__ __launch_bounds__(256) void k_incorrect(
    const int* __restrict__ dest, const float* __restrict__ q,
    const int* __restrict__ yv, float* __restrict__ keys_out,
    float* __restrict__ vals_out, float* __restrict__ age_out) {
  const int r = blockIdx.x;
  int d = dest[r];
  if (d < 0) return;
  const int t = threadIdx.x;
  keys_out[(size_t)d * DIM + t] = q[r * DIM + t];
  if (t == 0) {
    vals_out[d] = (float)yv[r];
    age_out[d] = 0.0f;
  }
}

extern "C" void kernel_launch(void* const* d_in, const int* in_sizes, int n_in,
                              void* d_out, int out_size, void* d_ws, size_t ws_size,
                              hipStream_t stream) {
  const float* x = (const float*)d_in[0];
  const int* y = (const int*)d_in[1];
  const float* W = (const float*)d_in[2];
  const float* b = (const float*)d_in[3];
  const float* keys = (const float*)d_in[4];
  const int* values = (const int*)d_in[5];
  const float* age = (const float*)d_in[6];
  const float* un = (const float*)d_in[7];
  float* out = (float*)d_out;

  char* ws = (char*)d_ws;
  float* q = (float*)ws;                             // 256 KB
  u16* ap_hi = (u16*)(ws + 262144);                  // 128 KB
  u16* ap_lo = (u16*)(ws + 393216);                  // 128 KB
  float* loss_arr = (float*)(ws + 524288);           // 1 KB
  int* corr = (int*)(ws + 525312);                   // 1 KB
  u64* obuf = (u64*)(ws + 527360);                   // 32 KB (OCAP u64)
  int* dest = (int*)(ws + 560128);                   // 1 KB
  int* row_cnt = (int*)(ws + 561152);                // 1 KB
  float* cut_row = (float*)(ws + 562176);            // 1 KB
  u16* old_max = (u16*)(ws + 563200);                // 8 KB (4096 u16)
  float* old_cut = (float*)(ws + 571392);            // 4 B
  int* ocnt = (int*)(ws + 571648);                   // 4 B
  u64* cand_row = (u64*)(ws + 1048576);              // 4 MB (256 x ROWCAP)

  // d_out layout (floats): yhat[256] | softmax[65536] | loss[1] | keys[67108864]
  //                        | values[262144] | age[262144]
  const size_t LOSS_OFF = 65792, KEYS_OFF = 65793, VALS_OFF = 67174657,
               AGE_OFF = 67436801;
  // rowmax scratch (bf16 u16, 2 MB) over last-key-float + values + age regions;
  // consumed by k_cut + k_rescore before k_age / k_topk2 rewrite those regions.
  u16* rowmax = (u16*)(out + 67174656);
  float* keys_out = out + KEYS_OFF;
  float* vals_out = out + VALS_OFF;
  float* age_out = out + AGE_OFF;

  k_query<<<dim3(256), dim3(256), 0, stream>>>(x, W, b, q, ap_hi, ap_lo, row_cnt, ocnt);
  k_gemm<<<dim3(2048), dim3(512), 0, stream>>>(ap_hi, ap_lo, keys, keys_out, rowmax);
  k_cut<<<dim3(256), dim3(256), 0, stream>>>(rowmax, cut_row, KSEL_SCORES);
  k_rescore<<<dim3(4096), dim3(256), 0, stream>>>(ap_hi, ap_lo, keys, cut_row, rowmax, cand_row, row_cnt);
  k_age<<<dim3(1024), dim3(256), 0, stream>>>(age, values, age_out, vals_out);
  k_topk2<<<dim3(256), dim3(256), 0, stream>>>(cand_row, row_cnt, values, y, keys, q,
                                               out, loss_arr, corr, age_out, keys_out);
  k_oldmax<<<dim3(256), dim3(256), 0, stream>>>(age_out, un, old_max);
  k_cut<<<dim3(1), dim3(256), 0, stream>>>(old_max, old_cut, 256);
  k_oldsweep<<<dim3(256), dim3(256), 0, stream>>>(age_out, un, old_cut, obuf, ocnt);
  k_oldB<<<dim3(1), dim3(256), 0, stream>>>(obuf, ocnt, corr, loss_arr, dest, out + LOSS_OFF);
  k_incorrect<<<dim3(256), dim3(256), 0, stream>>>(dest, q, y, keys_out, vals_out, age_out);
}

// Round 16
// 404.867 us; speedup vs baseline: 1.0833x; 1.0833x over previous
//
#include <hip/hip_runtime.h>

#define MEM_N 262144
#define DIM 256
#define NBATCH 256
#define OCAP 4096
#define NSEG 8
#define SEG_SZ 32768
#define ROWCAP 2048
#define KSEL_SCORES 320
#define BPAGE 528  // u16 per LDS page (1056B): 8-bank skew between kq pages

typedef __attribute__((ext_vector_type(8))) short short8;
typedef __attribute__((ext_vector_type(4))) float f32x4;
typedef unsigned long long u64;
typedef unsigned short u16;

__device__ __forceinline__ u16 bf16_rne(float f) {
  unsigned u = __builtin_bit_cast(unsigned, f);
  u += 0x7FFFu + ((u >> 16) & 1u);
  return (u16)(u >> 16);
}
__device__ __forceinline__ float bf16_f32(u16 h) {
  unsigned u = ((unsigned)h) << 16;
  return __builtin_bit_cast(float, u);
}
__device__ __forceinline__ u16 bf16_floor(float f) {
  unsigned u = __builtin_bit_cast(unsigned, f);
  u16 h = (u16)(u >> 16);
  if ((u & 0x80000000u) && (u & 0xFFFFu)) h++;
  return h;
}
__device__ __forceinline__ unsigned flip32(float f) {
  unsigned u = __builtin_bit_cast(unsigned, f);
  return u ^ ((unsigned)((int)u >> 31) | 0x80000000u);
}
__device__ __forceinline__ float unflip32(unsigned k) {
  unsigned u = (k & 0x80000000u) ? (k ^ 0x80000000u) : ~k;
  return __builtin_bit_cast(float, u);
}
__device__ __forceinline__ u16 flip16(u16 b) {
  return (b & 0x8000u) ? (u16)~b : (u16)(b | 0x8000u);
}
__device__ __forceinline__ u16 unflip16(u16 f) {
  return (f & 0x8000u) ? (u16)(f ^ 0x8000u) : (u16)~f;
}

// ---------------- query = normalize(x @ W^T + b), + packed-A emit ----------------
__global__ __launch_bounds__(256) void k_query(
    const float* __restrict__ x, const float* __restrict__ W,
    const float* __restrict__ b, float* __restrict__ q,
    u16* __restrict__ ap_hi, u16* __restrict__ ap_lo, int* __restrict__ row_cnt,
    int* __restrict__ ocnt) {
  __shared__ float Wt[256][36];
  __shared__ float xs[256];
  __shared__ float red[256];
  const int r = blockIdx.x, t = threadIdx.x;
  if (t == 0) row_cnt[r] = 0;
  if (r == 0 && t == 0) *ocnt = 0;
  xs[t] = x[r * DIM + t];
  float acc = b[t];
  for (int k0 = 0; k0 < DIM; k0 += 32) {
    __syncthreads();
#pragma unroll
    for (int i = 0; i < 8; i++) {
      int f = i * 256 + t;
      int j = f >> 3, c = (f & 7) * 4;
      *(float4*)&Wt[j][c] = *(const float4*)&W[j * DIM + k0 + c];
    }
    __syncthreads();
#pragma unroll
    for (int c = 0; c < 32; c++) acc = fmaf(xs[k0 + c], Wt[t][c], acc);
  }
  red[t] = acc * acc;
  __syncthreads();
  for (int s = 128; s > 0; s >>= 1) {
    if (t < s) red[t] += red[t + s];
    __syncthreads();
  }
  float nrm = fmaxf(sqrtf(red[0]), 1e-12f);
  float qv = acc / nrm;
  q[r * DIM + t] = qv;
  u16 h = bf16_rne(qv);
  u16 lo = bf16_rne(qv - bf16_f32(h));
  // packed MFMA A-fragment layout: [r16][kstep][lane][j]
  int r16 = r >> 4, s = t >> 5, hi = (t >> 3) & 3, j = t & 7;
  int l = hi * 16 + (r & 15);
  size_t off = ((size_t)(r16 * 8 + s) * 64 + l) * 8 + j;
  ap_hi[off] = h;
  ap_lo[off] = lo;
}

// --- scores = (q_hi+q_lo) @ bf16(keys)^T ; N=128/block, 8 waves (4M x 2N),
//     single skewed B buffer, LDS-transpose float4 epilogue (2 mf/round).
//     launch_bounds (512,4): cap 128 regs/lane = exactly 2 blocks/CU. ---
__global__ __launch_bounds__(512, 4) void k_gemm(
    const u16* __restrict__ ap_hi, const u16* __restrict__ ap_lo,
    const float* __restrict__ keys, float* __restrict__ scores,
    u16* __restrict__ rowmax) {
  // 67584 B shared: main loop uses first 33792 B as Bf; epilogue uses all of it
  __shared__ __align__(16) unsigned char smem[67584];
  u16* Bf = (u16*)smem;  // 2 colblk x 16 kq-pages x 528 u16 = 33792 B
  const int t = threadIdx.x;
  const int cb = blockIdx.x;  // 128-col tile
  const int slot0 = cb * 128;
  const int w = t >> 6, l = t & 63;
  const int wm = w & 3, wn = w >> 2;  // waves: 4 M-groups x 2 N-groups
  const int lrow = l & 15, lq = l >> 4;
  const int srow = t >> 2, sk = t & 3;
  const float* kp = keys + (size_t)(slot0 + srow) * DIM + sk * 8;
  const int sbase = (srow >> 6) * (16 * BPAGE);
  const int scol = srow & 63;

  f32x4 acc[4][4];
#pragma unroll
  for (int i = 0; i < 4; ++i)
#pragma unroll
    for (int j = 0; j < 4; ++j) acc[i][j] = f32x4{0.f, 0.f, 0.f, 0.f};

  // load + stage half 0 (k 0..127)
  {
    float4 va[4][2];
#pragma unroll
    for (int j = 0; j < 4; j++) {
      va[j][0] = *(const float4*)(kp + j * 32);
      va[j][1] = *(const float4*)(kp + j * 32 + 4);
    }
#pragma unroll
    for (int j = 0; j < 4; j++) {
      float f0[8] = {va[j][0].x, va[j][0].y, va[j][0].z, va[j][0].w,
                     va[j][1].x, va[j][1].y, va[j][1].z, va[j][1].w};
      uint4 pk;
      unsigned* pw = (unsigned*)&pk;
#pragma unroll
      for (int i = 0; i < 4; i++)
        pw[i] = (unsigned)bf16_rne(f0[2 * i]) | ((unsigned)bf16_rne(f0[2 * i + 1]) << 16);
      *(uint4*)&Bf[sbase + (j * 4 + sk) * BPAGE + scol * 8] = pk;
    }
  }
  __syncthreads();
  // MFMA half 0
#pragma unroll
  for (int ksl = 0; ksl < 4; ksl++) {
    short8 bh[4], ah[4], al[4];
#pragma unroll
    for (int nf = 0; nf < 4; nf++)
      bh[nf] = *(const short8*)(&Bf[wn * (16 * BPAGE) + (ksl * 4 + lq) * BPAGE + (nf * 16 + lrow) * 8]);
#pragma unroll
    for (int mf = 0; mf < 4; mf++) {
      size_t ab = ((size_t)((wm * 4 + mf) * 8 + ksl) * 64 + l) * 8;
      ah[mf] = *(const short8*)(ap_hi + ab);
      al[mf] = *(const short8*)(ap_lo + ab);
    }
#pragma unroll
    for (int mf = 0; mf < 4; mf++)
#pragma unroll
      for (int nf = 0; nf < 4; nf++) {
        acc[mf][nf] = __builtin_amdgcn_mfma_f32_16x16x32_bf16(al[mf], bh[nf], acc[mf][nf], 0, 0, 0);
        acc[mf][nf] = __builtin_amdgcn_mfma_f32_16x16x32_bf16(ah[mf], bh[nf], acc[mf][nf], 0, 0, 0);
      }
  }
  // load half 1 (k 128..255) after half-0 MFMA (keeps live VGPRs under the cap)
  float4 vb[4][2];
#pragma unroll
  for (int j = 0; j < 4; j++) {
    vb[j][0] = *(const float4*)(kp + 128 + j * 32);
    vb[j][1] = *(const float4*)(kp + 128 + j * 32 + 4);
  }
  __syncthreads();  // all reads of half-0 done
  // stage half 1 into same buffer
#pragma unroll
  for (int j = 0; j < 4; j++) {
    float f0[8] = {vb[j][0].x, vb[j][0].y, vb[j][0].z, vb[j][0].w,
                   vb[j][1].x, vb[j][1].y, vb[j][1].z, vb[j][1].w};
    uint4 pk;
    unsigned* pw = (unsigned*)&pk;
#pragma unroll
    for (int i = 0; i < 4; i++)
      pw[i] = (unsigned)bf16_rne(f0[2 * i]) | ((unsigned)bf16_rne(f0[2 * i + 1]) << 16);
    *(uint4*)&Bf[sbase + (j * 4 + sk) * BPAGE + scol * 8] = pk;
  }
  __syncthreads();
  // MFMA half 1
#pragma unroll
  for (int ksl = 0; ksl < 4; ksl++) {
    short8 bh[4], ah[4], al[4];
#pragma unroll
    for (int nf = 0; nf < 4; nf++)
      bh[nf] = *(const short8*)(&Bf[wn * (16 * BPAGE) + (ksl * 4 + lq) * BPAGE + (nf * 16 + lrow) * 8]);
#pragma unroll
    for (int mf = 0; mf < 4; mf++) {
      size_t ab = ((size_t)((wm * 4 + mf) * 8 + 4 + ksl) * 64 + l) * 8;
      ah[mf] = *(const short8*)(ap_hi + ab);
      al[mf] = *(const short8*)(ap_lo + ab);
    }
#pragma unroll
    for (int mf = 0; mf < 4; mf++)
#pragma unroll
      for (int nf = 0; nf < 4; nf++) {
        acc[mf][nf] = __builtin_amdgcn_mfma_f32_16x16x32_bf16(al[mf], bh[nf], acc[mf][nf], 0, 0, 0);
        acc[mf][nf] = __builtin_amdgcn_mfma_f32_16x16x32_bf16(ah[mf], bh[nf], acc[mf][nf], 0, 0, 0);
      }
  }

  // rowmax over this wave's 64 columns, per row (16-lane group reduce)
#pragma unroll
  for (int mf = 0; mf < 4; mf++)
#pragma unroll
    for (int j = 0; j < 4; j++) {
      float m = fmaxf(fmaxf(acc[mf][0][j], acc[mf][1][j]),
                      fmaxf(acc[mf][2][j], acc[mf][3][j]));
#pragma unroll
      for (int mk = 1; mk <= 8; mk <<= 1) m = fmaxf(m, __shfl_xor(m, mk));
      if ((l & 15) == 0) {
        int row = wm * 64 + mf * 16 + lq * 4 + j;
        rowmax[(size_t)row * 4096 + cb * 2 + wn] = bf16_floor(m);
      }
    }

  // epilogue: LDS transpose, 2 mf per round (4 barriers total).
  // scratch per (hh, wave): 16 x 66 floats; 2*8*1056 floats = 67584 B.
  float* trb = (float*)smem;
#pragma unroll
  for (int rd = 0; rd < 2; rd++) {
    __syncthreads();
#pragma unroll
    for (int hh = 0; hh < 2; hh++) {
      int mf = rd * 2 + hh;
      float* tr2 = trb + (hh * 8 + w) * 1056;
#pragma unroll
      for (int nf = 0; nf < 4; nf++)
#pragma unroll
        for (int j = 0; j < 4; j++)
          tr2[(lq * 4 + j) * 66 + nf * 16 + lrow] = acc[mf][nf][j];
    }
    __syncthreads();
#pragma unroll
    for (int hh = 0; hh < 2; hh++) {
      int mf = rd * 2 + hh;
      float* tr2 = trb + (hh * 8 + w) * 1056;
#pragma unroll
      for (int it = 0; it < 4; it++) {
        float4 vv = *(float4*)&tr2[(it * 4 + lq) * 66 + 4 * lrow];
        size_t row = (size_t)(wm * 64 + mf * 16 + it * 4 + lq);
        *(float4*)&scores[row * MEM_N + slot0 + wn * 64 + 4 * lrow] = vv;
      }
    }
  }
}

// ---- cutoff = exact ksel-th largest of 4096 bf16 group-maxima (per block-row) ----
__global__ __launch_bounds__(256) void k_cut(
    const u16* __restrict__ rowmax, float* __restrict__ cut_row, int ksel) {
  __shared__ int h[256];
  __shared__ int Bsh, Lsh;
  const int r = blockIdx.x, t = threadIdx.x;
  const u16* rm = rowmax + (size_t)r * 4096;
  uint4 a0 = *(const uint4*)(rm + t * 16);
  uint4 a1 = *(const uint4*)(rm + t * 16 + 8);
  u16 f[16];
  unsigned aw[8] = {a0.x, a0.y, a0.z, a0.w, a1.x, a1.y, a1.z, a1.w};
#pragma unroll
  for (int i = 0; i < 8; i++) {
    f[2 * i] = flip16((u16)(aw[i] & 0xFFFFu));
    f[2 * i + 1] = flip16((u16)(aw[i] >> 16));
  }
  h[t] = 0;
  __syncthreads();
#pragma unroll
  for (int i = 0; i < 16; i++) atomicAdd(&h[f[i] >> 8], 1);
  __syncthreads();
  for (int off = 1; off < 256; off <<= 1) {
    int v = (t + off < 256) ? h[t + off] : 0;
    __syncthreads();
    h[t] += v;
    __syncthreads();
  }
  if (h[t] >= ksel && (t == 255 || h[t + 1] < ksel)) Bsh = t;
  __syncthreads();
  const int B = Bsh;
  const int above = (B == 255) ? 0 : h[B + 1];
  __syncthreads();
  h[t] = 0;
  __syncthreads();
#pragma unroll
  for (int i = 0; i < 16; i++)
    if ((f[i] >> 8) == B) atomicAdd(&h[f[i] & 255], 1);
  __syncthreads();
  for (int off = 1; off < 256; off <<= 1) {
    int v = (t + off < 256) ? h[t + off] : 0;
    __syncthreads();
    h[t] += v;
    __syncthreads();
  }
  if (above + h[t] >= ksel && (t == 255 || above + h[t + 1] < ksel)) Lsh = t;
  __syncthreads();
  if (t == 0) {
    u16 fs = (u16)((B << 8) | Lsh);
    cut_row[r] = bf16_f32(unflip16(fs));
  }
}

// ---------------- sort helper ----------------
__device__ void bitonic_desc(u64* a, int N, int t) {
  for (int k = 2; k <= N; k <<= 1) {
    for (int j = k >> 1; j > 0; j >>= 1) {
      for (int i = t; i < N; i += 256) {
        int p = i ^ j;
        if (p > i) {
          u64 xv = a[i], yv = a[p];
          bool up = ((i & k) == 0);
          if (up ? (xv < yv) : (xv > yv)) { a[i] = yv; a[p] = xv; }
        }
      }
      __syncthreads();
    }
  }
}

// ---- sweep: rowmax-guided sparse filter + keys copy ----
// Only score blocks whose floored 64-max >= cutval can hold survivors
// (bf16_floor(m) < cut  =>  m < cut). Reads ~8% of scores.
__global__ __launch_bounds__(256) void k_sweep(
    const float* __restrict__ scores, const float* __restrict__ cut_row,
    const u16* __restrict__ rowmax, const float* __restrict__ keys,
    u64* __restrict__ cand_row, int* __restrict__ row_cnt,
    float* __restrict__ keys_out) {
  __shared__ u64 lbuf[2048];
  __shared__ u16 sblk[512];
  __shared__ int lcnt, nsb, gbase;
  const int seg = blockIdx.x, r = blockIdx.y, t = threadIdx.x;
  if (t == 0) { lcnt = 0; nsb = 0; }
  __syncthreads();
  const float cutval = cut_row[r];
  const float* p = scores + (size_t)r * MEM_N + (size_t)seg * SEG_SZ;

  // phase A1: find surviving 64-col blocks in this segment (512 candidates)
  const u16* rm = rowmax + (size_t)r * 4096 + seg * 512;
#pragma unroll
  for (int i2 = 0; i2 < 2; i2++) {
    int i = t * 2 + i2;
    if (bf16_f32(rm[i]) >= cutval) {
      int pz = atomicAdd(&nsb, 1);
      sblk[pz] = (u16)i;
    }
  }
  __syncthreads();
  const int ns = nsb;
  // phase A2: filter only surviving blocks (16 lanes x float4 per block)
  for (int i0 = 0; i0 < ns; i0 += 16) {
    int ib = i0 + (t >> 4);
    if (ib < ns) {
      int b = sblk[ib];
      int off = b * 64 + (t & 15) * 4;
      float4 v = *(const float4*)(p + off);
      float vv[4] = {v.x, v.y, v.z, v.w};
      int c0 = seg * SEG_SZ + off;
#pragma unroll
      for (int e = 0; e < 4; e++) {
        if (vv[e] >= cutval) {
          u64 key = (((u64)flip32(vv[e])) << 32) | (unsigned)(~(unsigned)(c0 + e));
          int pz = atomicAdd(&lcnt, 1);
          if (pz < 2048) lbuf[pz] = key;
        }
      }
    }
  }
  __syncthreads();
  int n = lcnt < 2048 ? lcnt : 2048;
  if (t == 0) gbase = atomicAdd(&row_cnt[r], n);
  __syncthreads();
  const int gb = gbase;
  u64* crow = cand_row + (size_t)r * ROWCAP;
  for (int i = t; i < n; i += 256) {
    int gp = gb + i;
    if (gp < ROWCAP) crow[gp] = lbuf[i];
  }

  // phase B: keys copy into the exact region this block's segment occupies.
  const long long b = (long long)r * MEM_N + (long long)seg * SEG_SZ - 1;
  for (int i = t; i < 8192; i += 256) {
    long long k4 = b + 4LL * i;
    if (k4 < 0) continue;  // only block (0,0) i=0
    float s = keys[k4];
    float4 v = *(const float4*)(keys + k4 + 1);
    float4 o;
    o.x = s; o.y = v.x; o.z = v.y; o.w = v.z;
    *(float4*)(keys_out + k4) = o;
  }
  if (r == 0 && seg == 0 && t == 0) {
    keys_out[0] = keys[0]; keys_out[1] = keys[1]; keys_out[2] = keys[2];
  }
  // NOTE: keys_out[N-1] aliases rowmax[0..1] (still being read) -> patched in k_topk2
}

// ---- top-k finalize: sort + softmax + loss + yhat + reset + correct-update ----
__global__ __launch_bounds__(256) void k_topk2(
    const u64* __restrict__ cand_row, const int* __restrict__ row_cnt,
    const int* __restrict__ values, const int* __restrict__ yv,
    const float* __restrict__ keys, const float* __restrict__ q,
    float* __restrict__ out, float* __restrict__ loss_arr,
    int* __restrict__ corr, float* __restrict__ age_out,
    float* __restrict__ keys_out) {
  __shared__ u64 buf[ROWCAP];
  __shared__ float red[256];
  const int r = blockIdx.x, t = threadIdx.x;
  if (r == 255 && t == 32) {
    const long long N = (long long)MEM_N * DIM;
    keys_out[N - 1] = keys[N - 1];  // safe: all k_sweep rowmax reads done
  }
  int cnt = row_cnt[r];
  cnt = cnt < ROWCAP ? cnt : ROWCAP;
  int S = 256;
  while (S < cnt) S <<= 1;
  const u64* src = cand_row + (size_t)r * ROWCAP;
  for (int i = t; i < S; i += 256) buf[i] = (i < cnt) ? src[i] : 0ULL;
  __syncthreads();
  bitonic_desc(buf, S, t);

  u64 mykey = buf[t];
  int midx = (int)(~(unsigned)(mykey & 0xFFFFFFFFull));
  float msc = unflip32((unsigned)(mykey >> 32));
  int yr = yv[r];
  float mask = (values[midx] == yr) ? 1.0f : 0.0f;
  float mtop = unflip32((unsigned)(buf[0] >> 32));
  int i0 = (int)(~(unsigned)(buf[0] & 0xFFFFFFFFull));
  int vi0 = values[i0];
  bool correct = (vi0 == yr);

  float e = expf(msc - mtop);  // TEMP == 1.0
  red[t] = e; __syncthreads();
  for (int s = 128; s > 0; s >>= 1) { if (t < s) red[t] += red[t + s]; __syncthreads(); }
  float denom = red[0]; __syncthreads();
  out[256 + r * 256 + t] = e / denom;

  red[t] = msc * mask; __syncthreads();
  for (int s = 128; s > 0; s >>= 1) { if (t < s) red[t] = fmaxf(red[t], red[t + s]); __syncthreads(); }
  float posr = red[0]; __syncthreads();

  red[t] = msc * (1.0f - mask); __syncthreads();
  for (int s = 128; s > 0; s >>= 1) { if (t < s) red[t] = fmaxf(red[t], red[t + s]); __syncthreads(); }
  float negr = red[0]; __syncthreads();

  red[t] = mask; __syncthreads();
  for (int s = 128; s > 0; s >>= 1) { if (t < s) red[t] += red[t + s]; __syncthreads(); }
  float hp = (red[0] > 0.0f) ? 1.0f : 0.0f;
  __syncthreads();

  if (t == 0) {
    float pos = posr * hp;
    loss_arr[r] = fmaxf(negr - pos + 0.1f, 0.0f);
    out[r] = (float)vi0;
    corr[r] = correct ? 1 : 0;
  }
  // merged reset + correct-row key update (block-uniform branch)
  if (correct) {
    if (t == 0) age_out[i0] = 0.0f;
    float v = keys[(size_t)i0 * DIM + t] + q[r * DIM + t];
    red[t] = v * v; __syncthreads();
    for (int s = 128; s > 0; s >>= 1) { if (t < s) red[t] += red[t + s]; __syncthreads(); }
    float nrm = fmaxf(sqrtf(red[0]), 1e-12f);
    keys_out[(size_t)i0 * DIM + t] = v / nrm;
  }
}

// ---------------- age/values init ----------------
__global__ __launch_bounds__(256) void k_age(
    const float* __restrict__ age, const int* __restrict__ values,
    float* __restrict__ age_out, float* __restrict__ vals_out) {
  int i = blockIdx.x * 256 + threadIdx.x;
  age_out[i] = age[i] + 1.0f;
  vals_out[i] = (float)values[i];
}

// ---- oldest path stage 1: 64-elt group maxima of age_noisy (bf16 floored) ----
__global__ __launch_bounds__(256) void k_oldmax(
    const float* __restrict__ age_out, const float* __restrict__ un,
    u16* __restrict__ old_max) {
  const int t = threadIdx.x, bid = blockIdx.x;
  int g = bid * 1024 + t * 4;
  float4 a = *(const float4*)(age_out + g);
  float4 n4 = *(const float4*)(un + g);
  float m = a.x + (2.0f * n4.x - 1.0f) * 8.0f;
  m = fmaxf(m, a.y + (2.0f * n4.y - 1.0f) * 8.0f);
  m = fmaxf(m, a.z + (2.0f * n4.z - 1.0f) * 8.0f);
  m = fmaxf(m, a.w + (2.0f * n4.w - 1.0f) * 8.0f);
#pragma unroll
  for (int mk = 1; mk <= 8; mk <<= 1) m = fmaxf(m, __shfl_xor(m, mk));
  if ((t & 15) == 0) old_max[bid * 16 + (t >> 4)] = bf16_floor(m);
}

// ---- oldest path stage 2: filtered sweep of age_noisy ----
__global__ __launch_bounds__(256) void k_oldsweep(
    const float* __restrict__ age_out, const float* __restrict__ un,
    const float* __restrict__ old_cut, u64* __restrict__ obuf,
    int* __restrict__ ocnt) {
  const int t = threadIdx.x, bid = blockIdx.x;
  int g = bid * 1024 + t * 4;
  const float cut = *old_cut;
  float4 a = *(const float4*)(age_out + g);
  float4 n4 = *(const float4*)(un + g);
  float av[4] = {a.x, a.y, a.z, a.w};
  float nv[4] = {n4.x, n4.y, n4.z, n4.w};
#pragma unroll
  for (int e = 0; e < 4; e++) {
    float v = av[e] + (2.0f * nv[e] - 1.0f) * 8.0f;
    if (v >= cut) {
      u64 k = (((u64)flip32(v)) << 32) | (unsigned)(~(unsigned)(g + e));
      int p = atomicAdd(ocnt, 1);
      if (p < OCAP) obuf[p] = k;
    }
  }
}

// ---- oldest path stage 3: sort survivors, dest assignment, loss mean ----
__global__ __launch_bounds__(256) void k_oldB(
    const u64* __restrict__ obuf, const int* __restrict__ ocnt,
    const int* __restrict__ corr, const float* __restrict__ loss_arr,
    int* __restrict__ dest, float* __restrict__ out_loss) {
  __shared__ u64 cand[OCAP];
  __shared__ int olds[256];
  __shared__ int pre[256];
  __shared__ float red[256];
  const int t = threadIdx.x;
  int n = *ocnt;
  n = n < OCAP ? n : OCAP;
  int S = 256;
  while (S < n) S <<= 1;
  for (int i = t; i < S; i += 256) cand[i] = (i < n) ? obuf[i] : 0ULL;
  __syncthreads();
  bitonic_desc(cand, S, t);
  olds[t] = (int)(~(unsigned)(cand[t] & 0xFFFFFFFFull));
  int inc = corr[t] ? 0 : 1;
  pre[t] = inc;
  __syncthreads();
  for (int off = 1; off < 256; off <<= 1) {
    int v = (t >= off) ? pre[t - off] : 0;
    __syncthreads();
    pre[t] += v;
    __syncthreads();
  }
  int rank = pre[t] - 1;
  dest[t] = inc ? olds[rank] : -1;
  red[t] = loss_arr[t]; __syncthreads();
  for (int s = 128; s > 0; s >>= 1) { if (t < s) red[t] += red[t + s]; __syncthreads(); }
  if (t == 0) *out_loss = red[0] * (1.0f / 256.0f);
}

// ---------------- incorrect-row scatter ----------------
__global__ __launch_bounds__(256) void k_incorrect(
    const int* __restrict__ dest, const float* __restrict__ q,
    const int* __restrict__ yv, float* __restrict__ keys_out,
    float* __restrict__ vals_out, float* __restrict__ age_out) {
  const int r = blockIdx.x;
  int d = dest[r];
  if (d < 0) return;
  const int t = threadIdx.x;
  keys_out[(size_t)d * DIM + t] = q[r * DIM + t];
  if (t == 0) {
    vals_out[d] = (float)yv[r];
    age_out[d] = 0.0f;
  }
}

extern "C" void kernel_launch(void* const* d_in, const int* in_sizes, int n_in,
                              void* d_out, int out_size, void* d_ws, size_t ws_size,
                              hipStream_t stream) {
  const float* x = (const float*)d_in[0];
  const int* y = (const int*)d_in[1];
  const float* W = (const float*)d_in[2];
  const float* b = (const float*)d_in[3];
  const float* keys = (const float*)d_in[4];
  const int* values = (const int*)d_in[5];
  const float* age = (const float*)d_in[6];
  const float* un = (const float*)d_in[7];
  float* out = (float*)d_out;

  char* ws = (char*)d_ws;
  float* q = (float*)ws;                             // 256 KB
  u16* ap_hi = (u16*)(ws + 262144);                  // 128 KB
  u16* ap_lo = (u16*)(ws + 393216);                  // 128 KB
  float* loss_arr = (float*)(ws + 524288);           // 1 KB
  int* corr = (int*)(ws + 525312);                   // 1 KB
  u64* obuf = (u64*)(ws + 527360);                   // 32 KB (OCAP u64)
  int* dest = (int*)(ws + 560128);                   // 1 KB
  int* row_cnt = (int*)(ws + 561152);                // 1 KB
  float* cut_row = (float*)(ws + 562176);            // 1 KB
  u16* old_max = (u16*)(ws + 563200);                // 8 KB (4096 u16)
  float* old_cut = (float*)(ws + 571392);            // 4 B
  int* ocnt = (int*)(ws + 571648);                   // 4 B
  u64* cand_row = (u64*)(ws + 1048576);              // 4 MB (256 x ROWCAP)

  // d_out layout (floats): yhat[256] | softmax[65536] | loss[1] | keys[67108864]
  //                        | values[262144] | age[262144]
  const size_t LOSS_OFF = 65792, KEYS_OFF = 65793, VALS_OFF = 67174657,
               AGE_OFF = 67436801;
  float* scores = out + 65792;          // 256 MB scratch over loss+keys region
  u16* rowmax = (u16*)(out + 67174656); // 2 MB scratch over last-key+values+age
  float* keys_out = out + KEYS_OFF;
  float* vals_out = out + VALS_OFF;
  float* age_out = out + AGE_OFF;

  k_query<<<dim3(256), dim3(256), 0, stream>>>(x, W, b, q, ap_hi, ap_lo, row_cnt, ocnt);
  k_gemm<<<dim3(2048), dim3(512), 0, stream>>>(ap_hi, ap_lo, keys, scores, rowmax);
  k_cut<<<dim3(256), dim3(256), 0, stream>>>(rowmax, cut_row, KSEL_SCORES);
  k_sweep<<<dim3(NSEG, 256), dim3(256), 0, stream>>>(scores, cut_row, rowmax, keys, cand_row, row_cnt, keys_out);
  k_age<<<dim3(1024), dim3(256), 0, stream>>>(age, values, age_out, vals_out);
  k_topk2<<<dim3(256), dim3(256), 0, stream>>>(cand_row, row_cnt, values, y, keys, q,
                                               out, loss_arr, corr, age_out, keys_out);
  k_oldmax<<<dim3(256), dim3(256), 0, stream>>>(age_out, un, old_max);
  k_cut<<<dim3(1), dim3(256), 0, stream>>>(old_max, old_cut, 256);
  k_oldsweep<<<dim3(256), dim3(256), 0, stream>>>(age_out, un, old_cut, obuf, ocnt);
  k_oldB<<<dim3(1), dim3(256), 0, stream>>>(obuf, ocnt, corr, loss_arr, dest, out + LOSS_OFF);
  k_incorrect<<<dim3(256), dim3(256), 0, stream>>>(dest, q, y, keys_out, vals_out, age_out);
}

// Round 17
// 395.962 us; speedup vs baseline: 1.1076x; 1.0225x over previous
//
#include <hip/hip_runtime.h>

#define MEM_N 262144
#define DIM 256
#define NBATCH 256
#define OCAP 4096
#define NSEG 8
#define SEG_SZ 32768
#define ROWCAP 2048
#define KSEL_SCORES 320
#define BPAGE 528  // u16 per LDS page (1056B): 8-bank skew between kq pages

typedef __attribute__((ext_vector_type(8))) short short8;
typedef __attribute__((ext_vector_type(4))) float f32x4;
typedef unsigned long long u64;
typedef unsigned short u16;

struct __attribute__((packed)) f4u { float x, y, z, w; };

__device__ __forceinline__ u16 bf16_rne(float f) {
  unsigned u = __builtin_bit_cast(unsigned, f);
  u += 0x7FFFu + ((u >> 16) & 1u);
  return (u16)(u >> 16);
}
__device__ __forceinline__ float bf16_f32(u16 h) {
  unsigned u = ((unsigned)h) << 16;
  return __builtin_bit_cast(float, u);
}
__device__ __forceinline__ u16 bf16_floor(float f) {
  unsigned u = __builtin_bit_cast(unsigned, f);
  u16 h = (u16)(u >> 16);
  if ((u & 0x80000000u) && (u & 0xFFFFu)) h++;
  return h;
}
__device__ __forceinline__ unsigned flip32(float f) {
  unsigned u = __builtin_bit_cast(unsigned, f);
  return u ^ ((unsigned)((int)u >> 31) | 0x80000000u);
}
__device__ __forceinline__ float unflip32(unsigned k) {
  unsigned u = (k & 0x80000000u) ? (k ^ 0x80000000u) : ~k;
  return __builtin_bit_cast(float, u);
}
__device__ __forceinline__ u16 flip16(u16 b) {
  return (b & 0x8000u) ? (u16)~b : (u16)(b | 0x8000u);
}
__device__ __forceinline__ u16 unflip16(u16 f) {
  return (f & 0x8000u) ? (u16)(f ^ 0x8000u) : (u16)~f;
}

// ---------------- query = normalize(x @ W^T + b), + packed-A emit ----------------
__global__ __launch_bounds__(256) void k_query(
    const float* __restrict__ x, const float* __restrict__ W,
    const float* __restrict__ b, float* __restrict__ q,
    u16* __restrict__ ap_hi, u16* __restrict__ ap_lo, int* __restrict__ row_cnt,
    int* __restrict__ ocnt) {
  __shared__ float Wt[256][36];
  __shared__ float xs[256];
  __shared__ float red[256];
  const int r = blockIdx.x, t = threadIdx.x;
  if (t == 0) row_cnt[r] = 0;
  if (r == 0 && t == 0) *ocnt = 0;
  xs[t] = x[r * DIM + t];
  float acc = b[t];
  for (int k0 = 0; k0 < DIM; k0 += 32) {
    __syncthreads();
#pragma unroll
    for (int i = 0; i < 8; i++) {
      int f = i * 256 + t;
      int j = f >> 3, c = (f & 7) * 4;
      *(float4*)&Wt[j][c] = *(const float4*)&W[j * DIM + k0 + c];
    }
    __syncthreads();
#pragma unroll
    for (int c = 0; c < 32; c++) acc = fmaf(xs[k0 + c], Wt[t][c], acc);
  }
  red[t] = acc * acc;
  __syncthreads();
  for (int s = 128; s > 0; s >>= 1) {
    if (t < s) red[t] += red[t + s];
    __syncthreads();
  }
  float nrm = fmaxf(sqrtf(red[0]), 1e-12f);
  float qv = acc / nrm;
  q[r * DIM + t] = qv;
  u16 h = bf16_rne(qv);
  u16 lo = bf16_rne(qv - bf16_f32(h));
  // packed MFMA A-fragment layout: [r16][kstep][lane][j]
  int r16 = r >> 4, s = t >> 5, hi = (t >> 3) & 3, j = t & 7;
  int l = hi * 16 + (r & 15);
  size_t off = ((size_t)(r16 * 8 + s) * 64 + l) * 8 + j;
  ap_hi[off] = h;
  ap_lo[off] = lo;
}

// ===== GEMM core macro-free shared body implemented twice (plain / fused copy) =====

// --- variant A (SMALL ws): scores to out-region scratch; keys copy left to sweep ---
__global__ __launch_bounds__(512, 4) void k_gemm(
    const u16* __restrict__ ap_hi, const u16* __restrict__ ap_lo,
    const float* __restrict__ keys, float* __restrict__ scores,
    u16* __restrict__ rowmax) {
  __shared__ __align__(16) unsigned char smem[67584];
  u16* Bf = (u16*)smem;
  const int t = threadIdx.x;
  const int cb = blockIdx.x;
  const int slot0 = cb * 128;
  const int w = t >> 6, l = t & 63;
  const int wm = w & 3, wn = w >> 2;
  const int lrow = l & 15, lq = l >> 4;
  const int srow = t >> 2, sk = t & 3;
  const float* kp = keys + (size_t)(slot0 + srow) * DIM + sk * 8;
  const int sbase = (srow >> 6) * (16 * BPAGE);
  const int scol = srow & 63;

  f32x4 acc[4][4];
#pragma unroll
  for (int i = 0; i < 4; ++i)
#pragma unroll
    for (int j = 0; j < 4; ++j) acc[i][j] = f32x4{0.f, 0.f, 0.f, 0.f};

  {
    float4 va[4][2];
#pragma unroll
    for (int j = 0; j < 4; j++) {
      va[j][0] = *(const float4*)(kp + j * 32);
      va[j][1] = *(const float4*)(kp + j * 32 + 4);
    }
#pragma unroll
    for (int j = 0; j < 4; j++) {
      float f0[8] = {va[j][0].x, va[j][0].y, va[j][0].z, va[j][0].w,
                     va[j][1].x, va[j][1].y, va[j][1].z, va[j][1].w};
      uint4 pk;
      unsigned* pw = (unsigned*)&pk;
#pragma unroll
      for (int i = 0; i < 4; i++)
        pw[i] = (unsigned)bf16_rne(f0[2 * i]) | ((unsigned)bf16_rne(f0[2 * i + 1]) << 16);
      *(uint4*)&Bf[sbase + (j * 4 + sk) * BPAGE + scol * 8] = pk;
    }
  }
  __syncthreads();
#pragma unroll
  for (int ksl = 0; ksl < 4; ksl++) {
    short8 bh[4], ah[4], al[4];
#pragma unroll
    for (int nf = 0; nf < 4; nf++)
      bh[nf] = *(const short8*)(&Bf[wn * (16 * BPAGE) + (ksl * 4 + lq) * BPAGE + (nf * 16 + lrow) * 8]);
#pragma unroll
    for (int mf = 0; mf < 4; mf++) {
      size_t ab = ((size_t)((wm * 4 + mf) * 8 + ksl) * 64 + l) * 8;
      ah[mf] = *(const short8*)(ap_hi + ab);
      al[mf] = *(const short8*)(ap_lo + ab);
    }
#pragma unroll
    for (int mf = 0; mf < 4; mf++)
#pragma unroll
      for (int nf = 0; nf < 4; nf++) {
        acc[mf][nf] = __builtin_amdgcn_mfma_f32_16x16x32_bf16(al[mf], bh[nf], acc[mf][nf], 0, 0, 0);
        acc[mf][nf] = __builtin_amdgcn_mfma_f32_16x16x32_bf16(ah[mf], bh[nf], acc[mf][nf], 0, 0, 0);
      }
  }
  float4 vb[4][2];
#pragma unroll
  for (int j = 0; j < 4; j++) {
    vb[j][0] = *(const float4*)(kp + 128 + j * 32);
    vb[j][1] = *(const float4*)(kp + 128 + j * 32 + 4);
  }
  __syncthreads();
#pragma unroll
  for (int j = 0; j < 4; j++) {
    float f0[8] = {vb[j][0].x, vb[j][0].y, vb[j][0].z, vb[j][0].w,
                   vb[j][1].x, vb[j][1].y, vb[j][1].z, vb[j][1].w};
    uint4 pk;
    unsigned* pw = (unsigned*)&pk;
#pragma unroll
    for (int i = 0; i < 4; i++)
      pw[i] = (unsigned)bf16_rne(f0[2 * i]) | ((unsigned)bf16_rne(f0[2 * i + 1]) << 16);
    *(uint4*)&Bf[sbase + (j * 4 + sk) * BPAGE + scol * 8] = pk;
  }
  __syncthreads();
#pragma unroll
  for (int ksl = 0; ksl < 4; ksl++) {
    short8 bh[4], ah[4], al[4];
#pragma unroll
    for (int nf = 0; nf < 4; nf++)
      bh[nf] = *(const short8*)(&Bf[wn * (16 * BPAGE) + (ksl * 4 + lq) * BPAGE + (nf * 16 + lrow) * 8]);
#pragma unroll
    for (int mf = 0; mf < 4; mf++) {
      size_t ab = ((size_t)((wm * 4 + mf) * 8 + 4 + ksl) * 64 + l) * 8;
      ah[mf] = *(const short8*)(ap_hi + ab);
      al[mf] = *(const short8*)(ap_lo + ab);
    }
#pragma unroll
    for (int mf = 0; mf < 4; mf++)
#pragma unroll
      for (int nf = 0; nf < 4; nf++) {
        acc[mf][nf] = __builtin_amdgcn_mfma_f32_16x16x32_bf16(al[mf], bh[nf], acc[mf][nf], 0, 0, 0);
        acc[mf][nf] = __builtin_amdgcn_mfma_f32_16x16x32_bf16(ah[mf], bh[nf], acc[mf][nf], 0, 0, 0);
      }
  }

#pragma unroll
  for (int mf = 0; mf < 4; mf++)
#pragma unroll
    for (int j = 0; j < 4; j++) {
      float m = fmaxf(fmaxf(acc[mf][0][j], acc[mf][1][j]),
                      fmaxf(acc[mf][2][j], acc[mf][3][j]));
#pragma unroll
      for (int mk = 1; mk <= 8; mk <<= 1) m = fmaxf(m, __shfl_xor(m, mk));
      if ((l & 15) == 0) {
        int row = wm * 64 + mf * 16 + lq * 4 + j;
        rowmax[(size_t)row * 4096 + cb * 2 + wn] = bf16_floor(m);
      }
    }

  float* trb = (float*)smem;
#pragma unroll
  for (int rd = 0; rd < 2; rd++) {
    __syncthreads();
#pragma unroll
    for (int hh = 0; hh < 2; hh++) {
      int mf = rd * 2 + hh;
      float* tr2 = trb + (hh * 8 + w) * 1056;
#pragma unroll
      for (int nf = 0; nf < 4; nf++)
#pragma unroll
        for (int j = 0; j < 4; j++)
          tr2[(lq * 4 + j) * 66 + nf * 16 + lrow] = acc[mf][nf][j];
    }
    __syncthreads();
#pragma unroll
    for (int hh = 0; hh < 2; hh++) {
      int mf = rd * 2 + hh;
      float* tr2 = trb + (hh * 8 + w) * 1056;
#pragma unroll
      for (int it = 0; it < 4; it++) {
        float4 vv = *(float4*)&tr2[(it * 4 + lq) * 66 + 4 * lrow];
        size_t row = (size_t)(wm * 64 + mf * 16 + it * 4 + lq);
        *(float4*)&scores[row * MEM_N + slot0 + wn * 64 + 4 * lrow] = vv;
      }
    }
  }
}

// --- variant B (LARGE ws): scores to ws + fused keys copy from registers ---
__global__ __launch_bounds__(512, 4) void k_gemm_f(
    const u16* __restrict__ ap_hi, const u16* __restrict__ ap_lo,
    const float* __restrict__ keys, float* __restrict__ scores,
    u16* __restrict__ rowmax, float* __restrict__ keys_out) {
  __shared__ __align__(16) unsigned char smem[67584];
  u16* Bf = (u16*)smem;
  const int t = threadIdx.x;
  const int cb = blockIdx.x;
  const int slot0 = cb * 128;
  const int w = t >> 6, l = t & 63;
  const int wm = w & 3, wn = w >> 2;
  const int lrow = l & 15, lq = l >> 4;
  const int srow = t >> 2, sk = t & 3;
  const float* kp = keys + (size_t)(slot0 + srow) * DIM + sk * 8;
  float* op = keys_out + ((size_t)(slot0 + srow) * DIM + sk * 8);
  const int sbase = (srow >> 6) * (16 * BPAGE);
  const int scol = srow & 63;

  f32x4 acc[4][4];
#pragma unroll
  for (int i = 0; i < 4; ++i)
#pragma unroll
    for (int j = 0; j < 4; ++j) acc[i][j] = f32x4{0.f, 0.f, 0.f, 0.f};

  {
    float4 va[4][2];
#pragma unroll
    for (int j = 0; j < 4; j++) {
      va[j][0] = *(const float4*)(kp + j * 32);
      va[j][1] = *(const float4*)(kp + j * 32 + 4);
    }
#pragma unroll
    for (int j = 0; j < 4; j++) {
      float f0[8] = {va[j][0].x, va[j][0].y, va[j][0].z, va[j][0].w,
                     va[j][1].x, va[j][1].y, va[j][1].z, va[j][1].w};
      uint4 pk;
      unsigned* pw = (unsigned*)&pk;
#pragma unroll
      for (int i = 0; i < 4; i++)
        pw[i] = (unsigned)bf16_rne(f0[2 * i]) | ((unsigned)bf16_rne(f0[2 * i + 1]) << 16);
      *(uint4*)&Bf[sbase + (j * 4 + sk) * BPAGE + scol * 8] = pk;
    }
    // fused keys copy, half 0 (unaligned packed stores; payload-exact)
#pragma unroll
    for (int j = 0; j < 4; j++) {
      *(f4u*)(op + j * 32) = f4u{va[j][0].x, va[j][0].y, va[j][0].z, va[j][0].w};
      *(f4u*)(op + j * 32 + 4) = f4u{va[j][1].x, va[j][1].y, va[j][1].z, va[j][1].w};
    }
  }
  __syncthreads();
#pragma unroll
  for (int ksl = 0; ksl < 4; ksl++) {
    short8 bh[4], ah[4], al[4];
#pragma unroll
    for (int nf = 0; nf < 4; nf++)
      bh[nf] = *(const short8*)(&Bf[wn * (16 * BPAGE) + (ksl * 4 + lq) * BPAGE + (nf * 16 + lrow) * 8]);
#pragma unroll
    for (int mf = 0; mf < 4; mf++) {
      size_t ab = ((size_t)((wm * 4 + mf) * 8 + ksl) * 64 + l) * 8;
      ah[mf] = *(const short8*)(ap_hi + ab);
      al[mf] = *(const short8*)(ap_lo + ab);
    }
#pragma unroll
    for (int mf = 0; mf < 4; mf++)
#pragma unroll
      for (int nf = 0; nf < 4; nf++) {
        acc[mf][nf] = __builtin_amdgcn_mfma_f32_16x16x32_bf16(al[mf], bh[nf], acc[mf][nf], 0, 0, 0);
        acc[mf][nf] = __builtin_amdgcn_mfma_f32_16x16x32_bf16(ah[mf], bh[nf], acc[mf][nf], 0, 0, 0);
      }
  }
  float4 vb[4][2];
#pragma unroll
  for (int j = 0; j < 4; j++) {
    vb[j][0] = *(const float4*)(kp + 128 + j * 32);
    vb[j][1] = *(const float4*)(kp + 128 + j * 32 + 4);
  }
  // fused keys copy, half 1
#pragma unroll
  for (int j = 0; j < 4; j++) {
    *(f4u*)(op + 128 + j * 32) = f4u{vb[j][0].x, vb[j][0].y, vb[j][0].z, vb[j][0].w};
    *(f4u*)(op + 128 + j * 32 + 4) = f4u{vb[j][1].x, vb[j][1].y, vb[j][1].z, vb[j][1].w};
  }
  __syncthreads();
#pragma unroll
  for (int j = 0; j < 4; j++) {
    float f0[8] = {vb[j][0].x, vb[j][0].y, vb[j][0].z, vb[j][0].w,
                   vb[j][1].x, vb[j][1].y, vb[j][1].z, vb[j][1].w};
    uint4 pk;
    unsigned* pw = (unsigned*)&pk;
#pragma unroll
    for (int i = 0; i < 4; i++)
      pw[i] = (unsigned)bf16_rne(f0[2 * i]) | ((unsigned)bf16_rne(f0[2 * i + 1]) << 16);
    *(uint4*)&Bf[sbase + (j * 4 + sk) * BPAGE + scol * 8] = pk;
  }
  __syncthreads();
#pragma unroll
  for (int ksl = 0; ksl < 4; ksl++) {
    short8 bh[4], ah[4], al[4];
#pragma unroll
    for (int nf = 0; nf < 4; nf++)
      bh[nf] = *(const short8*)(&Bf[wn * (16 * BPAGE) + (ksl * 4 + lq) * BPAGE + (nf * 16 + lrow) * 8]);
#pragma unroll
    for (int mf = 0; mf < 4; mf++) {
      size_t ab = ((size_t)((wm * 4 + mf) * 8 + 4 + ksl) * 64 + l) * 8;
      ah[mf] = *(const short8*)(ap_hi + ab);
      al[mf] = *(const short8*)(ap_lo + ab);
    }
#pragma unroll
    for (int mf = 0; mf < 4; mf++)
#pragma unroll
      for (int nf = 0; nf < 4; nf++) {
        acc[mf][nf] = __builtin_amdgcn_mfma_f32_16x16x32_bf16(al[mf], bh[nf], acc[mf][nf], 0, 0, 0);
        acc[mf][nf] = __builtin_amdgcn_mfma_f32_16x16x32_bf16(ah[mf], bh[nf], acc[mf][nf], 0, 0, 0);
      }
  }

#pragma unroll
  for (int mf = 0; mf < 4; mf++)
#pragma unroll
    for (int j = 0; j < 4; j++) {
      float m = fmaxf(fmaxf(acc[mf][0][j], acc[mf][1][j]),
                      fmaxf(acc[mf][2][j], acc[mf][3][j]));
#pragma unroll
      for (int mk = 1; mk <= 8; mk <<= 1) m = fmaxf(m, __shfl_xor(m, mk));
      if ((l & 15) == 0) {
        int row = wm * 64 + mf * 16 + lq * 4 + j;
        rowmax[(size_t)row * 4096 + cb * 2 + wn] = bf16_floor(m);
      }
    }

  float* trb = (float*)smem;
#pragma unroll
  for (int rd = 0; rd < 2; rd++) {
    __syncthreads();
#pragma unroll
    for (int hh = 0; hh < 2; hh++) {
      int mf = rd * 2 + hh;
      float* tr2 = trb + (hh * 8 + w) * 1056;
#pragma unroll
      for (int nf = 0; nf < 4; nf++)
#pragma unroll
        for (int j = 0; j < 4; j++)
          tr2[(lq * 4 + j) * 66 + nf * 16 + lrow] = acc[mf][nf][j];
    }
    __syncthreads();
#pragma unroll
    for (int hh = 0; hh < 2; hh++) {
      int mf = rd * 2 + hh;
      float* tr2 = trb + (hh * 8 + w) * 1056;
#pragma unroll
      for (int it = 0; it < 4; it++) {
        float4 vv = *(float4*)&tr2[(it * 4 + lq) * 66 + 4 * lrow];
        size_t row = (size_t)(wm * 64 + mf * 16 + it * 4 + lq);
        *(float4*)&scores[row * MEM_N + slot0 + wn * 64 + 4 * lrow] = vv;
      }
    }
  }
}

// ---- cutoff = exact ksel-th largest of 4096 bf16 group-maxima (per block-row) ----
__global__ __launch_bounds__(256) void k_cut(
    const u16* __restrict__ rowmax, float* __restrict__ cut_row, int ksel) {
  __shared__ int h[256];
  __shared__ int Bsh, Lsh;
  const int r = blockIdx.x, t = threadIdx.x;
  const u16* rm = rowmax + (size_t)r * 4096;
  uint4 a0 = *(const uint4*)(rm + t * 16);
  uint4 a1 = *(const uint4*)(rm + t * 16 + 8);
  u16 f[16];
  unsigned aw[8] = {a0.x, a0.y, a0.z, a0.w, a1.x, a1.y, a1.z, a1.w};
#pragma unroll
  for (int i = 0; i < 8; i++) {
    f[2 * i] = flip16((u16)(aw[i] & 0xFFFFu));
    f[2 * i + 1] = flip16((u16)(aw[i] >> 16));
  }
  h[t] = 0;
  __syncthreads();
#pragma unroll
  for (int i = 0; i < 16; i++) atomicAdd(&h[f[i] >> 8], 1);
  __syncthreads();
  for (int off = 1; off < 256; off <<= 1) {
    int v = (t + off < 256) ? h[t + off] : 0;
    __syncthreads();
    h[t] += v;
    __syncthreads();
  }
  if (h[t] >= ksel && (t == 255 || h[t + 1] < ksel)) Bsh = t;
  __syncthreads();
  const int B = Bsh;
  const int above = (B == 255) ? 0 : h[B + 1];
  __syncthreads();
  h[t] = 0;
  __syncthreads();
#pragma unroll
  for (int i = 0; i < 16; i++)
    if ((f[i] >> 8) == B) atomicAdd(&h[f[i] & 255], 1);
  __syncthreads();
  for (int off = 1; off < 256; off <<= 1) {
    int v = (t + off < 256) ? h[t + off] : 0;
    __syncthreads();
    h[t] += v;
    __syncthreads();
  }
  if (above + h[t] >= ksel && (t == 255 || above + h[t + 1] < ksel)) Lsh = t;
  __syncthreads();
  if (t == 0) {
    u16 fs = (u16)((B << 8) | Lsh);
    cut_row[r] = bf16_f32(unflip16(fs));
  }
}

// ---------------- sort helper ----------------
__device__ void bitonic_desc(u64* a, int N, int t) {
  for (int k = 2; k <= N; k <<= 1) {
    for (int j = k >> 1; j > 0; j >>= 1) {
      for (int i = t; i < N; i += 256) {
        int p = i ^ j;
        if (p > i) {
          u64 xv = a[i], yv = a[p];
          bool up = ((i & k) == 0);
          if (up ? (xv < yv) : (xv > yv)) { a[i] = yv; a[p] = xv; }
        }
      }
      __syncthreads();
    }
  }
}

// ---- sweep (SMALL): rowmax-guided sparse filter + keys copy ----
__global__ __launch_bounds__(256) void k_sweep(
    const float* __restrict__ scores, const float* __restrict__ cut_row,
    const u16* __restrict__ rowmax, const float* __restrict__ keys,
    u64* __restrict__ cand_row, int* __restrict__ row_cnt,
    float* __restrict__ keys_out) {
  __shared__ u64 lbuf[2048];
  __shared__ u16 sblk[512];
  __shared__ int lcnt, nsb, gbase;
  const int seg = blockIdx.x, r = blockIdx.y, t = threadIdx.x;
  if (t == 0) { lcnt = 0; nsb = 0; }
  __syncthreads();
  const float cutval = cut_row[r];
  const float* p = scores + (size_t)r * MEM_N + (size_t)seg * SEG_SZ;

  const u16* rm = rowmax + (size_t)r * 4096 + seg * 512;
#pragma unroll
  for (int i2 = 0; i2 < 2; i2++) {
    int i = t * 2 + i2;
    if (bf16_f32(rm[i]) >= cutval) {
      int pz = atomicAdd(&nsb, 1);
      sblk[pz] = (u16)i;
    }
  }
  __syncthreads();
  const int ns = nsb;
  for (int i0 = 0; i0 < ns; i0 += 16) {
    int ib = i0 + (t >> 4);
    if (ib < ns) {
      int b = sblk[ib];
      int off = b * 64 + (t & 15) * 4;
      float4 v = *(const float4*)(p + off);
      float vv[4] = {v.x, v.y, v.z, v.w};
      int c0 = seg * SEG_SZ + off;
#pragma unroll
      for (int e = 0; e < 4; e++) {
        if (vv[e] >= cutval) {
          u64 key = (((u64)flip32(vv[e])) << 32) | (unsigned)(~(unsigned)(c0 + e));
          int pz = atomicAdd(&lcnt, 1);
          if (pz < 2048) lbuf[pz] = key;
        }
      }
    }
  }
  __syncthreads();
  int n = lcnt < 2048 ? lcnt : 2048;
  if (t == 0) gbase = atomicAdd(&row_cnt[r], n);
  __syncthreads();
  const int gb = gbase;
  u64* crow = cand_row + (size_t)r * ROWCAP;
  for (int i = t; i < n; i += 256) {
    int gp = gb + i;
    if (gp < ROWCAP) crow[gp] = lbuf[i];
  }

  // phase B: keys copy (SMALL path only)
  const long long b = (long long)r * MEM_N + (long long)seg * SEG_SZ - 1;
  for (int i = t; i < 8192; i += 256) {
    long long k4 = b + 4LL * i;
    if (k4 < 0) continue;
    float s = keys[k4];
    float4 v = *(const float4*)(keys + k4 + 1);
    float4 o;
    o.x = s; o.y = v.x; o.z = v.y; o.w = v.z;
    *(float4*)(keys_out + k4) = o;
  }
  if (r == 0 && seg == 0 && t == 0) {
    keys_out[0] = keys[0]; keys_out[1] = keys[1]; keys_out[2] = keys[2];
  }
}

// ---- sweep (LARGE): sparse filter only ----
__global__ __launch_bounds__(256) void k_sweep_s(
    const float* __restrict__ scores, const float* __restrict__ cut_row,
    const u16* __restrict__ rowmax, u64* __restrict__ cand_row,
    int* __restrict__ row_cnt) {
  __shared__ u64 lbuf[2048];
  __shared__ u16 sblk[512];
  __shared__ int lcnt, nsb, gbase;
  const int seg = blockIdx.x, r = blockIdx.y, t = threadIdx.x;
  if (t == 0) { lcnt = 0; nsb = 0; }
  __syncthreads();
  const float cutval = cut_row[r];
  const float* p = scores + (size_t)r * MEM_N + (size_t)seg * SEG_SZ;
  const u16* rm = rowmax + (size_t)r * 4096 + seg * 512;
#pragma unroll
  for (int i2 = 0; i2 < 2; i2++) {
    int i = t * 2 + i2;
    if (bf16_f32(rm[i]) >= cutval) {
      int pz = atomicAdd(&nsb, 1);
      sblk[pz] = (u16)i;
    }
  }
  __syncthreads();
  const int ns = nsb;
  for (int i0 = 0; i0 < ns; i0 += 16) {
    int ib = i0 + (t >> 4);
    if (ib < ns) {
      int b = sblk[ib];
      int off = b * 64 + (t & 15) * 4;
      float4 v = *(const float4*)(p + off);
      float vv[4] = {v.x, v.y, v.z, v.w};
      int c0 = seg * SEG_SZ + off;
#pragma unroll
      for (int e = 0; e < 4; e++) {
        if (vv[e] >= cutval) {
          u64 key = (((u64)flip32(vv[e])) << 32) | (unsigned)(~(unsigned)(c0 + e));
          int pz = atomicAdd(&lcnt, 1);
          if (pz < 2048) lbuf[pz] = key;
        }
      }
    }
  }
  __syncthreads();
  int n = lcnt < 2048 ? lcnt : 2048;
  if (t == 0) gbase = atomicAdd(&row_cnt[r], n);
  __syncthreads();
  const int gb = gbase;
  u64* crow = cand_row + (size_t)r * ROWCAP;
  for (int i = t; i < n; i += 256) {
    int gp = gb + i;
    if (gp < ROWCAP) crow[gp] = lbuf[i];
  }
}

// ---- top-k finalize: sort + softmax + loss + yhat + reset + correct-update ----
__global__ __launch_bounds__(256) void k_topk2(
    const u64* __restrict__ cand_row, const int* __restrict__ row_cnt,
    const int* __restrict__ values, const int* __restrict__ yv,
    const float* __restrict__ keys, const float* __restrict__ q,
    float* __restrict__ out, float* __restrict__ loss_arr,
    int* __restrict__ corr, float* __restrict__ age_out,
    float* __restrict__ keys_out) {
  __shared__ u64 buf[ROWCAP];
  __shared__ float red[256];
  const int r = blockIdx.x, t = threadIdx.x;
  if (r == 255 && t == 32) {
    const long long N = (long long)MEM_N * DIM;
    keys_out[N - 1] = keys[N - 1];  // SMALL: required patch; LARGE: redundant-correct
  }
  int cnt = row_cnt[r];
  cnt = cnt < ROWCAP ? cnt : ROWCAP;
  int S = 256;
  while (S < cnt) S <<= 1;
  const u64* src = cand_row + (size_t)r * ROWCAP;
  for (int i = t; i < S; i += 256) buf[i] = (i < cnt) ? src[i] : 0ULL;
  __syncthreads();
  bitonic_desc(buf, S, t);

  u64 mykey = buf[t];
  int midx = (int)(~(unsigned)(mykey & 0xFFFFFFFFull));
  float msc = unflip32((unsigned)(mykey >> 32));
  int yr = yv[r];
  float mask = (values[midx] == yr) ? 1.0f : 0.0f;
  float mtop = unflip32((unsigned)(buf[0] >> 32));
  int i0 = (int)(~(unsigned)(buf[0] & 0xFFFFFFFFull));
  int vi0 = values[i0];
  bool correct = (vi0 == yr);

  float e = expf(msc - mtop);  // TEMP == 1.0
  red[t] = e; __syncthreads();
  for (int s = 128; s > 0; s >>= 1) { if (t < s) red[t] += red[t + s]; __syncthreads(); }
  float denom = red[0]; __syncthreads();
  out[256 + r * 256 + t] = e / denom;

  red[t] = msc * mask; __syncthreads();
  for (int s = 128; s > 0; s >>= 1) { if (t < s) red[t] = fmaxf(red[t], red[t + s]); __syncthreads(); }
  float posr = red[0]; __syncthreads();

  red[t] = msc * (1.0f - mask); __syncthreads();
  for (int s = 128; s > 0; s >>= 1) { if (t < s) red[t] = fmaxf(red[t], red[t + s]); __syncthreads(); }
  float negr = red[0]; __syncthreads();

  red[t] = mask; __syncthreads();
  for (int s = 128; s > 0; s >>= 1) { if (t < s) red[t] += red[t + s]; __syncthreads(); }
  float hp = (red[0] > 0.0f) ? 1.0f : 0.0f;
  __syncthreads();

  if (t == 0) {
    float pos = posr * hp;
    loss_arr[r] = fmaxf(negr - pos + 0.1f, 0.0f);
    out[r] = (float)vi0;
    corr[r] = correct ? 1 : 0;
  }
  if (correct) {
    if (t == 0) age_out[i0] = 0.0f;
    float v = keys[(size_t)i0 * DIM + t] + q[r * DIM + t];
    red[t] = v * v; __syncthreads();
    for (int s = 128; s > 0; s >>= 1) { if (t < s) red[t] += red[t + s]; __syncthreads(); }
    float nrm = fmaxf(sqrtf(red[0]), 1e-12f);
    keys_out[(size_t)i0 * DIM + t] = v / nrm;
  }
}

// ---------------- age/values init ----------------
__global__ __launch_bounds__(256) void k_age(
    const float* __restrict__ age, const int* __restrict__ values,
    float* __restrict__ age_out, float* __restrict__ vals_out) {
  int i = blockIdx.x * 256 + threadIdx.x;
  age_out[i] = age[i] + 1.0f;
  vals_out[i] = (float)values[i];
}

// ---- oldest path stage 1: 64-elt group maxima of age_noisy (bf16 floored) ----
__global__ __launch_bounds__(256) void k_oldmax(
    const float* __restrict__ age_out, const float* __restrict__ un,
    u16* __restrict__ old_max) {
  const int t = threadIdx.x, bid = blockIdx.x;
  int g = bid * 1024 + t * 4;
  float4 a = *(const float4*)(age_out + g);
  float4 n4 = *(const float4*)(un + g);
  float m = a.x + (2.0f * n4.x - 1.0f) * 8.0f;
  m = fmaxf(m, a.y + (2.0f * n4.y - 1.0f) * 8.0f);
  m = fmaxf(m, a.z + (2.0f * n4.z - 1.0f) * 8.0f);
  m = fmaxf(m, a.w + (2.0f * n4.w - 1.0f) * 8.0f);
#pragma unroll
  for (int mk = 1; mk <= 8; mk <<= 1) m = fmaxf(m, __shfl_xor(m, mk));
  if ((t & 15) == 0) old_max[bid * 16 + (t >> 4)] = bf16_floor(m);
}

// ---- oldest path stage 2: filtered sweep of age_noisy ----
__global__ __launch_bounds__(256) void k_oldsweep(
    const float* __restrict__ age_out, const float* __restrict__ un,
    const float* __restrict__ old_cut, u64* __restrict__ obuf,
    int* __restrict__ ocnt) {
  const int t = threadIdx.x, bid = blockIdx.x;
  int g = bid * 1024 + t * 4;
  const float cut = *old_cut;
  float4 a = *(const float4*)(age_out + g);
  float4 n4 = *(const float4*)(un + g);
  float av[4] = {a.x, a.y, a.z, a.w};
  float nv[4] = {n4.x, n4.y, n4.z, n4.w};
#pragma unroll
  for (int e = 0; e < 4; e++) {
    float v = av[e] + (2.0f * nv[e] - 1.0f) * 8.0f;
    if (v >= cut) {
      u64 k = (((u64)flip32(v)) << 32) | (unsigned)(~(unsigned)(g + e));
      int p = atomicAdd(ocnt, 1);
      if (p < OCAP) obuf[p] = k;
    }
  }
}

// ---- oldest path stage 3: sort survivors, dest assignment, loss mean ----
__global__ __launch_bounds__(256) void k_oldB(
    const u64* __restrict__ obuf, const int* __restrict__ ocnt,
    const int* __restrict__ corr, const float* __restrict__ loss_arr,
    int* __restrict__ dest, float* __restrict__ out_loss) {
  __shared__ u64 cand[OCAP];
  __shared__ int olds[256];
  __shared__ int pre[256];
  __shared__ float red[256];
  const int t = threadIdx.x;
  int n = *ocnt;
  n = n < OCAP ? n : OCAP;
  int S = 256;
  while (S < n) S <<= 1;
  for (int i = t; i < S; i += 256) cand[i] = (i < n) ? obuf[i] : 0ULL;
  __syncthreads();
  bitonic_desc(cand, S, t);
  olds[t] = (int)(~(unsigned)(cand[t] & 0xFFFFFFFFull));
  int inc = corr[t] ? 0 : 1;
  pre[t] = inc;
  __syncthreads();
  for (int off = 1; off < 256; off <<= 1) {
    int v = (t >= off) ? pre[t - off] : 0;
    __syncthreads();
    pre[t] += v;
    __syncthreads();
  }
  int rank = pre[t] - 1;
  dest[t] = inc ? olds[rank] : -1;
  red[t] = loss_arr[t]; __syncthreads();
  for (int s = 128; s > 0; s >>= 1) { if (t < s) red[t] += red[t + s]; __syncthreads(); }
  if (t == 0) *out_loss = red[0] * (1.0f / 256.0f);
}

// ---------------- incorrect-row scatter ----------------
__global__ __launch_bounds__(256) void k_incorrect(
    const int* __restrict__ dest, const float* __restrict__ q,
    const int* __restrict__ yv, float* __restrict__ keys_out,
    float* __restrict__ vals_out, float* __restrict__ age_out) {
  const int r = blockIdx.x;
  int d = dest[r];
  if (d < 0) return;
  const int t = threadIdx.x;
  keys_out[(size_t)d * DIM + t] = q[r * DIM + t];
  if (t == 0) {
    vals_out[d] = (float)yv[r];
    age_out[d] = 0.0f;
  }
}

extern "C" void kernel_launch(void* const* d_in, const int* in_sizes, int n_in,
                              void* d_out, int out_size, void* d_ws, size_t ws_size,
                              hipStream_t stream) {
  const float* x = (const float*)d_in[0];
  const int* y = (const int*)d_in[1];
  const float* W = (const float*)d_in[2];
  const float* b = (const float*)d_in[3];
  const float* keys = (const float*)d_in[4];
  const int* values = (const int*)d_in[5];
  const float* age = (const float*)d_in[6];
  const float* un = (const float*)d_in[7];
  float* out = (float*)d_out;

  char* ws = (char*)d_ws;
  float* q = (float*)ws;                             // 256 KB
  u16* ap_hi = (u16*)(ws + 262144);                  // 128 KB
  u16* ap_lo = (u16*)(ws + 393216);                  // 128 KB
  float* loss_arr = (float*)(ws + 524288);           // 1 KB
  int* corr = (int*)(ws + 525312);                   // 1 KB
  u64* obuf = (u64*)(ws + 527360);                   // 32 KB (OCAP u64)
  int* dest = (int*)(ws + 560128);                   // 1 KB
  int* row_cnt = (int*)(ws + 561152);                // 1 KB
  float* cut_row = (float*)(ws + 562176);            // 1 KB
  u16* old_max = (u16*)(ws + 563200);                // 8 KB (4096 u16)
  float* old_cut = (float*)(ws + 571392);            // 4 B
  int* ocnt = (int*)(ws + 571648);                   // 4 B
  u64* cand_row = (u64*)(ws + 1048576);              // 4 MB (256 x ROWCAP)

  // d_out layout (floats): yhat[256] | softmax[65536] | loss[1] | keys[67108864]
  //                        | values[262144] | age[262144]
  const size_t LOSS_OFF = 65792, KEYS_OFF = 65793, VALS_OFF = 67174657,
               AGE_OFF = 67436801;
  float* keys_out = out + KEYS_OFF;
  float* vals_out = out + VALS_OFF;
  float* age_out = out + AGE_OFF;

  const size_t NEED_LARGE = 8388608ull + 268435456ull;  // rowmax_ws + scores_ws
  const bool large = (ws_size >= NEED_LARGE);

  k_query<<<dim3(256), dim3(256), 0, stream>>>(x, W, b, q, ap_hi, ap_lo, row_cnt, ocnt);
  if (large) {
    u16* rowmax = (u16*)(ws + 6291456);    // 2 MB at ws+6MB
    float* scores = (float*)(ws + 8388608);  // 256 MB at ws+8MB
    k_gemm_f<<<dim3(2048), dim3(512), 0, stream>>>(ap_hi, ap_lo, keys, scores, rowmax, keys_out);
    k_cut<<<dim3(256), dim3(256), 0, stream>>>(rowmax, cut_row, KSEL_SCORES);
    k_sweep_s<<<dim3(NSEG, 256), dim3(256), 0, stream>>>(scores, cut_row, rowmax, cand_row, row_cnt);
  } else {
    float* scores = out + 65792;           // 256 MB scratch over loss+keys region
    u16* rowmax = (u16*)(out + 67174656);  // 2 MB over last-key+values+age
    k_gemm<<<dim3(2048), dim3(512), 0, stream>>>(ap_hi, ap_lo, keys, scores, rowmax);
    k_cut<<<dim3(256), dim3(256), 0, stream>>>(rowmax, cut_row, KSEL_SCORES);
    k_sweep<<<dim3(NSEG, 256), dim3(256), 0, stream>>>(scores, cut_row, rowmax, keys, cand_row, row_cnt, keys_out);
  }
  k_age<<<dim3(1024), dim3(256), 0, stream>>>(age, values, age_out, vals_out);
  k_topk2<<<dim3(256), dim3(256), 0, stream>>>(cand_row, row_cnt, values, y, keys, q,
                                               out, loss_arr, corr, age_out, keys_out);
  k_oldmax<<<dim3(256), dim3(256), 0, stream>>>(age_out, un, old_max);
  k_cut<<<dim3(1), dim3(256), 0, stream>>>(old_max, old_cut, 256);
  k_oldsweep<<<dim3(256), dim3(256), 0, stream>>>(age_out, un, old_cut, obuf, ocnt);
  k_oldB<<<dim3(1), dim3(256), 0, stream>>>(obuf, ocnt, corr, loss_arr, dest, out + LOSS_OFF);
  k_incorrect<<<dim3(256), dim3(256), 0, stream>>>(dest, q, y, keys_out, vals_out, age_out);
}

// Round 19
// 378.973 us; speedup vs baseline: 1.1573x; 1.0448x over previous
//
#include <hip/hip_runtime.h>

#define MEM_N 262144
#define DIM 256
#define NBATCH 256
#define OCAP 4096
#define NSEG 8
#define SEG_SZ 32768
#define ROWCAP 2048
#define KSEL_SCORES 320
#define BPAGE 528  // u16 per LDS page (1056B): 8-bank skew between kq pages

typedef __attribute__((ext_vector_type(8))) short short8;
typedef __attribute__((ext_vector_type(4))) float f32x4;
typedef unsigned long long u64;
typedef unsigned short u16;

struct __attribute__((packed)) f4u { float x, y, z, w; };

__device__ __forceinline__ u16 bf16_rne(float f) {
  unsigned u = __builtin_bit_cast(unsigned, f);
  u += 0x7FFFu + ((u >> 16) & 1u);
  return (u16)(u >> 16);
}
__device__ __forceinline__ float bf16_f32(u16 h) {
  unsigned u = ((unsigned)h) << 16;
  return __builtin_bit_cast(float, u);
}
__device__ __forceinline__ u16 bf16_floor(float f) {
  unsigned u = __builtin_bit_cast(unsigned, f);
  u16 h = (u16)(u >> 16);
  if ((u & 0x80000000u) && (u & 0xFFFFu)) h++;
  return h;
}
__device__ __forceinline__ unsigned flip32(float f) {
  unsigned u = __builtin_bit_cast(unsigned, f);
  return u ^ ((unsigned)((int)u >> 31) | 0x80000000u);
}
__device__ __forceinline__ float unflip32(unsigned k) {
  unsigned u = (k & 0x80000000u) ? (k ^ 0x80000000u) : ~k;
  return __builtin_bit_cast(float, u);
}
__device__ __forceinline__ u16 flip16(u16 b) {
  return (b & 0x8000u) ? (u16)~b : (u16)(b | 0x8000u);
}
__device__ __forceinline__ u16 unflip16(u16 f) {
  return (f & 0x8000u) ? (u16)(f ^ 0x8000u) : (u16)~f;
}
__device__ __forceinline__ void nt_store4(float4 v, float* p) {
  f32x4 x = {v.x, v.y, v.z, v.w};
  __builtin_nontemporal_store(x, (f32x4*)p);
}

// ---------------- query = normalize(x @ W^T + b), + packed-A emit ----------------
__global__ __launch_bounds__(256) void k_query(
    const float* __restrict__ x, const float* __restrict__ W,
    const float* __restrict__ b, float* __restrict__ q,
    u16* __restrict__ ap_hi, u16* __restrict__ ap_lo, int* __restrict__ row_cnt,
    int* __restrict__ ocnt) {
  __shared__ float Wt[256][36];
  __shared__ float xs[256];
  __shared__ float red[256];
  const int r = blockIdx.x, t = threadIdx.x;
  if (t == 0) row_cnt[r] = 0;
  if (r == 0 && t == 0) *ocnt = 0;
  xs[t] = x[r * DIM + t];
  float acc = b[t];
  for (int k0 = 0; k0 < DIM; k0 += 32) {
    __syncthreads();
#pragma unroll
    for (int i = 0; i < 8; i++) {
      int f = i * 256 + t;
      int j = f >> 3, c = (f & 7) * 4;
      *(float4*)&Wt[j][c] = *(const float4*)&W[j * DIM + k0 + c];
    }
    __syncthreads();
#pragma unroll
    for (int c = 0; c < 32; c++) acc = fmaf(xs[k0 + c], Wt[t][c], acc);
  }
  red[t] = acc * acc;
  __syncthreads();
  for (int s = 128; s > 0; s >>= 1) {
    if (t < s) red[t] += red[t + s];
    __syncthreads();
  }
  float nrm = fmaxf(sqrtf(red[0]), 1e-12f);
  float qv = acc / nrm;
  q[r * DIM + t] = qv;
  u16 h = bf16_rne(qv);
  u16 lo = bf16_rne(qv - bf16_f32(h));
  // packed MFMA A-fragment layout: [r16][kstep][lane][j]
  int r16 = r >> 4, s = t >> 5, hi = (t >> 3) & 3, j = t & 7;
  int l = hi * 16 + (r & 15);
  size_t off = ((size_t)(r16 * 8 + s) * 64 + l) * 8 + j;
  ap_hi[off] = h;
  ap_lo[off] = lo;
}

// --- variant A (SMALL ws): scores to out-region scratch; keys copy left to sweep ---
__global__ __launch_bounds__(512, 4) void k_gemm(
    const u16* __restrict__ ap_hi, const u16* __restrict__ ap_lo,
    const float* __restrict__ keys, float* __restrict__ scores,
    u16* __restrict__ rowmax) {
  __shared__ __align__(16) unsigned char smem[67584];
  u16* Bf = (u16*)smem;
  const int t = threadIdx.x;
  const int cb = blockIdx.x;
  const int slot0 = cb * 128;
  const int w = t >> 6, l = t & 63;
  const int wm = w & 3, wn = w >> 2;
  const int lrow = l & 15, lq = l >> 4;
  const int srow = t >> 2, sk = t & 3;
  const float* kp = keys + (size_t)(slot0 + srow) * DIM + sk * 8;
  const int sbase = (srow >> 6) * (16 * BPAGE);
  const int scol = srow & 63;

  f32x4 acc[4][4];
#pragma unroll
  for (int i = 0; i < 4; ++i)
#pragma unroll
    for (int j = 0; j < 4; ++j) acc[i][j] = f32x4{0.f, 0.f, 0.f, 0.f};

  {
    float4 va[4][2];
#pragma unroll
    for (int j = 0; j < 4; j++) {
      va[j][0] = *(const float4*)(kp + j * 32);
      va[j][1] = *(const float4*)(kp + j * 32 + 4);
    }
#pragma unroll
    for (int j = 0; j < 4; j++) {
      float f0[8] = {va[j][0].x, va[j][0].y, va[j][0].z, va[j][0].w,
                     va[j][1].x, va[j][1].y, va[j][1].z, va[j][1].w};
      uint4 pk;
      unsigned* pw = (unsigned*)&pk;
#pragma unroll
      for (int i = 0; i < 4; i++)
        pw[i] = (unsigned)bf16_rne(f0[2 * i]) | ((unsigned)bf16_rne(f0[2 * i + 1]) << 16);
      *(uint4*)&Bf[sbase + (j * 4 + sk) * BPAGE + scol * 8] = pk;
    }
  }
  __syncthreads();
#pragma unroll
  for (int ksl = 0; ksl < 4; ksl++) {
    short8 bh[4], ah[4], al[4];
#pragma unroll
    for (int nf = 0; nf < 4; nf++)
      bh[nf] = *(const short8*)(&Bf[wn * (16 * BPAGE) + (ksl * 4 + lq) * BPAGE + (nf * 16 + lrow) * 8]);
#pragma unroll
    for (int mf = 0; mf < 4; mf++) {
      size_t ab = ((size_t)((wm * 4 + mf) * 8 + ksl) * 64 + l) * 8;
      ah[mf] = *(const short8*)(ap_hi + ab);
      al[mf] = *(const short8*)(ap_lo + ab);
    }
#pragma unroll
    for (int mf = 0; mf < 4; mf++)
#pragma unroll
      for (int nf = 0; nf < 4; nf++) {
        acc[mf][nf] = __builtin_amdgcn_mfma_f32_16x16x32_bf16(al[mf], bh[nf], acc[mf][nf], 0, 0, 0);
        acc[mf][nf] = __builtin_amdgcn_mfma_f32_16x16x32_bf16(ah[mf], bh[nf], acc[mf][nf], 0, 0, 0);
      }
  }
  float4 vb[4][2];
#pragma unroll
  for (int j = 0; j < 4; j++) {
    vb[j][0] = *(const float4*)(kp + 128 + j * 32);
    vb[j][1] = *(const float4*)(kp + 128 + j * 32 + 4);
  }
  __syncthreads();
#pragma unroll
  for (int j = 0; j < 4; j++) {
    float f0[8] = {vb[j][0].x, vb[j][0].y, vb[j][0].z, vb[j][0].w,
                   vb[j][1].x, vb[j][1].y, vb[j][1].z, vb[j][1].w};
    uint4 pk;
    unsigned* pw = (unsigned*)&pk;
#pragma unroll
    for (int i = 0; i < 4; i++)
      pw[i] = (unsigned)bf16_rne(f0[2 * i]) | ((unsigned)bf16_rne(f0[2 * i + 1]) << 16);
    *(uint4*)&Bf[sbase + (j * 4 + sk) * BPAGE + scol * 8] = pk;
  }
  __syncthreads();
#pragma unroll
  for (int ksl = 0; ksl < 4; ksl++) {
    short8 bh[4], ah[4], al[4];
#pragma unroll
    for (int nf = 0; nf < 4; nf++)
      bh[nf] = *(const short8*)(&Bf[wn * (16 * BPAGE) + (ksl * 4 + lq) * BPAGE + (nf * 16 + lrow) * 8]);
#pragma unroll
    for (int mf = 0; mf < 4; mf++) {
      size_t ab = ((size_t)((wm * 4 + mf) * 8 + 4 + ksl) * 64 + l) * 8;
      ah[mf] = *(const short8*)(ap_hi + ab);
      al[mf] = *(const short8*)(ap_lo + ab);
    }
#pragma unroll
    for (int mf = 0; mf < 4; mf++)
#pragma unroll
      for (int nf = 0; nf < 4; nf++) {
        acc[mf][nf] = __builtin_amdgcn_mfma_f32_16x16x32_bf16(al[mf], bh[nf], acc[mf][nf], 0, 0, 0);
        acc[mf][nf] = __builtin_amdgcn_mfma_f32_16x16x32_bf16(ah[mf], bh[nf], acc[mf][nf], 0, 0, 0);
      }
  }

#pragma unroll
  for (int mf = 0; mf < 4; mf++)
#pragma unroll
    for (int j = 0; j < 4; j++) {
      float m = fmaxf(fmaxf(acc[mf][0][j], acc[mf][1][j]),
                      fmaxf(acc[mf][2][j], acc[mf][3][j]));
#pragma unroll
      for (int mk = 1; mk <= 8; mk <<= 1) m = fmaxf(m, __shfl_xor(m, mk));
      if ((l & 15) == 0) {
        int row = wm * 64 + mf * 16 + lq * 4 + j;
        rowmax[(size_t)row * 4096 + cb * 2 + wn] = bf16_floor(m);
      }
    }

  float* trb = (float*)smem;
#pragma unroll
  for (int rd = 0; rd < 2; rd++) {
    __syncthreads();
#pragma unroll
    for (int hh = 0; hh < 2; hh++) {
      int mf = rd * 2 + hh;
      float* tr2 = trb + (hh * 8 + w) * 1056;
#pragma unroll
      for (int nf = 0; nf < 4; nf++)
#pragma unroll
        for (int j = 0; j < 4; j++)
          tr2[(lq * 4 + j) * 66 + nf * 16 + lrow] = acc[mf][nf][j];
    }
    __syncthreads();
#pragma unroll
    for (int hh = 0; hh < 2; hh++) {
      int mf = rd * 2 + hh;
      float* tr2 = trb + (hh * 8 + w) * 1056;
#pragma unroll
      for (int it = 0; it < 4; it++) {
        float4 vv = *(float4*)&tr2[(it * 4 + lq) * 66 + 4 * lrow];
        size_t row = (size_t)(wm * 64 + mf * 16 + it * 4 + lq);
        nt_store4(vv, &scores[row * MEM_N + slot0 + wn * 64 + 4 * lrow]);
      }
    }
  }
}

// --- variant B (LARGE ws): scores to ws (nontemporal) + fused keys copy ---
__global__ __launch_bounds__(512, 4) void k_gemm_f(
    const u16* __restrict__ ap_hi, const u16* __restrict__ ap_lo,
    const float* __restrict__ keys, float* __restrict__ scores,
    u16* __restrict__ rowmax, float* __restrict__ keys_out) {
  __shared__ __align__(16) unsigned char smem[67584];
  u16* Bf = (u16*)smem;
  const int t = threadIdx.x;
  const int cb = blockIdx.x;
  const int slot0 = cb * 128;
  const int w = t >> 6, l = t & 63;
  const int wm = w & 3, wn = w >> 2;
  const int lrow = l & 15, lq = l >> 4;
  const int srow = t >> 2, sk = t & 3;
  const float* kp = keys + (size_t)(slot0 + srow) * DIM + sk * 8;
  float* op = keys_out + ((size_t)(slot0 + srow) * DIM + sk * 8);
  const int sbase = (srow >> 6) * (16 * BPAGE);
  const int scol = srow & 63;

  f32x4 acc[4][4];
#pragma unroll
  for (int i = 0; i < 4; ++i)
#pragma unroll
    for (int j = 0; j < 4; ++j) acc[i][j] = f32x4{0.f, 0.f, 0.f, 0.f};

  {
    float4 va[4][2];
#pragma unroll
    for (int j = 0; j < 4; j++) {
      va[j][0] = *(const float4*)(kp + j * 32);
      va[j][1] = *(const float4*)(kp + j * 32 + 4);
    }
#pragma unroll
    for (int j = 0; j < 4; j++) {
      float f0[8] = {va[j][0].x, va[j][0].y, va[j][0].z, va[j][0].w,
                     va[j][1].x, va[j][1].y, va[j][1].z, va[j][1].w};
      uint4 pk;
      unsigned* pw = (unsigned*)&pk;
#pragma unroll
      for (int i = 0; i < 4; i++)
        pw[i] = (unsigned)bf16_rne(f0[2 * i]) | ((unsigned)bf16_rne(f0[2 * i + 1]) << 16);
      *(uint4*)&Bf[sbase + (j * 4 + sk) * BPAGE + scol * 8] = pk;
    }
#pragma unroll
    for (int j = 0; j < 4; j++) {
      *(f4u*)(op + j * 32) = f4u{va[j][0].x, va[j][0].y, va[j][0].z, va[j][0].w};
      *(f4u*)(op + j * 32 + 4) = f4u{va[j][1].x, va[j][1].y, va[j][1].z, va[j][1].w};
    }
  }
  __syncthreads();
#pragma unroll
  for (int ksl = 0; ksl < 4; ksl++) {
    short8 bh[4], ah[4], al[4];
#pragma unroll
    for (int nf = 0; nf < 4; nf++)
      bh[nf] = *(const short8*)(&Bf[wn * (16 * BPAGE) + (ksl * 4 + lq) * BPAGE + (nf * 16 + lrow) * 8]);
#pragma unroll
    for (int mf = 0; mf < 4; mf++) {
      size_t ab = ((size_t)((wm * 4 + mf) * 8 + ksl) * 64 + l) * 8;
      ah[mf] = *(const short8*)(ap_hi + ab);
      al[mf] = *(const short8*)(ap_lo + ab);
    }
#pragma unroll
    for (int mf = 0; mf < 4; mf++)
#pragma unroll
      for (int nf = 0; nf < 4; nf++) {
        acc[mf][nf] = __builtin_amdgcn_mfma_f32_16x16x32_bf16(al[mf], bh[nf], acc[mf][nf], 0, 0, 0);
        acc[mf][nf] = __builtin_amdgcn_mfma_f32_16x16x32_bf16(ah[mf], bh[nf], acc[mf][nf], 0, 0, 0);
      }
  }
  float4 vb[4][2];
#pragma unroll
  for (int j = 0; j < 4; j++) {
    vb[j][0] = *(const float4*)(kp + 128 + j * 32);
    vb[j][1] = *(const float4*)(kp + 128 + j * 32 + 4);
  }
#pragma unroll
  for (int j = 0; j < 4; j++) {
    *(f4u*)(op + 128 + j * 32) = f4u{vb[j][0].x, vb[j][0].y, vb[j][0].z, vb[j][0].w};
    *(f4u*)(op + 128 + j * 32 + 4) = f4u{vb[j][1].x, vb[j][1].y, vb[j][1].z, vb[j][1].w};
  }
  __syncthreads();
#pragma unroll
  for (int j = 0; j < 4; j++) {
    float f0[8] = {vb[j][0].x, vb[j][0].y, vb[j][0].z, vb[j][0].w,
                   vb[j][1].x, vb[j][1].y, vb[j][1].z, vb[j][1].w};
    uint4 pk;
    unsigned* pw = (unsigned*)&pk;
#pragma unroll
    for (int i = 0; i < 4; i++)
      pw[i] = (unsigned)bf16_rne(f0[2 * i]) | ((unsigned)bf16_rne(f0[2 * i + 1]) << 16);
    *(uint4*)&Bf[sbase + (j * 4 + sk) * BPAGE + scol * 8] = pk;
  }
  __syncthreads();
#pragma unroll
  for (int ksl = 0; ksl < 4; ksl++) {
    short8 bh[4], ah[4], al[4];
#pragma unroll
    for (int nf = 0; nf < 4; nf++)
      bh[nf] = *(const short8*)(&Bf[wn * (16 * BPAGE) + (ksl * 4 + lq) * BPAGE + (nf * 16 + lrow) * 8]);
#pragma unroll
    for (int mf = 0; mf < 4; mf++) {
      size_t ab = ((size_t)((wm * 4 + mf) * 8 + 4 + ksl) * 64 + l) * 8;
      ah[mf] = *(const short8*)(ap_hi + ab);
      al[mf] = *(const short8*)(ap_lo + ab);
    }
#pragma unroll
    for (int mf = 0; mf < 4; mf++)
#pragma unroll
      for (int nf = 0; nf < 4; nf++) {
        acc[mf][nf] = __builtin_amdgcn_mfma_f32_16x16x32_bf16(al[mf], bh[nf], acc[mf][nf], 0, 0, 0);
        acc[mf][nf] = __builtin_amdgcn_mfma_f32_16x16x32_bf16(ah[mf], bh[nf], acc[mf][nf], 0, 0, 0);
      }
  }

#pragma unroll
  for (int mf = 0; mf < 4; mf++)
#pragma unroll
    for (int j = 0; j < 4; j++) {
      float m = fmaxf(fmaxf(acc[mf][0][j], acc[mf][1][j]),
                      fmaxf(acc[mf][2][j], acc[mf][3][j]));
#pragma unroll
      for (int mk = 1; mk <= 8; mk <<= 1) m = fmaxf(m, __shfl_xor(m, mk));
      if ((l & 15) == 0) {
        int row = wm * 64 + mf * 16 + lq * 4 + j;
        rowmax[(size_t)row * 4096 + cb * 2 + wn] = bf16_floor(m);
      }
    }

  float* trb = (float*)smem;
#pragma unroll
  for (int rd = 0; rd < 2; rd++) {
    __syncthreads();
#pragma unroll
    for (int hh = 0; hh < 2; hh++) {
      int mf = rd * 2 + hh;
      float* tr2 = trb + (hh * 8 + w) * 1056;
#pragma unroll
      for (int nf = 0; nf < 4; nf++)
#pragma unroll
        for (int j = 0; j < 4; j++)
          tr2[(lq * 4 + j) * 66 + nf * 16 + lrow] = acc[mf][nf][j];
    }
    __syncthreads();
#pragma unroll
    for (int hh = 0; hh < 2; hh++) {
      int mf = rd * 2 + hh;
      float* tr2 = trb + (hh * 8 + w) * 1056;
#pragma unroll
      for (int it = 0; it < 4; it++) {
        float4 vv = *(float4*)&tr2[(it * 4 + lq) * 66 + 4 * lrow];
        size_t row = (size_t)(wm * 64 + mf * 16 + it * 4 + lq);
        nt_store4(vv, &scores[row * MEM_N + slot0 + wn * 64 + 4 * lrow]);
      }
    }
  }
}

// ---- cutoff = exact ksel-th largest of 4096 bf16 group-maxima (per block-row) ----
__global__ __launch_bounds__(256) void k_cut(
    const u16* __restrict__ rowmax, float* __restrict__ cut_row, int ksel) {
  __shared__ int h[256];
  __shared__ int Bsh, Lsh;
  const int r = blockIdx.x, t = threadIdx.x;
  const u16* rm = rowmax + (size_t)r * 4096;
  uint4 a0 = *(const uint4*)(rm + t * 16);
  uint4 a1 = *(const uint4*)(rm + t * 16 + 8);
  u16 f[16];
  unsigned aw[8] = {a0.x, a0.y, a0.z, a0.w, a1.x, a1.y, a1.z, a1.w};
#pragma unroll
  for (int i = 0; i < 8; i++) {
    f[2 * i] = flip16((u16)(aw[i] & 0xFFFFu));
    f[2 * i + 1] = flip16((u16)(aw[i] >> 16));
  }
  h[t] = 0;
  __syncthreads();
#pragma unroll
  for (int i = 0; i < 16; i++) atomicAdd(&h[f[i] >> 8], 1);
  __syncthreads();
  for (int off = 1; off < 256; off <<= 1) {
    int v = (t + off < 256) ? h[t + off] : 0;
    __syncthreads();
    h[t] += v;
    __syncthreads();
  }
  if (h[t] >= ksel && (t == 255 || h[t + 1] < ksel)) Bsh = t;
  __syncthreads();
  const int B = Bsh;
  const int above = (B == 255) ? 0 : h[B + 1];
  __syncthreads();
  h[t] = 0;
  __syncthreads();
#pragma unroll
  for (int i = 0; i < 16; i++)
    if ((f[i] >> 8) == B) atomicAdd(&h[f[i] & 255], 1);
  __syncthreads();
  for (int off = 1; off < 256; off <<= 1) {
    int v = (t + off < 256) ? h[t + off] : 0;
    __syncthreads();
    h[t] += v;
    __syncthreads();
  }
  if (above + h[t] >= ksel && (t == 255 || above + h[t + 1] < ksel)) Lsh = t;
  __syncthreads();
  if (t == 0) {
    u16 fs = (u16)((B << 8) | Lsh);
    cut_row[r] = bf16_f32(unflip16(fs));
  }
}

// ---------------- sort helper ----------------
__device__ void bitonic_desc(u64* a, int N, int t) {
  for (int k = 2; k <= N; k <<= 1) {
    for (int j = k >> 1; j > 0; j >>= 1) {
      for (int i = t; i < N; i += 256) {
        int p = i ^ j;
        if (p > i) {
          u64 xv = a[i], yv = a[p];
          bool up = ((i & k) == 0);
          if (up ? (xv < yv) : (xv > yv)) { a[i] = yv; a[p] = xv; }
        }
      }
      __syncthreads();
    }
  }
}

// ---- sweep (SMALL): rowmax-guided sparse filter + keys copy ----
__global__ __launch_bounds__(256) void k_sweep(
    const float* __restrict__ scores, const float* __restrict__ cut_row,
    const u16* __restrict__ rowmax, const float* __restrict__ keys,
    u64* __restrict__ cand_row, int* __restrict__ row_cnt,
    float* __restrict__ keys_out) {
  __shared__ u64 lbuf[2048];
  __shared__ u16 sblk[512];
  __shared__ int lcnt, nsb, gbase;
  const int seg = blockIdx.x, r = blockIdx.y, t = threadIdx.x;
  if (t == 0) { lcnt = 0; nsb = 0; }
  __syncthreads();
  const float cutval = cut_row[r];
  const float* p = scores + (size_t)r * MEM_N + (size_t)seg * SEG_SZ;

  const u16* rm = rowmax + (size_t)r * 4096 + seg * 512;
#pragma unroll
  for (int i2 = 0; i2 < 2; i2++) {
    int i = t * 2 + i2;
    if (bf16_f32(rm[i]) >= cutval) {
      int pz = atomicAdd(&nsb, 1);
      sblk[pz] = (u16)i;
    }
  }
  __syncthreads();
  const int ns = nsb;
  for (int i0 = 0; i0 < ns; i0 += 16) {
    int ib = i0 + (t >> 4);
    if (ib < ns) {
      int b = sblk[ib];
      int off = b * 64 + (t & 15) * 4;
      float4 v = *(const float4*)(p + off);
      float vv[4] = {v.x, v.y, v.z, v.w};
      int c0 = seg * SEG_SZ + off;
#pragma unroll
      for (int e = 0; e < 4; e++) {
        if (vv[e] >= cutval) {
          u64 key = (((u64)flip32(vv[e])) << 32) | (unsigned)(~(unsigned)(c0 + e));
          int pz = atomicAdd(&lcnt, 1);
          if (pz < 2048) lbuf[pz] = key;
        }
      }
    }
  }
  __syncthreads();
  int n = lcnt < 2048 ? lcnt : 2048;
  if (t == 0) gbase = atomicAdd(&row_cnt[r], n);
  __syncthreads();
  const int gb = gbase;
  u64* crow = cand_row + (size_t)r * ROWCAP;
  for (int i = t; i < n; i += 256) {
    int gp = gb + i;
    if (gp < ROWCAP) crow[gp] = lbuf[i];
  }

  const long long b = (long long)r * MEM_N + (long long)seg * SEG_SZ - 1;
  for (int i = t; i < 8192; i += 256) {
    long long k4 = b + 4LL * i;
    if (k4 < 0) continue;
    float s = keys[k4];
    float4 v = *(const float4*)(keys + k4 + 1);
    float4 o;
    o.x = s; o.y = v.x; o.z = v.y; o.w = v.z;
    *(float4*)(keys_out + k4) = o;
  }
  if (r == 0 && seg == 0 && t == 0) {
    keys_out[0] = keys[0]; keys_out[1] = keys[1]; keys_out[2] = keys[2];
  }
}

// ---- sweep (LARGE): sparse filter + fused age/vals init ----
__global__ __launch_bounds__(256) void k_sweep_s(
    const float* __restrict__ scores, const float* __restrict__ cut_row,
    const u16* __restrict__ rowmax, u64* __restrict__ cand_row,
    int* __restrict__ row_cnt, const float* __restrict__ age,
    const int* __restrict__ values, float* __restrict__ age_out,
    float* __restrict__ vals_out) {
  __shared__ u64 lbuf[2048];
  __shared__ u16 sblk[512];
  __shared__ int lcnt, nsb, gbase;
  const int seg = blockIdx.x, r = blockIdx.y, t = threadIdx.x;
  if (t == 0) { lcnt = 0; nsb = 0; }
  // fused age/vals init: block lid covers 128 elements
  {
    int lid = r * NSEG + seg;  // 0..2047
    if (t < 32) {
      int g = lid * 128 + t * 4;
      float4 a = *(const float4*)(age + g);
      int4 vvv = *(const int4*)(values + g);
      float4 ao = {a.x + 1.0f, a.y + 1.0f, a.z + 1.0f, a.w + 1.0f};
      float4 vo = {(float)vvv.x, (float)vvv.y, (float)vvv.z, (float)vvv.w};
      *(float4*)(age_out + g) = ao;
      *(float4*)(vals_out + g) = vo;
    }
  }
  __syncthreads();
  const float cutval = cut_row[r];
  const float* p = scores + (size_t)r * MEM_N + (size_t)seg * SEG_SZ;
  const u16* rm = rowmax + (size_t)r * 4096 + seg * 512;
#pragma unroll
  for (int i2 = 0; i2 < 2; i2++) {
    int i = t * 2 + i2;
    if (bf16_f32(rm[i]) >= cutval) {
      int pz = atomicAdd(&nsb, 1);
      sblk[pz] = (u16)i;
    }
  }
  __syncthreads();
  const int ns = nsb;
  for (int i0 = 0; i0 < ns; i0 += 16) {
    int ib = i0 + (t >> 4);
    if (ib < ns) {
      int b = sblk[ib];
      int off = b * 64 + (t & 15) * 4;
      float4 v = *(const float4*)(p + off);
      float vv[4] = {v.x, v.y, v.z, v.w};
      int c0 = seg * SEG_SZ + off;
#pragma unroll
      for (int e = 0; e < 4; e++) {
        if (vv[e] >= cutval) {
          u64 key = (((u64)flip32(vv[e])) << 32) | (unsigned)(~(unsigned)(c0 + e));
          int pz = atomicAdd(&lcnt, 1);
          if (pz < 2048) lbuf[pz] = key;
        }
      }
    }
  }
  __syncthreads();
  int n = lcnt < 2048 ? lcnt : 2048;
  if (t == 0) gbase = atomicAdd(&row_cnt[r], n);
  __syncthreads();
  const int gb = gbase;
  u64* crow = cand_row + (size_t)r * ROWCAP;
  for (int i = t; i < n; i += 256) {
    int gp = gb + i;
    if (gp < ROWCAP) crow[gp] = lbuf[i];
  }
}

// ---- top-k finalize: sort + softmax + loss + yhat + reset + correct-update ----
__global__ __launch_bounds__(256) void k_topk2(
    const u64* __restrict__ cand_row, const int* __restrict__ row_cnt,
    const int* __restrict__ values, const int* __restrict__ yv,
    const float* __restrict__ keys, const float* __restrict__ q,
    float* __restrict__ out, float* __restrict__ loss_arr,
    int* __restrict__ corr, float* __restrict__ age_out,
    float* __restrict__ keys_out) {
  __shared__ u64 buf[ROWCAP];
  __shared__ float red[256];
  __shared__ float wred[4][4];
  const int r = blockIdx.x, t = threadIdx.x;
  if (r == 255 && t == 32) {
    const long long N = (long long)MEM_N * DIM;
    keys_out[N - 1] = keys[N - 1];  // SMALL: required; LARGE: redundant-correct
  }
  int cnt = row_cnt[r];
  cnt = cnt < ROWCAP ? cnt : ROWCAP;
  int S = 256;
  while (S < cnt) S <<= 1;
  const u64* src = cand_row + (size_t)r * ROWCAP;
  for (int i = t; i < S; i += 256) buf[i] = (i < cnt) ? src[i] : 0ULL;
  __syncthreads();
  bitonic_desc(buf, S, t);

  u64 mykey = buf[t];
  int midx = (int)(~(unsigned)(mykey & 0xFFFFFFFFull));
  float msc = unflip32((unsigned)(mykey >> 32));
  int yr = yv[r];
  float mask = (values[midx] == yr) ? 1.0f : 0.0f;
  float mtop = unflip32((unsigned)(buf[0] >> 32));
  int i0 = (int)(~(unsigned)(buf[0] & 0xFFFFFFFFull));
  int vi0 = values[i0];
  bool correct = (vi0 == yr);

  // wave-parallel reductions: sum(e), max(msc*mask), max(msc*(1-mask)), sum(mask)
  float e = expf(msc - mtop);  // TEMP == 1.0
  float vsum = e, vpos = msc * mask, vneg = msc * (1.0f - mask), vmsk = mask;
#pragma unroll
  for (int off = 32; off > 0; off >>= 1) {
    vsum += __shfl_xor(vsum, off);
    vpos = fmaxf(vpos, __shfl_xor(vpos, off));
    vneg = fmaxf(vneg, __shfl_xor(vneg, off));
    vmsk += __shfl_xor(vmsk, off);
  }
  const int wv = t >> 6;
  if ((t & 63) == 0) {
    wred[wv][0] = vsum; wred[wv][1] = vpos; wred[wv][2] = vneg; wred[wv][3] = vmsk;
  }
  __syncthreads();
  float denom = wred[0][0] + wred[1][0] + wred[2][0] + wred[3][0];
  float posr = fmaxf(fmaxf(wred[0][1], wred[1][1]), fmaxf(wred[2][1], wred[3][1]));
  float negr = fmaxf(fmaxf(wred[0][2], wred[1][2]), fmaxf(wred[2][2], wred[3][2]));
  float hp = (wred[0][3] + wred[1][3] + wred[2][3] + wred[3][3]) > 0.0f ? 1.0f : 0.0f;
  out[256 + r * 256 + t] = e / denom;

  if (t == 0) {
    float pos = posr * hp;
    loss_arr[r] = fmaxf(negr - pos + 0.1f, 0.0f);
    out[r] = (float)vi0;
    corr[r] = correct ? 1 : 0;
  }
  if (correct) {
    if (t == 0) age_out[i0] = 0.0f;
    float v = keys[(size_t)i0 * DIM + t] + q[r * DIM + t];
    red[t] = v * v; __syncthreads();
    for (int s = 128; s > 0; s >>= 1) { if (t < s) red[t] += red[t + s]; __syncthreads(); }
    float nrm = fmaxf(sqrtf(red[0]), 1e-12f);
    keys_out[(size_t)i0 * DIM + t] = v / nrm;
  }
}

// ---------------- age/values init (SMALL path only) ----------------
__global__ __launch_bounds__(256) void k_age(
    const float* __restrict__ age, const int* __restrict__ values,
    float* __restrict__ age_out, float* __restrict__ vals_out) {
  int i = blockIdx.x * 256 + threadIdx.x;
  age_out[i] = age[i] + 1.0f;
  vals_out[i] = (float)values[i];
}

// ---- oldest path stage 1: 64-elt group maxima of age_noisy (bf16 floored) ----
__global__ __launch_bounds__(256) void k_oldmax(
    const float* __restrict__ age_out, const float* __restrict__ un,
    u16* __restrict__ old_max) {
  const int t = threadIdx.x, bid = blockIdx.x;
  int g = bid * 1024 + t * 4;
  float4 a = *(const float4*)(age_out + g);
  float4 n4 = *(const float4*)(un + g);
  float m = a.x + (2.0f * n4.x - 1.0f) * 8.0f;
  m = fmaxf(m, a.y + (2.0f * n4.y - 1.0f) * 8.0f);
  m = fmaxf(m, a.z + (2.0f * n4.z - 1.0f) * 8.0f);
  m = fmaxf(m, a.w + (2.0f * n4.w - 1.0f) * 8.0f);
#pragma unroll
  for (int mk = 1; mk <= 8; mk <<= 1) m = fmaxf(m, __shfl_xor(m, mk));
  if ((t & 15) == 0) old_max[bid * 16 + (t >> 4)] = bf16_floor(m);
}

// ---- oldest path stage 2: filtered sweep of age_noisy ----
__global__ __launch_bounds__(256) void k_oldsweep(
    const float* __restrict__ age_out, const float* __restrict__ un,
    const float* __restrict__ old_cut, u64* __restrict__ obuf,
    int* __restrict__ ocnt) {
  const int t = threadIdx.x, bid = blockIdx.x;
  int g = bid * 1024 + t * 4;
  const float cut = *old_cut;
  float4 a = *(const float4*)(age_out + g);
  float4 n4 = *(const float4*)(un + g);
  float av[4] = {a.x, a.y, a.z, a.w};
  float nv[4] = {n4.x, n4.y, n4.z, n4.w};
#pragma unroll
  for (int e = 0; e < 4; e++) {
    float v = av[e] + (2.0f * nv[e] - 1.0f) * 8.0f;
    if (v >= cut) {
      u64 k = (((u64)flip32(v)) << 32) | (unsigned)(~(unsigned)(g + e));
      int p = atomicAdd(ocnt, 1);
      if (p < OCAP) obuf[p] = k;
    }
  }
}

// ---- oldest path stage 3: sort survivors, dest assignment, loss mean ----
__global__ __launch_bounds__(256) void k_oldB(
    const u64* __restrict__ obuf, const int* __restrict__ ocnt,
    const int* __restrict__ corr, const float* __restrict__ loss_arr,
    int* __restrict__ dest, float* __restrict__ out_loss) {
  __shared__ u64 cand[OCAP];
  __shared__ int olds[256];
  __shared__ int pre[256];
  __shared__ float red[256];
  const int t = threadIdx.x;
  int n = *ocnt;
  n = n < OCAP ? n : OCAP;
  int S = 256;
  while (S < n) S <<= 1;
  for (int i = t; i < S; i += 256) cand[i] = (i < n) ? obuf[i] : 0ULL;
  __syncthreads();
  bitonic_desc(cand, S, t);
  olds[t] = (int)(~(unsigned)(cand[t] & 0xFFFFFFFFull));
  int inc = corr[t] ? 0 : 1;
  pre[t] = inc;
  __syncthreads();
  for (int off = 1; off < 256; off <<= 1) {
    int v = (t >= off) ? pre[t - off] : 0;
    __syncthreads();
    pre[t] += v;
    __syncthreads();
  }
  int rank = pre[t] - 1;
  dest[t] = inc ? olds[rank] : -1;
  red[t] = loss_arr[t]; __syncthreads();
  for (int s = 128; s > 0; s >>= 1) { if (t < s) red[t] += red[t + s]; __syncthreads(); }
  if (t == 0) *out_loss = red[0] * (1.0f / 256.0f);
}

// ---------------- incorrect-row scatter ----------------
__global__ __launch_bounds__(256) void k_incorrect(
    const int* __restrict__ dest, const float* __restrict__ q,
    const int* __restrict__ yv, float* __restrict__ keys_out,
    float* __restrict__ vals_out, float* __restrict__ age_out) {
  const int r = blockIdx.x;
  int d = dest[r];
  if (d < 0) return;
  const int t = threadIdx.x;
  keys_out[(size_t)d * DIM + t] = q[r * DIM + t];
  if (t == 0) {
    vals_out[d] = (float)yv[r];
    age_out[d] = 0.0f;
  }
}

extern "C" void kernel_launch(void* const* d_in, const int* in_sizes, int n_in,
                              void* d_out, int out_size, void* d_ws, size_t ws_size,
                              hipStream_t stream) {
  const float* x = (const float*)d_in[0];
  const int* y = (const int*)d_in[1];
  const float* W = (const float*)d_in[2];
  const float* b = (const float*)d_in[3];
  const float* keys = (const float*)d_in[4];
  const int* values = (const int*)d_in[5];
  const float* age = (const float*)d_in[6];
  const float* un = (const float*)d_in[7];
  float* out = (float*)d_out;

  char* ws = (char*)d_ws;
  float* q = (float*)ws;                             // 256 KB
  u16* ap_hi = (u16*)(ws + 262144);                  // 128 KB
  u16* ap_lo = (u16*)(ws + 393216);                  // 128 KB
  float* loss_arr = (float*)(ws + 524288);           // 1 KB
  int* corr = (int*)(ws + 525312);                   // 1 KB
  u64* obuf = (u64*)(ws + 527360);                   // 32 KB (OCAP u64)
  int* dest = (int*)(ws + 560128);                   // 1 KB
  int* row_cnt = (int*)(ws + 561152);                // 1 KB
  float* cut_row = (float*)(ws + 562176);            // 1 KB
  u16* old_max = (u16*)(ws + 563200);                // 8 KB (4096 u16)
  float* old_cut = (float*)(ws + 571392);            // 4 B
  int* ocnt = (int*)(ws + 571648);                   // 4 B
  u64* cand_row = (u64*)(ws + 1048576);              // 4 MB (256 x ROWCAP)

  // d_out layout (floats): yhat[256] | softmax[65536] | loss[1] | keys[67108864]
  //                        | values[262144] | age[262144]
  const size_t LOSS_OFF = 65792, KEYS_OFF = 65793, VALS_OFF = 67174657,
               AGE_OFF = 67436801;
  float* keys_out = out + KEYS_OFF;
  float* vals_out = out + VALS_OFF;
  float* age_out = out + AGE_OFF;

  const size_t NEED_LARGE = 8388608ull + 268435456ull;  // rowmax_ws + scores_ws
  const bool large = (ws_size >= NEED_LARGE);

  k_query<<<dim3(256), dim3(256), 0, stream>>>(x, W, b, q, ap_hi, ap_lo, row_cnt, ocnt);
  if (large) {
    u16* rowmax = (u16*)(ws + 6291456);      // 2 MB at ws+6MB
    float* scores = (float*)(ws + 8388608);  // 256 MB at ws+8MB
    k_gemm_f<<<dim3(2048), dim3(512), 0, stream>>>(ap_hi, ap_lo, keys, scores, rowmax, keys_out);
    k_cut<<<dim3(256), dim3(256), 0, stream>>>(rowmax, cut_row, KSEL_SCORES);
    k_sweep_s<<<dim3(NSEG, 256), dim3(256), 0, stream>>>(scores, cut_row, rowmax, cand_row, row_cnt,
                                                         age, values, age_out, vals_out);
  } else {
    float* scores = out + 65792;           // 256 MB scratch over loss+keys region
    u16* rowmax = (u16*)(out + 67174656);  // 2 MB over last-key+values+age
    k_gemm<<<dim3(2048), dim3(512), 0, stream>>>(ap_hi, ap_lo, keys, scores, rowmax);
    k_cut<<<dim3(256), dim3(256), 0, stream>>>(rowmax, cut_row, KSEL_SCORES);
    k_sweep<<<dim3(NSEG, 256), dim3(256), 0, stream>>>(scores, cut_row, rowmax, keys, cand_row, row_cnt, keys_out);
    k_age<<<dim3(1024), dim3(256), 0, stream>>>(age, values, age_out, vals_out);
  }
  k_topk2<<<dim3(256), dim3(256), 0, stream>>>(cand_row, row_cnt, values, y, keys, q,
                                               out, loss_arr, corr, age_out, keys_out);
  k_oldmax<<<dim3(256), dim3(256), 0, stream>>>(age_out, un, old_max);
  k_cut<<<dim3(1), dim3(256), 0, stream>>>(old_max, old_cut, 256);
  k_oldsweep<<<dim3(256), dim3(256), 0, stream>>>(age_out, un, old_cut, obuf, ocnt);
  k_oldB<<<dim3(1), dim3(256), 0, stream>>>(obuf, ocnt, corr, loss_arr, dest, out + LOSS_OFF);
  k_incorrect<<<dim3(256), dim3(256), 0, stream>>>(dest, q, y, keys_out, vals_out, age_out);
}

// Round 21
// 368.468 us; speedup vs baseline: 1.1903x; 1.0285x over previous
//
#include <hip/hip_runtime.h>

#define MEM_N 262144
#define DIM 256
#define NBATCH 256
#define OCAP 4096
#define NSEG 8
#define SEG_SZ 32768
#define ROWCAP 2048
#define KSEL_SCORES 320
#define BPAGE 528  // u16 per LDS page (1056B): 8-bank skew between kq pages

typedef __attribute__((ext_vector_type(8))) short short8;
typedef __attribute__((ext_vector_type(4))) float f32x4;
typedef unsigned long long u64;
typedef unsigned short u16;

__device__ __forceinline__ u16 bf16_rne(float f) {
  unsigned u = __builtin_bit_cast(unsigned, f);
  u += 0x7FFFu + ((u >> 16) & 1u);
  return (u16)(u >> 16);
}
__device__ __forceinline__ float bf16_f32(u16 h) {
  unsigned u = ((unsigned)h) << 16;
  return __builtin_bit_cast(float, u);
}
__device__ __forceinline__ u16 bf16_floor(float f) {
  unsigned u = __builtin_bit_cast(unsigned, f);
  u16 h = (u16)(u >> 16);
  if ((u & 0x80000000u) && (u & 0xFFFFu)) h++;
  return h;
}
__device__ __forceinline__ unsigned flip32(float f) {
  unsigned u = __builtin_bit_cast(unsigned, f);
  return u ^ ((unsigned)((int)u >> 31) | 0x80000000u);
}
__device__ __forceinline__ float unflip32(unsigned k) {
  unsigned u = (k & 0x80000000u) ? (k ^ 0x80000000u) : ~k;
  return __builtin_bit_cast(float, u);
}
__device__ __forceinline__ u16 flip16(u16 b) {
  return (b & 0x8000u) ? (u16)~b : (u16)(b | 0x8000u);
}
__device__ __forceinline__ u16 unflip16(u16 f) {
  return (f & 0x8000u) ? (u16)(f ^ 0x8000u) : (u16)~f;
}
__device__ __forceinline__ void nt_store4(float4 v, float* p) {
  f32x4 x = {v.x, v.y, v.z, v.w};
  __builtin_nontemporal_store(x, (f32x4*)p);
}

// ---------------- query = normalize(x @ W^T + b), + packed-A emit ----------------
__global__ __launch_bounds__(256) void k_query(
    const float* __restrict__ x, const float* __restrict__ W,
    const float* __restrict__ b, float* __restrict__ q,
    u16* __restrict__ ap_hi, u16* __restrict__ ap_lo, int* __restrict__ row_cnt,
    int* __restrict__ ocnt) {
  __shared__ float Wt[256][36];
  __shared__ float xs[256];
  __shared__ float red[256];
  const int r = blockIdx.x, t = threadIdx.x;
  if (t == 0) row_cnt[r] = 0;
  if (r == 0 && t == 0) *ocnt = 0;
  xs[t] = x[r * DIM + t];
  float acc = b[t];
  for (int k0 = 0; k0 < DIM; k0 += 32) {
    __syncthreads();
#pragma unroll
    for (int i = 0; i < 8; i++) {
      int f = i * 256 + t;
      int j = f >> 3, c = (f & 7) * 4;
      *(float4*)&Wt[j][c] = *(const float4*)&W[j * DIM + k0 + c];
    }
    __syncthreads();
#pragma unroll
    for (int c = 0; c < 32; c++) acc = fmaf(xs[k0 + c], Wt[t][c], acc);
  }
  red[t] = acc * acc;
  __syncthreads();
  for (int s = 128; s > 0; s >>= 1) {
    if (t < s) red[t] += red[t + s];
    __syncthreads();
  }
  float nrm = fmaxf(sqrtf(red[0]), 1e-12f);
  float qv = acc / nrm;
  q[r * DIM + t] = qv;
  u16 h = bf16_rne(qv);
  u16 lo = bf16_rne(qv - bf16_f32(h));
  // packed MFMA A-fragment layout: [r16][kstep][lane][j]
  int r16 = r >> 4, s = t >> 5, hi = (t >> 3) & 3, j = t & 7;
  int l = hi * 16 + (r & 15);
  size_t off = ((size_t)(r16 * 8 + s) * 64 + l) * 8 + j;
  ap_hi[off] = h;
  ap_lo[off] = lo;
}

// --- variant A (SMALL ws): scores to out-region scratch; keys copy left to sweep ---
__global__ __launch_bounds__(512, 4) void k_gemm(
    const u16* __restrict__ ap_hi, const u16* __restrict__ ap_lo,
    const float* __restrict__ keys, float* __restrict__ scores,
    u16* __restrict__ rowmax) {
  __shared__ __align__(16) unsigned char smem[67584];
  u16* Bf = (u16*)smem;
  const int t = threadIdx.x;
  const int cb = blockIdx.x;
  const int slot0 = cb * 128;
  const int w = t >> 6, l = t & 63;
  const int wm = w & 3, wn = w >> 2;
  const int lrow = l & 15, lq = l >> 4;
  const int srow = t >> 2, sk = t & 3;
  const float* kp = keys + (size_t)(slot0 + srow) * DIM + sk * 8;
  const int sbase = (srow >> 6) * (16 * BPAGE);
  const int scol = srow & 63;

  f32x4 acc[4][4];
#pragma unroll
  for (int i = 0; i < 4; ++i)
#pragma unroll
    for (int j = 0; j < 4; ++j) acc[i][j] = f32x4{0.f, 0.f, 0.f, 0.f};

  {
    float4 va[4][2];
#pragma unroll
    for (int j = 0; j < 4; j++) {
      va[j][0] = *(const float4*)(kp + j * 32);
      va[j][1] = *(const float4*)(kp + j * 32 + 4);
    }
#pragma unroll
    for (int j = 0; j < 4; j++) {
      float f0[8] = {va[j][0].x, va[j][0].y, va[j][0].z, va[j][0].w,
                     va[j][1].x, va[j][1].y, va[j][1].z, va[j][1].w};
      uint4 pk;
      unsigned* pw = (unsigned*)&pk;
#pragma unroll
      for (int i = 0; i < 4; i++)
        pw[i] = (unsigned)bf16_rne(f0[2 * i]) | ((unsigned)bf16_rne(f0[2 * i + 1]) << 16);
      *(uint4*)&Bf[sbase + (j * 4 + sk) * BPAGE + scol * 8] = pk;
    }
  }
  __syncthreads();
#pragma unroll
  for (int ksl = 0; ksl < 4; ksl++) {
    short8 bh[4], ah[4], al[4];
#pragma unroll
    for (int nf = 0; nf < 4; nf++)
      bh[nf] = *(const short8*)(&Bf[wn * (16 * BPAGE) + (ksl * 4 + lq) * BPAGE + (nf * 16 + lrow) * 8]);
#pragma unroll
    for (int mf = 0; mf < 4; mf++) {
      size_t ab = ((size_t)((wm * 4 + mf) * 8 + ksl) * 64 + l) * 8;
      ah[mf] = *(const short8*)(ap_hi + ab);
      al[mf] = *(const short8*)(ap_lo + ab);
    }
#pragma unroll
    for (int mf = 0; mf < 4; mf++)
#pragma unroll
      for (int nf = 0; nf < 4; nf++) {
        acc[mf][nf] = __builtin_amdgcn_mfma_f32_16x16x32_bf16(al[mf], bh[nf], acc[mf][nf], 0, 0, 0);
        acc[mf][nf] = __builtin_amdgcn_mfma_f32_16x16x32_bf16(ah[mf], bh[nf], acc[mf][nf], 0, 0, 0);
      }
  }
  float4 vb[4][2];
#pragma unroll
  for (int j = 0; j < 4; j++) {
    vb[j][0] = *(const float4*)(kp + 128 + j * 32);
    vb[j][1] = *(const float4*)(kp + 128 + j * 32 + 4);
  }
  __syncthreads();
#pragma unroll
  for (int j = 0; j < 4; j++) {
    float f0[8] = {vb[j][0].x, vb[j][0].y, vb[j][0].z, vb[j][0].w,
                   vb[j][1].x, vb[j][1].y, vb[j][1].z, vb[j][1].w};
    uint4 pk;
    unsigned* pw = (unsigned*)&pk;
#pragma unroll
    for (int i = 0; i < 4; i++)
      pw[i] = (unsigned)bf16_rne(f0[2 * i]) | ((unsigned)bf16_rne(f0[2 * i + 1]) << 16);
    *(uint4*)&Bf[sbase + (j * 4 + sk) * BPAGE + scol * 8] = pk;
  }
  __syncthreads();
#pragma unroll
  for (int ksl = 0; ksl < 4; ksl++) {
    short8 bh[4], ah[4], al[4];
#pragma unroll
    for (int nf = 0; nf < 4; nf++)
      bh[nf] = *(const short8*)(&Bf[wn * (16 * BPAGE) + (ksl * 4 + lq) * BPAGE + (nf * 16 + lrow) * 8]);
#pragma unroll
    for (int mf = 0; mf < 4; mf++) {
      size_t ab = ((size_t)((wm * 4 + mf) * 8 + 4 + ksl) * 64 + l) * 8;
      ah[mf] = *(const short8*)(ap_hi + ab);
      al[mf] = *(const short8*)(ap_lo + ab);
    }
#pragma unroll
    for (int mf = 0; mf < 4; mf++)
#pragma unroll
      for (int nf = 0; nf < 4; nf++) {
        acc[mf][nf] = __builtin_amdgcn_mfma_f32_16x16x32_bf16(al[mf], bh[nf], acc[mf][nf], 0, 0, 0);
        acc[mf][nf] = __builtin_amdgcn_mfma_f32_16x16x32_bf16(ah[mf], bh[nf], acc[mf][nf], 0, 0, 0);
      }
  }

#pragma unroll
  for (int mf = 0; mf < 4; mf++)
#pragma unroll
    for (int j = 0; j < 4; j++) {
      float m = fmaxf(fmaxf(acc[mf][0][j], acc[mf][1][j]),
                      fmaxf(acc[mf][2][j], acc[mf][3][j]));
#pragma unroll
      for (int mk = 1; mk <= 8; mk <<= 1) m = fmaxf(m, __shfl_xor(m, mk));
      if ((l & 15) == 0) {
        int row = wm * 64 + mf * 16 + lq * 4 + j;
        rowmax[(size_t)row * 4096 + cb * 2 + wn] = bf16_floor(m);
      }
    }

  float* trb = (float*)smem;
#pragma unroll
  for (int rd = 0; rd < 2; rd++) {
    __syncthreads();
#pragma unroll
    for (int hh = 0; hh < 2; hh++) {
      int mf = rd * 2 + hh;
      float* tr2 = trb + (hh * 8 + w) * 1056;
#pragma unroll
      for (int nf = 0; nf < 4; nf++)
#pragma unroll
        for (int j = 0; j < 4; j++)
          tr2[(lq * 4 + j) * 66 + nf * 16 + lrow] = acc[mf][nf][j];
    }
    __syncthreads();
#pragma unroll
    for (int hh = 0; hh < 2; hh++) {
      int mf = rd * 2 + hh;
      float* tr2 = trb + (hh * 8 + w) * 1056;
#pragma unroll
      for (int it = 0; it < 4; it++) {
        float4 vv = *(float4*)&tr2[(it * 4 + lq) * 66 + 4 * lrow];
        size_t row = (size_t)(wm * 64 + mf * 16 + it * 4 + lq);
        nt_store4(vv, &scores[row * MEM_N + slot0 + wn * 64 + 4 * lrow]);
      }
    }
  }
}

// --- variant B (LARGE ws): scores to ws (nontemporal) + aligned coalesced
//     keys copy via L2-hot re-read (store-aligned recombination) ---
__global__ __launch_bounds__(512, 4) void k_gemm_f(
    const u16* __restrict__ ap_hi, const u16* __restrict__ ap_lo,
    const float* __restrict__ keys, float* __restrict__ scores,
    u16* __restrict__ rowmax, float* __restrict__ keys_out) {
  __shared__ __align__(16) unsigned char smem[67584];
  u16* Bf = (u16*)smem;
  const int t = threadIdx.x;
  const int cb = blockIdx.x;
  const int slot0 = cb * 128;
  const int w = t >> 6, l = t & 63;
  const int wm = w & 3, wn = w >> 2;
  const int lrow = l & 15, lq = l >> 4;
  const int srow = t >> 2, sk = t & 3;
  const float* kp = keys + (size_t)(slot0 + srow) * DIM + sk * 8;
  const int sbase = (srow >> 6) * (16 * BPAGE);
  const int scol = srow & 63;

  f32x4 acc[4][4];
#pragma unroll
  for (int i = 0; i < 4; ++i)
#pragma unroll
    for (int j = 0; j < 4; ++j) acc[i][j] = f32x4{0.f, 0.f, 0.f, 0.f};

  {
    float4 va[4][2];
#pragma unroll
    for (int j = 0; j < 4; j++) {
      va[j][0] = *(const float4*)(kp + j * 32);
      va[j][1] = *(const float4*)(kp + j * 32 + 4);
    }
#pragma unroll
    for (int j = 0; j < 4; j++) {
      float f0[8] = {va[j][0].x, va[j][0].y, va[j][0].z, va[j][0].w,
                     va[j][1].x, va[j][1].y, va[j][1].z, va[j][1].w};
      uint4 pk;
      unsigned* pw = (unsigned*)&pk;
#pragma unroll
      for (int i = 0; i < 4; i++)
        pw[i] = (unsigned)bf16_rne(f0[2 * i]) | ((unsigned)bf16_rne(f0[2 * i + 1]) << 16);
      *(uint4*)&Bf[sbase + (j * 4 + sk) * BPAGE + scol * 8] = pk;
    }
  }
  __syncthreads();
#pragma unroll
  for (int ksl = 0; ksl < 4; ksl++) {
    short8 bh[4], ah[4], al[4];
#pragma unroll
    for (int nf = 0; nf < 4; nf++)
      bh[nf] = *(const short8*)(&Bf[wn * (16 * BPAGE) + (ksl * 4 + lq) * BPAGE + (nf * 16 + lrow) * 8]);
#pragma unroll
    for (int mf = 0; mf < 4; mf++) {
      size_t ab = ((size_t)((wm * 4 + mf) * 8 + ksl) * 64 + l) * 8;
      ah[mf] = *(const short8*)(ap_hi + ab);
      al[mf] = *(const short8*)(ap_lo + ab);
    }
#pragma unroll
    for (int mf = 0; mf < 4; mf++)
#pragma unroll
      for (int nf = 0; nf < 4; nf++) {
        acc[mf][nf] = __builtin_amdgcn_mfma_f32_16x16x32_bf16(al[mf], bh[nf], acc[mf][nf], 0, 0, 0);
        acc[mf][nf] = __builtin_amdgcn_mfma_f32_16x16x32_bf16(ah[mf], bh[nf], acc[mf][nf], 0, 0, 0);
      }
  }
  float4 vb[4][2];
#pragma unroll
  for (int j = 0; j < 4; j++) {
    vb[j][0] = *(const float4*)(kp + 128 + j * 32);
    vb[j][1] = *(const float4*)(kp + 128 + j * 32 + 4);
  }
  // aligned coalesced keys copy for this block's 128 rows (32768 floats,
  // L2-hot re-read). keys_out[k4] with k4 % 4 == 3 is 16B-aligned.
  // Block covers flat [cb*32768 - 1, cb*32768 + 32766]; next block starts
  // at +32767; element N-1 patched in k_topk2.
  {
    const long long bbase = (long long)cb * 32768 - 1;
    for (int i = t; i < 8192; i += 512) {
      long long k4 = bbase + 4LL * i;
      if (k4 >= 0) {
        float s0 = keys[k4];
        float4 v = *(const float4*)(keys + k4 + 1);
        float4 o;
        o.x = s0; o.y = v.x; o.z = v.y; o.w = v.z;
        *(float4*)(keys_out + k4) = o;
      } else {
        keys_out[0] = keys[0]; keys_out[1] = keys[1]; keys_out[2] = keys[2];
      }
    }
  }
  __syncthreads();
#pragma unroll
  for (int j = 0; j < 4; j++) {
    float f0[8] = {vb[j][0].x, vb[j][0].y, vb[j][0].z, vb[j][0].w,
                   vb[j][1].x, vb[j][1].y, vb[j][1].z, vb[j][1].w};
    uint4 pk;
    unsigned* pw = (unsigned*)&pk;
#pragma unroll
    for (int i = 0; i < 4; i++)
      pw[i] = (unsigned)bf16_rne(f0[2 * i]) | ((unsigned)bf16_rne(f0[2 * i + 1]) << 16);
    *(uint4*)&Bf[sbase + (j * 4 + sk) * BPAGE + scol * 8] = pk;
  }
  __syncthreads();
#pragma unroll
  for (int ksl = 0; ksl < 4; ksl++) {
    short8 bh[4], ah[4], al[4];
#pragma unroll
    for (int nf = 0; nf < 4; nf++)
      bh[nf] = *(const short8*)(&Bf[wn * (16 * BPAGE) + (ksl * 4 + lq) * BPAGE + (nf * 16 + lrow) * 8]);
#pragma unroll
    for (int mf = 0; mf < 4; mf++) {
      size_t ab = ((size_t)((wm * 4 + mf) * 8 + 4 + ksl) * 64 + l) * 8;
      ah[mf] = *(const short8*)(ap_hi + ab);
      al[mf] = *(const short8*)(ap_lo + ab);
    }
#pragma unroll
    for (int mf = 0; mf < 4; mf++)
#pragma unroll
      for (int nf = 0; nf < 4; nf++) {
        acc[mf][nf] = __builtin_amdgcn_mfma_f32_16x16x32_bf16(al[mf], bh[nf], acc[mf][nf], 0, 0, 0);
        acc[mf][nf] = __builtin_amdgcn_mfma_f32_16x16x32_bf16(ah[mf], bh[nf], acc[mf][nf], 0, 0, 0);
      }
  }

#pragma unroll
  for (int mf = 0; mf < 4; mf++)
#pragma unroll
    for (int j = 0; j < 4; j++) {
      float m = fmaxf(fmaxf(acc[mf][0][j], acc[mf][1][j]),
                      fmaxf(acc[mf][2][j], acc[mf][3][j]));
#pragma unroll
      for (int mk = 1; mk <= 8; mk <<= 1) m = fmaxf(m, __shfl_xor(m, mk));
      if ((l & 15) == 0) {
        int row = wm * 64 + mf * 16 + lq * 4 + j;
        rowmax[(size_t)row * 4096 + cb * 2 + wn] = bf16_floor(m);
      }
    }

  float* trb = (float*)smem;
#pragma unroll
  for (int rd = 0; rd < 2; rd++) {
    __syncthreads();
#pragma unroll
    for (int hh = 0; hh < 2; hh++) {
      int mf = rd * 2 + hh;
      float* tr2 = trb + (hh * 8 + w) * 1056;
#pragma unroll
      for (int nf = 0; nf < 4; nf++)
#pragma unroll
        for (int j = 0; j < 4; j++)
          tr2[(lq * 4 + j) * 66 + nf * 16 + lrow] = acc[mf][nf][j];
    }
    __syncthreads();
#pragma unroll
    for (int hh = 0; hh < 2; hh++) {
      int mf = rd * 2 + hh;
      float* tr2 = trb + (hh * 8 + w) * 1056;
#pragma unroll
      for (int it = 0; it < 4; it++) {
        float4 vv = *(float4*)&tr2[(it * 4 + lq) * 66 + 4 * lrow];
        size_t row = (size_t)(wm * 64 + mf * 16 + it * 4 + lq);
        nt_store4(vv, &scores[row * MEM_N + slot0 + wn * 64 + 4 * lrow]);
      }
    }
  }
}

// ---- cutoff = exact ksel-th largest of 4096 bf16 group-maxima (per block-row) ----
__global__ __launch_bounds__(256) void k_cut(
    const u16* __restrict__ rowmax, float* __restrict__ cut_row, int ksel) {
  __shared__ int h[256];
  __shared__ int Bsh, Lsh;
  const int r = blockIdx.x, t = threadIdx.x;
  const u16* rm = rowmax + (size_t)r * 4096;
  uint4 a0 = *(const uint4*)(rm + t * 16);
  uint4 a1 = *(const uint4*)(rm + t * 16 + 8);
  u16 f[16];
  unsigned aw[8] = {a0.x, a0.y, a0.z, a0.w, a1.x, a1.y, a1.z, a1.w};
#pragma unroll
  for (int i = 0; i < 8; i++) {
    f[2 * i] = flip16((u16)(aw[i] & 0xFFFFu));
    f[2 * i + 1] = flip16((u16)(aw[i] >> 16));
  }
  h[t] = 0;
  __syncthreads();
#pragma unroll
  for (int i = 0; i < 16; i++) atomicAdd(&h[f[i] >> 8], 1);
  __syncthreads();
  for (int off = 1; off < 256; off <<= 1) {
    int v = (t + off < 256) ? h[t + off] : 0;
    __syncthreads();
    h[t] += v;
    __syncthreads();
  }
  if (h[t] >= ksel && (t == 255 || h[t + 1] < ksel)) Bsh = t;
  __syncthreads();
  const int B = Bsh;
  const int above = (B == 255) ? 0 : h[B + 1];
  __syncthreads();
  h[t] = 0;
  __syncthreads();
#pragma unroll
  for (int i = 0; i < 16; i++)
    if ((f[i] >> 8) == B) atomicAdd(&h[f[i] & 255], 1);
  __syncthreads();
  for (int off = 1; off < 256; off <<= 1) {
    int v = (t + off < 256) ? h[t + off] : 0;
    __syncthreads();
    h[t] += v;
    __syncthreads();
  }
  if (above + h[t] >= ksel && (t == 255 || above + h[t + 1] < ksel)) Lsh = t;
  __syncthreads();
  if (t == 0) {
    u16 fs = (u16)((B << 8) | Lsh);
    cut_row[r] = bf16_f32(unflip16(fs));
  }
}

// ---------------- sort helper ----------------
__device__ void bitonic_desc(u64* a, int N, int t) {
  for (int k = 2; k <= N; k <<= 1) {
    for (int j = k >> 1; j > 0; j >>= 1) {
      for (int i = t; i < N; i += 256) {
        int p = i ^ j;
        if (p > i) {
          u64 xv = a[i], yv = a[p];
          bool up = ((i & k) == 0);
          if (up ? (xv < yv) : (xv > yv)) { a[i] = yv; a[p] = xv; }
        }
      }
      __syncthreads();
    }
  }
}

// ---- sweep (SMALL): rowmax-guided sparse filter + keys copy ----
__global__ __launch_bounds__(256) void k_sweep(
    const float* __restrict__ scores, const float* __restrict__ cut_row,
    const u16* __restrict__ rowmax, const float* __restrict__ keys,
    u64* __restrict__ cand_row, int* __restrict__ row_cnt,
    float* __restrict__ keys_out) {
  __shared__ u64 lbuf[2048];
  __shared__ u16 sblk[512];
  __shared__ int lcnt, nsb, gbase;
  const int seg = blockIdx.x, r = blockIdx.y, t = threadIdx.x;
  if (t == 0) { lcnt = 0; nsb = 0; }
  __syncthreads();
  const float cutval = cut_row[r];
  const float* p = scores + (size_t)r * MEM_N + (size_t)seg * SEG_SZ;

  const u16* rm = rowmax + (size_t)r * 4096 + seg * 512;
#pragma unroll
  for (int i2 = 0; i2 < 2; i2++) {
    int i = t * 2 + i2;
    if (bf16_f32(rm[i]) >= cutval) {
      int pz = atomicAdd(&nsb, 1);
      sblk[pz] = (u16)i;
    }
  }
  __syncthreads();
  const int ns = nsb;
  for (int i0 = 0; i0 < ns; i0 += 16) {
    int ib = i0 + (t >> 4);
    if (ib < ns) {
      int b = sblk[ib];
      int off = b * 64 + (t & 15) * 4;
      float4 v = *(const float4*)(p + off);
      float vv[4] = {v.x, v.y, v.z, v.w};
      int c0 = seg * SEG_SZ + off;
#pragma unroll
      for (int e = 0; e < 4; e++) {
        if (vv[e] >= cutval) {
          u64 key = (((u64)flip32(vv[e])) << 32) | (unsigned)(~(unsigned)(c0 + e));
          int pz = atomicAdd(&lcnt, 1);
          if (pz < 2048) lbuf[pz] = key;
        }
      }
    }
  }
  __syncthreads();
  int n = lcnt < 2048 ? lcnt : 2048;
  if (t == 0) gbase = atomicAdd(&row_cnt[r], n);
  __syncthreads();
  const int gb = gbase;
  u64* crow = cand_row + (size_t)r * ROWCAP;
  for (int i = t; i < n; i += 256) {
    int gp = gb + i;
    if (gp < ROWCAP) crow[gp] = lbuf[i];
  }

  const long long b = (long long)r * MEM_N + (long long)seg * SEG_SZ - 1;
  for (int i = t; i < 8192; i += 256) {
    long long k4 = b + 4LL * i;
    if (k4 < 0) continue;
    float s = keys[k4];
    float4 v = *(const float4*)(keys + k4 + 1);
    float4 o;
    o.x = s; o.y = v.x; o.z = v.y; o.w = v.z;
    *(float4*)(keys_out + k4) = o;
  }
  if (r == 0 && seg == 0 && t == 0) {
    keys_out[0] = keys[0]; keys_out[1] = keys[1]; keys_out[2] = keys[2];
  }
}

// ---- sweep (LARGE): sparse filter + fused age/vals init ----
__global__ __launch_bounds__(256) void k_sweep_s(
    const float* __restrict__ scores, const float* __restrict__ cut_row,
    const u16* __restrict__ rowmax, u64* __restrict__ cand_row,
    int* __restrict__ row_cnt, const float* __restrict__ age,
    const int* __restrict__ values, float* __restrict__ age_out,
    float* __restrict__ vals_out) {
  __shared__ u64 lbuf[2048];
  __shared__ u16 sblk[512];
  __shared__ int lcnt, nsb, gbase;
  const int seg = blockIdx.x, r = blockIdx.y, t = threadIdx.x;
  if (t == 0) { lcnt = 0; nsb = 0; }
  // fused age/vals init: block lid covers 128 elements
  {
    int lid = r * NSEG + seg;  // 0..2047
    if (t < 32) {
      int g = lid * 128 + t * 4;
      float4 a = *(const float4*)(age + g);
      int4 vvv = *(const int4*)(values + g);
      float4 ao = {a.x + 1.0f, a.y + 1.0f, a.z + 1.0f, a.w + 1.0f};
      float4 vo = {(float)vvv.x, (float)vvv.y, (float)vvv.z, (float)vvv.w};
      *(float4*)(age_out + g) = ao;
      *(float4*)(vals_out + g) = vo;
    }
  }
  __syncthreads();
  const float cutval = cut_row[r];
  const float* p = scores + (size_t)r * MEM_N + (size_t)seg * SEG_SZ;
  const u16* rm = rowmax + (size_t)r * 4096 + seg * 512;
#pragma unroll
  for (int i2 = 0; i2 < 2; i2++) {
    int i = t * 2 + i2;
    if (bf16_f32(rm[i]) >= cutval) {
      int pz = atomicAdd(&nsb, 1);
      sblk[pz] = (u16)i;
    }
  }
  __syncthreads();
  const int ns = nsb;
  for (int i0 = 0; i0 < ns; i0 += 16) {
    int ib = i0 + (t >> 4);
    if (ib < ns) {
      int b = sblk[ib];
      int off = b * 64 + (t & 15) * 4;
      float4 v = *(const float4*)(p + off);
      float vv[4] = {v.x, v.y, v.z, v.w};
      int c0 = seg * SEG_SZ + off;
#pragma unroll
      for (int e = 0; e < 4; e++) {
        if (vv[e] >= cutval) {
          u64 key = (((u64)flip32(vv[e])) << 32) | (unsigned)(~(unsigned)(c0 + e));
          int pz = atomicAdd(&lcnt, 1);
          if (pz < 2048) lbuf[pz] = key;
        }
      }
    }
  }
  __syncthreads();
  int n = lcnt < 2048 ? lcnt : 2048;
  if (t == 0) gbase = atomicAdd(&row_cnt[r], n);
  __syncthreads();
  const int gb = gbase;
  u64* crow = cand_row + (size_t)r * ROWCAP;
  for (int i = t; i < n; i += 256) {
    int gp = gb + i;
    if (gp < ROWCAP) crow[gp] = lbuf[i];
  }
}

// ---- top-k finalize: sort + softmax + loss + yhat + reset + correct-update ----
__global__ __launch_bounds__(256) void k_topk2(
    const u64* __restrict__ cand_row, const int* __restrict__ row_cnt,
    const int* __restrict__ values, const int* __restrict__ yv,
    const float* __restrict__ keys, const float* __restrict__ q,
    float* __restrict__ out, float* __restrict__ loss_arr,
    int* __restrict__ corr, float* __restrict__ age_out,
    float* __restrict__ keys_out) {
  __shared__ u64 buf[ROWCAP];
  __shared__ float red[256];
  __shared__ float wred[4][4];
  const int r = blockIdx.x, t = threadIdx.x;
  if (r == 255 && t == 32) {
    const long long N = (long long)MEM_N * DIM;
    keys_out[N - 1] = keys[N - 1];  // last element not covered by either copy path
  }
  int cnt = row_cnt[r];
  cnt = cnt < ROWCAP ? cnt : ROWCAP;
  int S = 256;
  while (S < cnt) S <<= 1;
  const u64* src = cand_row + (size_t)r * ROWCAP;
  for (int i = t; i < S; i += 256) buf[i] = (i < cnt) ? src[i] : 0ULL;
  __syncthreads();
  bitonic_desc(buf, S, t);

  u64 mykey = buf[t];
  int midx = (int)(~(unsigned)(mykey & 0xFFFFFFFFull));
  float msc = unflip32((unsigned)(mykey >> 32));
  int yr = yv[r];
  float mask = (values[midx] == yr) ? 1.0f : 0.0f;
  float mtop = unflip32((unsigned)(buf[0] >> 32));
  int i0 = (int)(~(unsigned)(buf[0] & 0xFFFFFFFFull));
  int vi0 = values[i0];
  bool correct = (vi0 == yr);

  // wave-parallel reductions: sum(e), max(msc*mask), max(msc*(1-mask)), sum(mask)
  float e = expf(msc - mtop);  // TEMP == 1.0
  float vsum = e, vpos = msc * mask, vneg = msc * (1.0f - mask), vmsk = mask;
#pragma unroll
  for (int off = 32; off > 0; off >>= 1) {
    vsum += __shfl_xor(vsum, off);
    vpos = fmaxf(vpos, __shfl_xor(vpos, off));
    vneg = fmaxf(vneg, __shfl_xor(vneg, off));
    vmsk += __shfl_xor(vmsk, off);
  }
  const int wv = t >> 6;
  if ((t & 63) == 0) {
    wred[wv][0] = vsum; wred[wv][1] = vpos; wred[wv][2] = vneg; wred[wv][3] = vmsk;
  }
  __syncthreads();
  float denom = wred[0][0] + wred[1][0] + wred[2][0] + wred[3][0];
  float posr = fmaxf(fmaxf(wred[0][1], wred[1][1]), fmaxf(wred[2][1], wred[3][1]));
  float negr = fmaxf(fmaxf(wred[0][2], wred[1][2]), fmaxf(wred[2][2], wred[3][2]));
  float hp = (wred[0][3] + wred[1][3] + wred[2][3] + wred[3][3]) > 0.0f ? 1.0f : 0.0f;
  out[256 + r * 256 + t] = e / denom;

  if (t == 0) {
    float pos = posr * hp;
    loss_arr[r] = fmaxf(negr - pos + 0.1f, 0.0f);
    out[r] = (float)vi0;
    corr[r] = correct ? 1 : 0;
  }
  if (correct) {
    if (t == 0) age_out[i0] = 0.0f;
    float v = keys[(size_t)i0 * DIM + t] + q[r * DIM + t];
    red[t] = v * v; __syncthreads();
    for (int s = 128; s > 0; s >>= 1) { if (t < s) red[t] += red[t + s]; __syncthreads(); }
    float nrm = fmaxf(sqrtf(red[0]), 1e-12f);
    keys_out[(size_t)i0 * DIM + t] = v / nrm;
  }
}

// ---------------- age/values init (SMALL path only) ----------------
__global__ __launch_bounds__(256) void k_age(
    const float* __restrict__ age, const int* __restrict__ values,
    float* __restrict__ age_out, float* __restrict__ vals_out) {
  int i = blockIdx.x * 256 + threadIdx.x;
  age_out[i] = age[i] + 1.0f;
  vals_out[i] = (float)values[i];
}

// ---- oldest path stage 1: 64-elt group maxima of age_noisy (bf16 floored) ----
__global__ __launch_bounds__(256) void k_oldmax(
    const float* __restrict__ age_out, const float* __restrict__ un,
    u16* __restrict__ old_max) {
  const int t = threadIdx.x, bid = blockIdx.x;
  int g = bid * 1024 + t * 4;
  float4 a = *(const float4*)(age_out + g);
  float4 n4 = *(const float4*)(un + g);
  float m = a.x + (2.0f * n4.x - 1.0f) * 8.0f;
  m = fmaxf(m, a.y + (2.0f * n4.y - 1.0f) * 8.0f);
  m = fmaxf(m, a.z + (2.0f * n4.z - 1.0f) * 8.0f);
  m = fmaxf(m, a.w + (2.0f * n4.w - 1.0f) * 8.0f);
#pragma unroll
  for (int mk = 1; mk <= 8; mk <<= 1) m = fmaxf(m, __shfl_xor(m, mk));
  if ((t & 15) == 0) old_max[bid * 16 + (t >> 4)] = bf16_floor(m);
}

// ---- oldest path stage 2: filtered sweep of age_noisy ----
__global__ __launch_bounds__(256) void k_oldsweep(
    const float* __restrict__ age_out, const float* __restrict__ un,
    const float* __restrict__ old_cut, u64* __restrict__ obuf,
    int* __restrict__ ocnt) {
  const int t = threadIdx.x, bid = blockIdx.x;
  int g = bid * 1024 + t * 4;
  const float cut = *old_cut;
  float4 a = *(const float4*)(age_out + g);
  float4 n4 = *(const float4*)(un + g);
  float av[4] = {a.x, a.y, a.z, a.w};
  float nv[4] = {n4.x, n4.y, n4.z, n4.w};
#pragma unroll
  for (int e = 0; e < 4; e++) {
    float v = av[e] + (2.0f * nv[e] - 1.0f) * 8.0f;
    if (v >= cut) {
      u64 k = (((u64)flip32(v)) << 32) | (unsigned)(~(unsigned)(g + e));
      int p = atomicAdd(ocnt, 1);
      if (p < OCAP) obuf[p] = k;
    }
  }
}

// ---- oldest path stage 3: sort survivors, dest assignment, loss mean ----
__global__ __launch_bounds__(256) void k_oldB(
    const u64* __restrict__ obuf, const int* __restrict__ ocnt,
    const int* __restrict__ corr, const float* __restrict__ loss_arr,
    int* __restrict__ dest, float* __restrict__ out_loss) {
  __shared__ u64 cand[OCAP];
  __shared__ int olds[256];
  __shared__ int pre[256];
  __shared__ float red[256];
  const int t = threadIdx.x;
  int n = *ocnt;
  n = n < OCAP ? n : OCAP;
  int S = 256;
  while (S < n) S <<= 1;
  for (int i = t; i < S; i += 256) cand[i] = (i < n) ? obuf[i] : 0ULL;
  __syncthreads();
  bitonic_desc(cand, S, t);
  olds[t] = (int)(~(unsigned)(cand[t] & 0xFFFFFFFFull));
  int inc = corr[t] ? 0 : 1;
  pre[t] = inc;
  __syncthreads();
  for (int off = 1; off < 256; off <<= 1) {
    int v = (t >= off) ? pre[t - off] : 0;
    __syncthreads();
    pre[t] += v;
    __syncthreads();
  }
  int rank = pre[t] - 1;
  dest[t] = inc ? olds[rank] : -1;
  red[t] = loss_arr[t]; __syncthreads();
  for (int s = 128; s > 0; s >>= 1) { if (t < s) red[t] += red[t + s]; __syncthreads(); }
  if (t == 0) *out_loss = red[0] * (1.0f / 256.0f);
}

// ---------------- incorrect-row scatter ----------------
__global__ __launch_bounds__(256) void k_incorrect(
    const int* __restrict__ dest, const float* __restrict__ q,
    const int* __restrict__ yv, float* __restrict__ keys_out,
    float* __restrict__ vals_out, float* __restrict__ age_out) {
  const int r = blockIdx.x;
  int d = dest[r];
  if (d < 0) return;
  const int t = threadIdx.x;
  keys_out[(size_t)d * DIM + t] = q[r * DIM + t];
  if (t == 0) {
    vals_out[d] = (float)yv[r];
    age_out[d] = 0.0f;
  }
}

extern "C" void kernel_launch(void* const* d_in, const int* in_sizes, int n_in,
                              void* d_out, int out_size, void* d_ws, size_t ws_size,
                              hipStream_t stream) {
  const float* x = (const float*)d_in[0];
  const int* y = (const int*)d_in[1];
  const float* W = (const float*)d_in[2];
  const float* b = (const float*)d_in[3];
  const float* keys = (const float*)d_in[4];
  const int* values = (const int*)d_in[5];
  const float* age = (const float*)d_in[6];
  const float* un = (const float*)d_in[7];
  float* out = (float*)d_out;

  char* ws = (char*)d_ws;
  float* q = (float*)ws;                             // 256 KB
  u16* ap_hi = (u16*)(ws + 262144);                  // 128 KB
  u16* ap_lo = (u16*)(ws + 393216);                  // 128 KB
  float* loss_arr = (float*)(ws + 524288);           // 1 KB
  int* corr = (int*)(ws + 525312);                   // 1 KB
  u64* obuf = (u64*)(ws + 527360);                   // 32 KB (OCAP u64)
  int* dest = (int*)(ws + 560128);                   // 1 KB
  int* row_cnt = (int*)(ws + 561152);                // 1 KB
  float* cut_row = (float*)(ws + 562176);            // 1 KB
  u16* old_max = (u16*)(ws + 563200);                // 8 KB (4096 u16)
  float* old_cut = (float*)(ws + 571392);            // 4 B
  int* ocnt = (int*)(ws + 571648);                   // 4 B
  u64* cand_row = (u64*)(ws + 1048576);              // 4 MB (256 x ROWCAP)

  // d_out layout (floats): yhat[256] | softmax[65536] | loss[1] | keys[67108864]
  //                        | values[262144] | age[262144]
  const size_t LOSS_OFF = 65792, KEYS_OFF = 65793, VALS_OFF = 67174657,
               AGE_OFF = 67436801;
  float* keys_out = out + KEYS_OFF;
  float* vals_out = out + VALS_OFF;
  float* age_out = out + AGE_OFF;

  const size_t NEED_LARGE = 8388608ull + 268435456ull;  // rowmax_ws + scores_ws
  const bool large = (ws_size >= NEED_LARGE);

  k_query<<<dim3(256), dim3(256), 0, stream>>>(x, W, b, q, ap_hi, ap_lo, row_cnt, ocnt);
  if (large) {
    u16* rowmax = (u16*)(ws + 6291456);      // 2 MB at ws+6MB
    float* scores = (float*)(ws + 8388608);  // 256 MB at ws+8MB
    k_gemm_f<<<dim3(2048), dim3(512), 0, stream>>>(ap_hi, ap_lo, keys, scores, rowmax, keys_out);
    k_cut<<<dim3(256), dim3(256), 0, stream>>>(rowmax, cut_row, KSEL_SCORES);
    k_sweep_s<<<dim3(NSEG, 256), dim3(256), 0, stream>>>(scores, cut_row, rowmax, cand_row, row_cnt,
                                                         age, values, age_out, vals_out);
  } else {
    float* scores = out + 65792;           // 256 MB scratch over loss+keys region
    u16* rowmax = (u16*)(out + 67174656);  // 2 MB over last-key+values+age
    k_gemm<<<dim3(2048), dim3(512), 0, stream>>>(ap_hi, ap_lo, keys, scores, rowmax);
    k_cut<<<dim3(256), dim3(256), 0, stream>>>(rowmax, cut_row, KSEL_SCORES);
    k_sweep<<<dim3(NSEG, 256), dim3(256), 0, stream>>>(scores, cut_row, rowmax, keys, cand_row, row_cnt, keys_out);
    k_age<<<dim3(1024), dim3(256), 0, stream>>>(age, values, age_out, vals_out);
  }
  k_topk2<<<dim3(256), dim3(256), 0, stream>>>(cand_row, row_cnt, values, y, keys, q,
                                               out, loss_arr, corr, age_out, keys_out);
  k_oldmax<<<dim3(256), dim3(256), 0, stream>>>(age_out, un, old_max);
  k_cut<<<dim3(1), dim3(256), 0, stream>>>(old_max, old_cut, 256);
  k_oldsweep<<<dim3(256), dim3(256), 0, stream>>>(age_out, un, old_cut, obuf, ocnt);
  k_oldB<<<dim3(1), dim3(256), 0, stream>>>(obuf, ocnt, corr, loss_arr, dest, out + LOSS_OFF);
  k_incorrect<<<dim3(256), dim3(256), 0, stream>>>(dest, q, y, keys_out, vals_out, age_out);
}

// Round 22
// 367.333 us; speedup vs baseline: 1.1940x; 1.0031x over previous
//
#include <hip/hip_runtime.h>

#define MEM_N 262144
#define DIM 256
#define NBATCH 256
#define OCAP 4096
#define NSEG 8
#define SEG_SZ 32768
#define ROWCAP 2048
#define KSEL_SCORES 320
#define BPAGE 528  // u16 per LDS page (1056B): 8-bank skew between kq pages

typedef __attribute__((ext_vector_type(8))) short short8;
typedef __attribute__((ext_vector_type(4))) float f32x4;
typedef unsigned long long u64;
typedef unsigned short u16;

__device__ __forceinline__ u16 bf16_rne(float f) {
  unsigned u = __builtin_bit_cast(unsigned, f);
  u += 0x7FFFu + ((u >> 16) & 1u);
  return (u16)(u >> 16);
}
__device__ __forceinline__ float bf16_f32(u16 h) {
  unsigned u = ((unsigned)h) << 16;
  return __builtin_bit_cast(float, u);
}
__device__ __forceinline__ u16 bf16_floor(float f) {
  unsigned u = __builtin_bit_cast(unsigned, f);
  u16 h = (u16)(u >> 16);
  if ((u & 0x80000000u) && (u & 0xFFFFu)) h++;
  return h;
}
__device__ __forceinline__ unsigned flip32(float f) {
  unsigned u = __builtin_bit_cast(unsigned, f);
  return u ^ ((unsigned)((int)u >> 31) | 0x80000000u);
}
__device__ __forceinline__ float unflip32(unsigned k) {
  unsigned u = (k & 0x80000000u) ? (k ^ 0x80000000u) : ~k;
  return __builtin_bit_cast(float, u);
}
__device__ __forceinline__ u16 flip16(u16 b) {
  return (b & 0x8000u) ? (u16)~b : (u16)(b | 0x8000u);
}
__device__ __forceinline__ u16 unflip16(u16 f) {
  return (f & 0x8000u) ? (u16)(f ^ 0x8000u) : (u16)~f;
}
__device__ __forceinline__ void nt_store4(float4 v, float* p) {
  f32x4 x = {v.x, v.y, v.z, v.w};
  __builtin_nontemporal_store(x, (f32x4*)p);
}

// ---------------- query = normalize(x @ W^T + b), + packed-A emit ----------------
__global__ __launch_bounds__(256) void k_query(
    const float* __restrict__ x, const float* __restrict__ W,
    const float* __restrict__ b, float* __restrict__ q,
    u16* __restrict__ ap_hi, u16* __restrict__ ap_lo, int* __restrict__ row_cnt,
    int* __restrict__ ocnt) {
  __shared__ float Wt[256][36];
  __shared__ float xs[256];
  __shared__ float red[256];
  const int r = blockIdx.x, t = threadIdx.x;
  if (t == 0) row_cnt[r] = 0;
  if (r == 0 && t == 0) *ocnt = 0;
  xs[t] = x[r * DIM + t];
  float acc = b[t];
  for (int k0 = 0; k0 < DIM; k0 += 32) {
    __syncthreads();
#pragma unroll
    for (int i = 0; i < 8; i++) {
      int f = i * 256 + t;
      int j = f >> 3, c = (f & 7) * 4;
      *(float4*)&Wt[j][c] = *(const float4*)&W[j * DIM + k0 + c];
    }
    __syncthreads();
#pragma unroll
    for (int c = 0; c < 32; c++) acc = fmaf(xs[k0 + c], Wt[t][c], acc);
  }
  red[t] = acc * acc;
  __syncthreads();
  for (int s = 128; s > 0; s >>= 1) {
    if (t < s) red[t] += red[t + s];
    __syncthreads();
  }
  float nrm = fmaxf(sqrtf(red[0]), 1e-12f);
  float qv = acc / nrm;
  q[r * DIM + t] = qv;
  u16 h = bf16_rne(qv);
  u16 lo = bf16_rne(qv - bf16_f32(h));
  // packed MFMA A-fragment layout: [r16][kstep][lane][j]
  int r16 = r >> 4, s = t >> 5, hi = (t >> 3) & 3, j = t & 7;
  int l = hi * 16 + (r & 15);
  size_t off = ((size_t)(r16 * 8 + s) * 64 + l) * 8 + j;
  ap_hi[off] = h;
  ap_lo[off] = lo;
}

// --- variant A (SMALL ws): scores to out-region scratch; keys copy left to sweep ---
__global__ __launch_bounds__(512, 4) void k_gemm(
    const u16* __restrict__ ap_hi, const u16* __restrict__ ap_lo,
    const float* __restrict__ keys, float* __restrict__ scores,
    u16* __restrict__ rowmax) {
  __shared__ __align__(16) unsigned char smem[67584];
  u16* Bf = (u16*)smem;
  const int t = threadIdx.x;
  const int cb = blockIdx.x;
  const int slot0 = cb * 128;
  const int w = t >> 6, l = t & 63;
  const int wm = w & 3, wn = w >> 2;
  const int lrow = l & 15, lq = l >> 4;
  const int srow = t >> 2, sk = t & 3;
  const float* kp = keys + (size_t)(slot0 + srow) * DIM + sk * 8;
  const int sbase = (srow >> 6) * (16 * BPAGE);
  const int scol = srow & 63;

  f32x4 acc[4][4];
#pragma unroll
  for (int i = 0; i < 4; ++i)
#pragma unroll
    for (int j = 0; j < 4; ++j) acc[i][j] = f32x4{0.f, 0.f, 0.f, 0.f};

  {
    float4 va[4][2];
#pragma unroll
    for (int j = 0; j < 4; j++) {
      va[j][0] = *(const float4*)(kp + j * 32);
      va[j][1] = *(const float4*)(kp + j * 32 + 4);
    }
#pragma unroll
    for (int j = 0; j < 4; j++) {
      float f0[8] = {va[j][0].x, va[j][0].y, va[j][0].z, va[j][0].w,
                     va[j][1].x, va[j][1].y, va[j][1].z, va[j][1].w};
      uint4 pk;
      unsigned* pw = (unsigned*)&pk;
#pragma unroll
      for (int i = 0; i < 4; i++)
        pw[i] = (unsigned)bf16_rne(f0[2 * i]) | ((unsigned)bf16_rne(f0[2 * i + 1]) << 16);
      *(uint4*)&Bf[sbase + (j * 4 + sk) * BPAGE + scol * 8] = pk;
    }
  }
  __syncthreads();
#pragma unroll
  for (int ksl = 0; ksl < 4; ksl++) {
    short8 bh[4], ah[4], al[4];
#pragma unroll
    for (int nf = 0; nf < 4; nf++)
      bh[nf] = *(const short8*)(&Bf[wn * (16 * BPAGE) + (ksl * 4 + lq) * BPAGE + (nf * 16 + lrow) * 8]);
#pragma unroll
    for (int mf = 0; mf < 4; mf++) {
      size_t ab = ((size_t)((wm * 4 + mf) * 8 + ksl) * 64 + l) * 8;
      ah[mf] = *(const short8*)(ap_hi + ab);
      al[mf] = *(const short8*)(ap_lo + ab);
    }
#pragma unroll
    for (int mf = 0; mf < 4; mf++)
#pragma unroll
      for (int nf = 0; nf < 4; nf++) {
        acc[mf][nf] = __builtin_amdgcn_mfma_f32_16x16x32_bf16(al[mf], bh[nf], acc[mf][nf], 0, 0, 0);
        acc[mf][nf] = __builtin_amdgcn_mfma_f32_16x16x32_bf16(ah[mf], bh[nf], acc[mf][nf], 0, 0, 0);
      }
  }
  float4 vb[4][2];
#pragma unroll
  for (int j = 0; j < 4; j++) {
    vb[j][0] = *(const float4*)(kp + 128 + j * 32);
    vb[j][1] = *(const float4*)(kp + 128 + j * 32 + 4);
  }
  __syncthreads();
#pragma unroll
  for (int j = 0; j < 4; j++) {
    float f0[8] = {vb[j][0].x, vb[j][0].y, vb[j][0].z, vb[j][0].w,
                   vb[j][1].x, vb[j][1].y, vb[j][1].z, vb[j][1].w};
    uint4 pk;
    unsigned* pw = (unsigned*)&pk;
#pragma unroll
    for (int i = 0; i < 4; i++)
      pw[i] = (unsigned)bf16_rne(f0[2 * i]) | ((unsigned)bf16_rne(f0[2 * i + 1]) << 16);
    *(uint4*)&Bf[sbase + (j * 4 + sk) * BPAGE + scol * 8] = pk;
  }
  __syncthreads();
#pragma unroll
  for (int ksl = 0; ksl < 4; ksl++) {
    short8 bh[4], ah[4], al[4];
#pragma unroll
    for (int nf = 0; nf < 4; nf++)
      bh[nf] = *(const short8*)(&Bf[wn * (16 * BPAGE) + (ksl * 4 + lq) * BPAGE + (nf * 16 + lrow) * 8]);
#pragma unroll
    for (int mf = 0; mf < 4; mf++) {
      size_t ab = ((size_t)((wm * 4 + mf) * 8 + 4 + ksl) * 64 + l) * 8;
      ah[mf] = *(const short8*)(ap_hi + ab);
      al[mf] = *(const short8*)(ap_lo + ab);
    }
#pragma unroll
    for (int mf = 0; mf < 4; mf++)
#pragma unroll
      for (int nf = 0; nf < 4; nf++) {
        acc[mf][nf] = __builtin_amdgcn_mfma_f32_16x16x32_bf16(al[mf], bh[nf], acc[mf][nf], 0, 0, 0);
        acc[mf][nf] = __builtin_amdgcn_mfma_f32_16x16x32_bf16(ah[mf], bh[nf], acc[mf][nf], 0, 0, 0);
      }
  }

#pragma unroll
  for (int mf = 0; mf < 4; mf++)
#pragma unroll
    for (int j = 0; j < 4; j++) {
      float m = fmaxf(fmaxf(acc[mf][0][j], acc[mf][1][j]),
                      fmaxf(acc[mf][2][j], acc[mf][3][j]));
#pragma unroll
      for (int mk = 1; mk <= 8; mk <<= 1) m = fmaxf(m, __shfl_xor(m, mk));
      if ((l & 15) == 0) {
        int row = wm * 64 + mf * 16 + lq * 4 + j;
        rowmax[(size_t)row * 4096 + cb * 2 + wn] = bf16_floor(m);
      }
    }

  float* trb = (float*)smem;
#pragma unroll
  for (int rd = 0; rd < 2; rd++) {
    __syncthreads();
#pragma unroll
    for (int hh = 0; hh < 2; hh++) {
      int mf = rd * 2 + hh;
      float* tr2 = trb + (hh * 8 + w) * 1056;
#pragma unroll
      for (int nf = 0; nf < 4; nf++)
#pragma unroll
        for (int j = 0; j < 4; j++)
          tr2[(lq * 4 + j) * 66 + nf * 16 + lrow] = acc[mf][nf][j];
    }
    __syncthreads();
#pragma unroll
    for (int hh = 0; hh < 2; hh++) {
      int mf = rd * 2 + hh;
      float* tr2 = trb + (hh * 8 + w) * 1056;
#pragma unroll
      for (int it = 0; it < 4; it++) {
        float4 vv = *(float4*)&tr2[(it * 4 + lq) * 66 + 4 * lrow];
        size_t row = (size_t)(wm * 64 + mf * 16 + it * 4 + lq);
        nt_store4(vv, &scores[row * MEM_N + slot0 + wn * 64 + 4 * lrow]);
      }
    }
  }
}

// --- variant B (LARGE ws): scores to ws (NT) + aligned coalesced keys copy
//     (NT stores; write-once stream) via L2-hot re-read ---
__global__ __launch_bounds__(512, 4) void k_gemm_f(
    const u16* __restrict__ ap_hi, const u16* __restrict__ ap_lo,
    const float* __restrict__ keys, float* __restrict__ scores,
    u16* __restrict__ rowmax, float* __restrict__ keys_out) {
  __shared__ __align__(16) unsigned char smem[67584];
  u16* Bf = (u16*)smem;
  const int t = threadIdx.x;
  const int cb = blockIdx.x;
  const int slot0 = cb * 128;
  const int w = t >> 6, l = t & 63;
  const int wm = w & 3, wn = w >> 2;
  const int lrow = l & 15, lq = l >> 4;
  const int srow = t >> 2, sk = t & 3;
  const float* kp = keys + (size_t)(slot0 + srow) * DIM + sk * 8;
  const int sbase = (srow >> 6) * (16 * BPAGE);
  const int scol = srow & 63;

  f32x4 acc[4][4];
#pragma unroll
  for (int i = 0; i < 4; ++i)
#pragma unroll
    for (int j = 0; j < 4; ++j) acc[i][j] = f32x4{0.f, 0.f, 0.f, 0.f};

  {
    float4 va[4][2];
#pragma unroll
    for (int j = 0; j < 4; j++) {
      va[j][0] = *(const float4*)(kp + j * 32);
      va[j][1] = *(const float4*)(kp + j * 32 + 4);
    }
#pragma unroll
    for (int j = 0; j < 4; j++) {
      float f0[8] = {va[j][0].x, va[j][0].y, va[j][0].z, va[j][0].w,
                     va[j][1].x, va[j][1].y, va[j][1].z, va[j][1].w};
      uint4 pk;
      unsigned* pw = (unsigned*)&pk;
#pragma unroll
      for (int i = 0; i < 4; i++)
        pw[i] = (unsigned)bf16_rne(f0[2 * i]) | ((unsigned)bf16_rne(f0[2 * i + 1]) << 16);
      *(uint4*)&Bf[sbase + (j * 4 + sk) * BPAGE + scol * 8] = pk;
    }
  }
  __syncthreads();
#pragma unroll
  for (int ksl = 0; ksl < 4; ksl++) {
    short8 bh[4], ah[4], al[4];
#pragma unroll
    for (int nf = 0; nf < 4; nf++)
      bh[nf] = *(const short8*)(&Bf[wn * (16 * BPAGE) + (ksl * 4 + lq) * BPAGE + (nf * 16 + lrow) * 8]);
#pragma unroll
    for (int mf = 0; mf < 4; mf++) {
      size_t ab = ((size_t)((wm * 4 + mf) * 8 + ksl) * 64 + l) * 8;
      ah[mf] = *(const short8*)(ap_hi + ab);
      al[mf] = *(const short8*)(ap_lo + ab);
    }
#pragma unroll
    for (int mf = 0; mf < 4; mf++)
#pragma unroll
      for (int nf = 0; nf < 4; nf++) {
        acc[mf][nf] = __builtin_amdgcn_mfma_f32_16x16x32_bf16(al[mf], bh[nf], acc[mf][nf], 0, 0, 0);
        acc[mf][nf] = __builtin_amdgcn_mfma_f32_16x16x32_bf16(ah[mf], bh[nf], acc[mf][nf], 0, 0, 0);
      }
  }
  float4 vb[4][2];
#pragma unroll
  for (int j = 0; j < 4; j++) {
    vb[j][0] = *(const float4*)(kp + 128 + j * 32);
    vb[j][1] = *(const float4*)(kp + 128 + j * 32 + 4);
  }
  // aligned coalesced keys copy for this block's 128 rows (32768 floats,
  // L2-hot re-read; NT stores keep keys_out out of L2).
  // Block covers flat [cb*32768 - 1, cb*32768 + 32766]; element N-1 in k_topk2.
  {
    const long long bbase = (long long)cb * 32768 - 1;
    for (int i = t; i < 8192; i += 512) {
      long long k4 = bbase + 4LL * i;
      if (k4 >= 0) {
        float s0 = keys[k4];
        float4 v = *(const float4*)(keys + k4 + 1);
        float4 o;
        o.x = s0; o.y = v.x; o.z = v.y; o.w = v.z;
        nt_store4(o, keys_out + k4);
      } else {
        keys_out[0] = keys[0]; keys_out[1] = keys[1]; keys_out[2] = keys[2];
      }
    }
  }
  __syncthreads();
#pragma unroll
  for (int j = 0; j < 4; j++) {
    float f0[8] = {vb[j][0].x, vb[j][0].y, vb[j][0].z, vb[j][0].w,
                   vb[j][1].x, vb[j][1].y, vb[j][1].z, vb[j][1].w};
    uint4 pk;
    unsigned* pw = (unsigned*)&pk;
#pragma unroll
    for (int i = 0; i < 4; i++)
      pw[i] = (unsigned)bf16_rne(f0[2 * i]) | ((unsigned)bf16_rne(f0[2 * i + 1]) << 16);
    *(uint4*)&Bf[sbase + (j * 4 + sk) * BPAGE + scol * 8] = pk;
  }
  __syncthreads();
#pragma unroll
  for (int ksl = 0; ksl < 4; ksl++) {
    short8 bh[4], ah[4], al[4];
#pragma unroll
    for (int nf = 0; nf < 4; nf++)
      bh[nf] = *(const short8*)(&Bf[wn * (16 * BPAGE) + (ksl * 4 + lq) * BPAGE + (nf * 16 + lrow) * 8]);
#pragma unroll
    for (int mf = 0; mf < 4; mf++) {
      size_t ab = ((size_t)((wm * 4 + mf) * 8 + 4 + ksl) * 64 + l) * 8;
      ah[mf] = *(const short8*)(ap_hi + ab);
      al[mf] = *(const short8*)(ap_lo + ab);
    }
#pragma unroll
    for (int mf = 0; mf < 4; mf++)
#pragma unroll
      for (int nf = 0; nf < 4; nf++) {
        acc[mf][nf] = __builtin_amdgcn_mfma_f32_16x16x32_bf16(al[mf], bh[nf], acc[mf][nf], 0, 0, 0);
        acc[mf][nf] = __builtin_amdgcn_mfma_f32_16x16x32_bf16(ah[mf], bh[nf], acc[mf][nf], 0, 0, 0);
      }
  }

#pragma unroll
  for (int mf = 0; mf < 4; mf++)
#pragma unroll
    for (int j = 0; j < 4; j++) {
      float m = fmaxf(fmaxf(acc[mf][0][j], acc[mf][1][j]),
                      fmaxf(acc[mf][2][j], acc[mf][3][j]));
#pragma unroll
      for (int mk = 1; mk <= 8; mk <<= 1) m = fmaxf(m, __shfl_xor(m, mk));
      if ((l & 15) == 0) {
        int row = wm * 64 + mf * 16 + lq * 4 + j;
        rowmax[(size_t)row * 4096 + cb * 2 + wn] = bf16_floor(m);
      }
    }

  float* trb = (float*)smem;
#pragma unroll
  for (int rd = 0; rd < 2; rd++) {
    __syncthreads();
#pragma unroll
    for (int hh = 0; hh < 2; hh++) {
      int mf = rd * 2 + hh;
      float* tr2 = trb + (hh * 8 + w) * 1056;
#pragma unroll
      for (int nf = 0; nf < 4; nf++)
#pragma unroll
        for (int j = 0; j < 4; j++)
          tr2[(lq * 4 + j) * 66 + nf * 16 + lrow] = acc[mf][nf][j];
    }
    __syncthreads();
#pragma unroll
    for (int hh = 0; hh < 2; hh++) {
      int mf = rd * 2 + hh;
      float* tr2 = trb + (hh * 8 + w) * 1056;
#pragma unroll
      for (int it = 0; it < 4; it++) {
        float4 vv = *(float4*)&tr2[(it * 4 + lq) * 66 + 4 * lrow];
        size_t row = (size_t)(wm * 64 + mf * 16 + it * 4 + lq);
        nt_store4(vv, &scores[row * MEM_N + slot0 + wn * 64 + 4 * lrow]);
      }
    }
  }
}

// ---- cutoff = exact ksel-th largest of 4096 bf16 group-maxima (per block-row) ----
__global__ __launch_bounds__(256) void k_cut(
    const u16* __restrict__ rowmax, float* __restrict__ cut_row, int ksel) {
  __shared__ int h[256];
  __shared__ int Bsh, Lsh;
  const int r = blockIdx.x, t = threadIdx.x;
  const u16* rm = rowmax + (size_t)r * 4096;
  uint4 a0 = *(const uint4*)(rm + t * 16);
  uint4 a1 = *(const uint4*)(rm + t * 16 + 8);
  u16 f[16];
  unsigned aw[8] = {a0.x, a0.y, a0.z, a0.w, a1.x, a1.y, a1.z, a1.w};
#pragma unroll
  for (int i = 0; i < 8; i++) {
    f[2 * i] = flip16((u16)(aw[i] & 0xFFFFu));
    f[2 * i + 1] = flip16((u16)(aw[i] >> 16));
  }
  h[t] = 0;
  __syncthreads();
#pragma unroll
  for (int i = 0; i < 16; i++) atomicAdd(&h[f[i] >> 8], 1);
  __syncthreads();
  for (int off = 1; off < 256; off <<= 1) {
    int v = (t + off < 256) ? h[t + off] : 0;
    __syncthreads();
    h[t] += v;
    __syncthreads();
  }
  if (h[t] >= ksel && (t == 255 || h[t + 1] < ksel)) Bsh = t;
  __syncthreads();
  const int B = Bsh;
  const int above = (B == 255) ? 0 : h[B + 1];
  __syncthreads();
  h[t] = 0;
  __syncthreads();
#pragma unroll
  for (int i = 0; i < 16; i++)
    if ((f[i] >> 8) == B) atomicAdd(&h[f[i] & 255], 1);
  __syncthreads();
  for (int off = 1; off < 256; off <<= 1) {
    int v = (t + off < 256) ? h[t + off] : 0;
    __syncthreads();
    h[t] += v;
    __syncthreads();
  }
  if (above + h[t] >= ksel && (t == 255 || above + h[t + 1] < ksel)) Lsh = t;
  __syncthreads();
  if (t == 0) {
    u16 fs = (u16)((B << 8) | Lsh);
    cut_row[r] = bf16_f32(unflip16(fs));
  }
}

// ---------------- sort helper ----------------
__device__ void bitonic_desc(u64* a, int N, int t) {
  for (int k = 2; k <= N; k <<= 1) {
    for (int j = k >> 1; j > 0; j >>= 1) {
      for (int i = t; i < N; i += 256) {
        int p = i ^ j;
        if (p > i) {
          u64 xv = a[i], yv = a[p];
          bool up = ((i & k) == 0);
          if (up ? (xv < yv) : (xv > yv)) { a[i] = yv; a[p] = xv; }
        }
      }
      __syncthreads();
    }
  }
}

// ---- sweep (SMALL): rowmax-guided sparse filter + keys copy ----
__global__ __launch_bounds__(256) void k_sweep(
    const float* __restrict__ scores, const float* __restrict__ cut_row,
    const u16* __restrict__ rowmax, const float* __restrict__ keys,
    u64* __restrict__ cand_row, int* __restrict__ row_cnt,
    float* __restrict__ keys_out) {
  __shared__ u64 lbuf[2048];
  __shared__ u16 sblk[512];
  __shared__ int lcnt, nsb, gbase;
  const int seg = blockIdx.x, r = blockIdx.y, t = threadIdx.x;
  if (t == 0) { lcnt = 0; nsb = 0; }
  __syncthreads();
  const float cutval = cut_row[r];
  const float* p = scores + (size_t)r * MEM_N + (size_t)seg * SEG_SZ;

  const u16* rm = rowmax + (size_t)r * 4096 + seg * 512;
#pragma unroll
  for (int i2 = 0; i2 < 2; i2++) {
    int i = t * 2 + i2;
    if (bf16_f32(rm[i]) >= cutval) {
      int pz = atomicAdd(&nsb, 1);
      sblk[pz] = (u16)i;
    }
  }
  __syncthreads();
  const int ns = nsb;
  for (int i0 = 0; i0 < ns; i0 += 16) {
    int ib = i0 + (t >> 4);
    if (ib < ns) {
      int b = sblk[ib];
      int off = b * 64 + (t & 15) * 4;
      float4 v = *(const float4*)(p + off);
      float vv[4] = {v.x, v.y, v.z, v.w};
      int c0 = seg * SEG_SZ + off;
#pragma unroll
      for (int e = 0; e < 4; e++) {
        if (vv[e] >= cutval) {
          u64 key = (((u64)flip32(vv[e])) << 32) | (unsigned)(~(unsigned)(c0 + e));
          int pz = atomicAdd(&lcnt, 1);
          if (pz < 2048) lbuf[pz] = key;
        }
      }
    }
  }
  __syncthreads();
  int n = lcnt < 2048 ? lcnt : 2048;
  if (t == 0) gbase = atomicAdd(&row_cnt[r], n);
  __syncthreads();
  const int gb = gbase;
  u64* crow = cand_row + (size_t)r * ROWCAP;
  for (int i = t; i < n; i += 256) {
    int gp = gb + i;
    if (gp < ROWCAP) crow[gp] = lbuf[i];
  }

  const long long b = (long long)r * MEM_N + (long long)seg * SEG_SZ - 1;
  for (int i = t; i < 8192; i += 256) {
    long long k4 = b + 4LL * i;
    if (k4 < 0) continue;
    float s = keys[k4];
    float4 v = *(const float4*)(keys + k4 + 1);
    float4 o;
    o.x = s; o.y = v.x; o.z = v.y; o.w = v.z;
    *(float4*)(keys_out + k4) = o;
  }
  if (r == 0 && seg == 0 && t == 0) {
    keys_out[0] = keys[0]; keys_out[1] = keys[1]; keys_out[2] = keys[2];
  }
}

// ---- sweep (LARGE): sparse filter + fused age/vals init ----
__global__ __launch_bounds__(256) void k_sweep_s(
    const float* __restrict__ scores, const float* __restrict__ cut_row,
    const u16* __restrict__ rowmax, u64* __restrict__ cand_row,
    int* __restrict__ row_cnt, const float* __restrict__ age,
    const int* __restrict__ values, float* __restrict__ age_out,
    float* __restrict__ vals_out) {
  __shared__ u64 lbuf[2048];
  __shared__ u16 sblk[512];
  __shared__ int lcnt, nsb, gbase;
  const int seg = blockIdx.x, r = blockIdx.y, t = threadIdx.x;
  if (t == 0) { lcnt = 0; nsb = 0; }
  // fused age/vals init: block lid covers 128 elements
  {
    int lid = r * NSEG + seg;  // 0..2047
    if (t < 32) {
      int g = lid * 128 + t * 4;
      float4 a = *(const float4*)(age + g);
      int4 vvv = *(const int4*)(values + g);
      float4 ao = {a.x + 1.0f, a.y + 1.0f, a.z + 1.0f, a.w + 1.0f};
      float4 vo = {(float)vvv.x, (float)vvv.y, (float)vvv.z, (float)vvv.w};
      *(float4*)(age_out + g) = ao;
      *(float4*)(vals_out + g) = vo;
    }
  }
  __syncthreads();
  const float cutval = cut_row[r];
  const float* p = scores + (size_t)r * MEM_N + (size_t)seg * SEG_SZ;
  const u16* rm = rowmax + (size_t)r * 4096 + seg * 512;
#pragma unroll
  for (int i2 = 0; i2 < 2; i2++) {
    int i = t * 2 + i2;
    if (bf16_f32(rm[i]) >= cutval) {
      int pz = atomicAdd(&nsb, 1);
      sblk[pz] = (u16)i;
    }
  }
  __syncthreads();
  const int ns = nsb;
  for (int i0 = 0; i0 < ns; i0 += 16) {
    int ib = i0 + (t >> 4);
    if (ib < ns) {
      int b = sblk[ib];
      int off = b * 64 + (t & 15) * 4;
      float4 v = *(const float4*)(p + off);
      float vv[4] = {v.x, v.y, v.z, v.w};
      int c0 = seg * SEG_SZ + off;
#pragma unroll
      for (int e = 0; e < 4; e++) {
        if (vv[e] >= cutval) {
          u64 key = (((u64)flip32(vv[e])) << 32) | (unsigned)(~(unsigned)(c0 + e));
          int pz = atomicAdd(&lcnt, 1);
          if (pz < 2048) lbuf[pz] = key;
        }
      }
    }
  }
  __syncthreads();
  int n = lcnt < 2048 ? lcnt : 2048;
  if (t == 0) gbase = atomicAdd(&row_cnt[r], n);
  __syncthreads();
  const int gb = gbase;
  u64* crow = cand_row + (size_t)r * ROWCAP;
  for (int i = t; i < n; i += 256) {
    int gp = gb + i;
    if (gp < ROWCAP) crow[gp] = lbuf[i];
  }
}

// ---- top-k finalize: sort + softmax + loss + yhat + reset + correct-update ----
__global__ __launch_bounds__(256) void k_topk2(
    const u64* __restrict__ cand_row, const int* __restrict__ row_cnt,
    const int* __restrict__ values, const int* __restrict__ yv,
    const float* __restrict__ keys, const float* __restrict__ q,
    float* __restrict__ out, float* __restrict__ loss_arr,
    int* __restrict__ corr, float* __restrict__ age_out,
    float* __restrict__ keys_out) {
  __shared__ u64 buf[ROWCAP];
  __shared__ float red[256];
  __shared__ float wred[4][4];
  const int r = blockIdx.x, t = threadIdx.x;
  if (r == 255 && t == 32) {
    const long long N = (long long)MEM_N * DIM;
    keys_out[N - 1] = keys[N - 1];  // last element not covered by either copy path
  }
  int cnt = row_cnt[r];
  cnt = cnt < ROWCAP ? cnt : ROWCAP;
  int S = 256;
  while (S < cnt) S <<= 1;
  const u64* src = cand_row + (size_t)r * ROWCAP;
  for (int i = t; i < S; i += 256) buf[i] = (i < cnt) ? src[i] : 0ULL;
  __syncthreads();
  bitonic_desc(buf, S, t);

  u64 mykey = buf[t];
  int midx = (int)(~(unsigned)(mykey & 0xFFFFFFFFull));
  float msc = unflip32((unsigned)(mykey >> 32));
  int yr = yv[r];
  float mask = (values[midx] == yr) ? 1.0f : 0.0f;
  float mtop = unflip32((unsigned)(buf[0] >> 32));
  int i0 = (int)(~(unsigned)(buf[0] & 0xFFFFFFFFull));
  int vi0 = values[i0];
  bool correct = (vi0 == yr);

  // wave-parallel reductions: sum(e), max(msc*mask), max(msc*(1-mask)), sum(mask)
  float e = expf(msc - mtop);  // TEMP == 1.0
  float vsum = e, vpos = msc * mask, vneg = msc * (1.0f - mask), vmsk = mask;
#pragma unroll
  for (int off = 32; off > 0; off >>= 1) {
    vsum += __shfl_xor(vsum, off);
    vpos = fmaxf(vpos, __shfl_xor(vpos, off));
    vneg = fmaxf(vneg, __shfl_xor(vneg, off));
    vmsk += __shfl_xor(vmsk, off);
  }
  const int wv = t >> 6;
  if ((t & 63) == 0) {
    wred[wv][0] = vsum; wred[wv][1] = vpos; wred[wv][2] = vneg; wred[wv][3] = vmsk;
  }
  __syncthreads();
  float denom = wred[0][0] + wred[1][0] + wred[2][0] + wred[3][0];
  float posr = fmaxf(fmaxf(wred[0][1], wred[1][1]), fmaxf(wred[2][1], wred[3][1]));
  float negr = fmaxf(fmaxf(wred[0][2], wred[1][2]), fmaxf(wred[2][2], wred[3][2]));
  float hp = (wred[0][3] + wred[1][3] + wred[2][3] + wred[3][3]) > 0.0f ? 1.0f : 0.0f;
  out[256 + r * 256 + t] = e / denom;

  if (t == 0) {
    float pos = posr * hp;
    loss_arr[r] = fmaxf(negr - pos + 0.1f, 0.0f);
    out[r] = (float)vi0;
    corr[r] = correct ? 1 : 0;
  }
  if (correct) {
    if (t == 0) age_out[i0] = 0.0f;
    float v = keys[(size_t)i0 * DIM + t] + q[r * DIM + t];
    red[t] = v * v; __syncthreads();
    for (int s = 128; s > 0; s >>= 1) { if (t < s) red[t] += red[t + s]; __syncthreads(); }
    float nrm = fmaxf(sqrtf(red[0]), 1e-12f);
    keys_out[(size_t)i0 * DIM + t] = v / nrm;
  }
}

// ---------------- age/values init (SMALL path only) ----------------
__global__ __launch_bounds__(256) void k_age(
    const float* __restrict__ age, const int* __restrict__ values,
    float* __restrict__ age_out, float* __restrict__ vals_out) {
  int i = blockIdx.x * 256 + threadIdx.x;
  age_out[i] = age[i] + 1.0f;
  vals_out[i] = (float)values[i];
}

// ---- oldest path stage 1: 64-elt group maxima of age_noisy (bf16 floored) ----
__global__ __launch_bounds__(256) void k_oldmax(
    const float* __restrict__ age_out, const float* __restrict__ un,
    u16* __restrict__ old_max) {
  const int t = threadIdx.x, bid = blockIdx.x;
  int g = bid * 1024 + t * 4;
  float4 a = *(const float4*)(age_out + g);
  float4 n4 = *(const float4*)(un + g);
  float m = a.x + (2.0f * n4.x - 1.0f) * 8.0f;
  m = fmaxf(m, a.y + (2.0f * n4.y - 1.0f) * 8.0f);
  m = fmaxf(m, a.z + (2.0f * n4.z - 1.0f) * 8.0f);
  m = fmaxf(m, a.w + (2.0f * n4.w - 1.0f) * 8.0f);
#pragma unroll
  for (int mk = 1; mk <= 8; mk <<= 1) m = fmaxf(m, __shfl_xor(m, mk));
  if ((t & 15) == 0) old_max[bid * 16 + (t >> 4)] = bf16_floor(m);
}

// ---- oldest path stage 2: filtered sweep of age_noisy ----
__global__ __launch_bounds__(256) void k_oldsweep(
    const float* __restrict__ age_out, const float* __restrict__ un,
    const float* __restrict__ old_cut, u64* __restrict__ obuf,
    int* __restrict__ ocnt) {
  const int t = threadIdx.x, bid = blockIdx.x;
  int g = bid * 1024 + t * 4;
  const float cut = *old_cut;
  float4 a = *(const float4*)(age_out + g);
  float4 n4 = *(const float4*)(un + g);
  float av[4] = {a.x, a.y, a.z, a.w};
  float nv[4] = {n4.x, n4.y, n4.z, n4.w};
#pragma unroll
  for (int e = 0; e < 4; e++) {
    float v = av[e] + (2.0f * nv[e] - 1.0f) * 8.0f;
    if (v >= cut) {
      u64 k = (((u64)flip32(v)) << 32) | (unsigned)(~(unsigned)(g + e));
      int p = atomicAdd(ocnt, 1);
      if (p < OCAP) obuf[p] = k;
    }
  }
}

// ---- oldest path stage 3: sort survivors, dest assignment, loss mean ----
__global__ __launch_bounds__(256) void k_oldB(
    const u64* __restrict__ obuf, const int* __restrict__ ocnt,
    const int* __restrict__ corr, const float* __restrict__ loss_arr,
    int* __restrict__ dest, float* __restrict__ out_loss) {
  __shared__ u64 cand[OCAP];
  __shared__ int olds[256];
  __shared__ int pre[256];
  __shared__ float red[256];
  const int t = threadIdx.x;
  int n = *ocnt;
  n = n < OCAP ? n : OCAP;
  int S = 256;
  while (S < n) S <<= 1;
  for (int i = t; i < S; i += 256) cand[i] = (i < n) ? obuf[i] : 0ULL;
  __syncthreads();
  bitonic_desc(cand, S, t);
  olds[t] = (int)(~(unsigned)(cand[t] & 0xFFFFFFFFull));
  int inc = corr[t] ? 0 : 1;
  pre[t] = inc;
  __syncthreads();
  for (int off = 1; off < 256; off <<= 1) {
    int v = (t >= off) ? pre[t - off] : 0;
    __syncthreads();
    pre[t] += v;
    __syncthreads();
  }
  int rank = pre[t] - 1;
  dest[t] = inc ? olds[rank] : -1;
  red[t] = loss_arr[t]; __syncthreads();
  for (int s = 128; s > 0; s >>= 1) { if (t < s) red[t] += red[t + s]; __syncthreads(); }
  if (t == 0) *out_loss = red[0] * (1.0f / 256.0f);
}

// ---------------- incorrect-row scatter ----------------
__global__ __launch_bounds__(256) void k_incorrect(
    const int* __restrict__ dest, const float* __restrict__ q,
    const int* __restrict__ yv, float* __restrict__ keys_out,
    float* __restrict__ vals_out, float* __restrict__ age_out) {
  const int r = blockIdx.x;
  int d = dest[r];
  if (d < 0) return;
  const int t = threadIdx.x;
  keys_out[(size_t)d * DIM + t] = q[r * DIM + t];
  if (t == 0) {
    vals_out[d] = (float)yv[r];
    age_out[d] = 0.0f;
  }
}

extern "C" void kernel_launch(void* const* d_in, const int* in_sizes, int n_in,
                              void* d_out, int out_size, void* d_ws, size_t ws_size,
                              hipStream_t stream) {
  const float* x = (const float*)d_in[0];
  const int* y = (const int*)d_in[1];
  const float* W = (const float*)d_in[2];
  const float* b = (const float*)d_in[3];
  const float* keys = (const float*)d_in[4];
  const int* values = (const int*)d_in[5];
  const float* age = (const float*)d_in[6];
  const float* un = (const float*)d_in[7];
  float* out = (float*)d_out;

  char* ws = (char*)d_ws;
  float* q = (float*)ws;                             // 256 KB
  u16* ap_hi = (u16*)(ws + 262144);                  // 128 KB
  u16* ap_lo = (u16*)(ws + 393216);                  // 128 KB
  float* loss_arr = (float*)(ws + 524288);           // 1 KB
  int* corr = (int*)(ws + 525312);                   // 1 KB
  u64* obuf = (u64*)(ws + 527360);                   // 32 KB (OCAP u64)
  int* dest = (int*)(ws + 560128);                   // 1 KB
  int* row_cnt = (int*)(ws + 561152);                // 1 KB
  float* cut_row = (float*)(ws + 562176);            // 1 KB
  u16* old_max = (u16*)(ws + 563200);                // 8 KB (4096 u16)
  float* old_cut = (float*)(ws + 571392);            // 4 B
  int* ocnt = (int*)(ws + 571648);                   // 4 B
  u64* cand_row = (u64*)(ws + 1048576);              // 4 MB (256 x ROWCAP)

  // d_out layout (floats): yhat[256] | softmax[65536] | loss[1] | keys[67108864]
  //                        | values[262144] | age[262144]
  const size_t LOSS_OFF = 65792, KEYS_OFF = 65793, VALS_OFF = 67174657,
               AGE_OFF = 67436801;
  float* keys_out = out + KEYS_OFF;
  float* vals_out = out + VALS_OFF;
  float* age_out = out + AGE_OFF;

  const size_t NEED_LARGE = 8388608ull + 268435456ull;  // rowmax_ws + scores_ws
  const bool large = (ws_size >= NEED_LARGE);

  k_query<<<dim3(256), dim3(256), 0, stream>>>(x, W, b, q, ap_hi, ap_lo, row_cnt, ocnt);
  if (large) {
    u16* rowmax = (u16*)(ws + 6291456);      // 2 MB at ws+6MB
    float* scores = (float*)(ws + 8388608);  // 256 MB at ws+8MB
    k_gemm_f<<<dim3(2048), dim3(512), 0, stream>>>(ap_hi, ap_lo, keys, scores, rowmax, keys_out);
    k_cut<<<dim3(256), dim3(256), 0, stream>>>(rowmax, cut_row, KSEL_SCORES);
    k_sweep_s<<<dim3(NSEG, 256), dim3(256), 0, stream>>>(scores, cut_row, rowmax, cand_row, row_cnt,
                                                         age, values, age_out, vals_out);
  } else {
    float* scores = out + 65792;           // 256 MB scratch over loss+keys region
    u16* rowmax = (u16*)(out + 67174656);  // 2 MB over last-key+values+age
    k_gemm<<<dim3(2048), dim3(512), 0, stream>>>(ap_hi, ap_lo, keys, scores, rowmax);
    k_cut<<<dim3(256), dim3(256), 0, stream>>>(rowmax, cut_row, KSEL_SCORES);
    k_sweep<<<dim3(NSEG, 256), dim3(256), 0, stream>>>(scores, cut_row, rowmax, keys, cand_row, row_cnt, keys_out);
    k_age<<<dim3(1024), dim3(256), 0, stream>>>(age, values, age_out, vals_out);
  }
  k_topk2<<<dim3(256), dim3(256), 0, stream>>>(cand_row, row_cnt, values, y, keys, q,
                                               out, loss_arr, corr, age_out, keys_out);
  k_oldmax<<<dim3(256), dim3(256), 0, stream>>>(age_out, un, old_max);
  k_cut<<<dim3(1), dim3(256), 0, stream>>>(old_max, old_cut, 256);
  k_oldsweep<<<dim3(256), dim3(256), 0, stream>>>(age_out, un, old_cut, obuf, ocnt);
  k_oldB<<<dim3(1), dim3(256), 0, stream>>>(obuf, ocnt, corr, loss_arr, dest, out + LOSS_OFF);
  k_incorrect<<<dim3(256), dim3(256), 0, stream>>>(dest, q, y, keys_out, vals_out, age_out);
}

// Round 23
// 361.788 us; speedup vs baseline: 1.2123x; 1.0153x over previous
//
#include <hip/hip_runtime.h>

#define MEM_N 262144
#define DIM 256
#define NBATCH 256
#define OCAP 4096
#define NSEG 8
#define SEG_SZ 32768
#define ROWCAP 2048
#define KSEL_SCORES 320
#define BPAGE 528  // u16 per LDS page (1056B): 8-bank skew between kq pages

typedef __attribute__((ext_vector_type(8))) short short8;
typedef __attribute__((ext_vector_type(4))) float f32x4;
typedef unsigned long long u64;
typedef unsigned short u16;

__device__ __forceinline__ u16 bf16_rne(float f) {
  unsigned u = __builtin_bit_cast(unsigned, f);
  u += 0x7FFFu + ((u >> 16) & 1u);
  return (u16)(u >> 16);
}
__device__ __forceinline__ float bf16_f32(u16 h) {
  unsigned u = ((unsigned)h) << 16;
  return __builtin_bit_cast(float, u);
}
__device__ __forceinline__ u16 bf16_floor(float f) {
  unsigned u = __builtin_bit_cast(unsigned, f);
  u16 h = (u16)(u >> 16);
  if ((u & 0x80000000u) && (u & 0xFFFFu)) h++;
  return h;
}
__device__ __forceinline__ unsigned flip32(float f) {
  unsigned u = __builtin_bit_cast(unsigned, f);
  return u ^ ((unsigned)((int)u >> 31) | 0x80000000u);
}
__device__ __forceinline__ float unflip32(unsigned k) {
  unsigned u = (k & 0x80000000u) ? (k ^ 0x80000000u) : ~k;
  return __builtin_bit_cast(float, u);
}
__device__ __forceinline__ u16 flip16(u16 b) {
  return (b & 0x8000u) ? (u16)~b : (u16)(b | 0x8000u);
}
__device__ __forceinline__ u16 unflip16(u16 f) {
  return (f & 0x8000u) ? (u16)(f ^ 0x8000u) : (u16)~f;
}
__device__ __forceinline__ void nt_store4(float4 v, float* p) {
  f32x4 x = {v.x, v.y, v.z, v.w};
  __builtin_nontemporal_store(x, (f32x4*)p);
}

// ---------------- query = normalize(x @ W^T + b), + packed-A emit ----------------
__global__ __launch_bounds__(256) void k_query(
    const float* __restrict__ x, const float* __restrict__ W,
    const float* __restrict__ b, float* __restrict__ q,
    u16* __restrict__ ap_hi, u16* __restrict__ ap_lo, int* __restrict__ row_cnt,
    int* __restrict__ ocnt) {
  __shared__ float Wt[256][36];
  __shared__ float xs[256];
  __shared__ float red[256];
  const int r = blockIdx.x, t = threadIdx.x;
  if (t == 0) row_cnt[r] = 0;
  if (r == 0 && t == 0) *ocnt = 0;
  xs[t] = x[r * DIM + t];
  float acc = b[t];
  for (int k0 = 0; k0 < DIM; k0 += 32) {
    __syncthreads();
#pragma unroll
    for (int i = 0; i < 8; i++) {
      int f = i * 256 + t;
      int j = f >> 3, c = (f & 7) * 4;
      *(float4*)&Wt[j][c] = *(const float4*)&W[j * DIM + k0 + c];
    }
    __syncthreads();
#pragma unroll
    for (int c = 0; c < 32; c++) acc = fmaf(xs[k0 + c], Wt[t][c], acc);
  }
  red[t] = acc * acc;
  __syncthreads();
  for (int s = 128; s > 0; s >>= 1) {
    if (t < s) red[t] += red[t + s];
    __syncthreads();
  }
  float nrm = fmaxf(sqrtf(red[0]), 1e-12f);
  float qv = acc / nrm;
  q[r * DIM + t] = qv;
  u16 h = bf16_rne(qv);
  u16 lo = bf16_rne(qv - bf16_f32(h));
  // packed MFMA A-fragment layout: [r16][kstep][lane][j]
  int r16 = r >> 4, s = t >> 5, hi = (t >> 3) & 3, j = t & 7;
  int l = hi * 16 + (r & 15);
  size_t off = ((size_t)(r16 * 8 + s) * 64 + l) * 8 + j;
  ap_hi[off] = h;
  ap_lo[off] = lo;
}

// --- variant A (SMALL ws): scores to out-region scratch; keys copy left to sweep ---
__global__ __launch_bounds__(512, 4) void k_gemm(
    const u16* __restrict__ ap_hi, const u16* __restrict__ ap_lo,
    const float* __restrict__ keys, float* __restrict__ scores,
    u16* __restrict__ rowmax) {
  __shared__ __align__(16) unsigned char smem[67584];
  u16* Bf = (u16*)smem;
  const int t = threadIdx.x;
  const int cb = blockIdx.x;
  const int slot0 = cb * 128;
  const int w = t >> 6, l = t & 63;
  const int wm = w & 3, wn = w >> 2;
  const int lrow = l & 15, lq = l >> 4;
  const int srow = t >> 2, sk = t & 3;
  const float* kp = keys + (size_t)(slot0 + srow) * DIM + sk * 8;
  const int sbase = (srow >> 6) * (16 * BPAGE);
  const int scol = srow & 63;

  f32x4 acc[4][4];
#pragma unroll
  for (int i = 0; i < 4; ++i)
#pragma unroll
    for (int j = 0; j < 4; ++j) acc[i][j] = f32x4{0.f, 0.f, 0.f, 0.f};

  {
    float4 va[4][2];
#pragma unroll
    for (int j = 0; j < 4; j++) {
      va[j][0] = *(const float4*)(kp + j * 32);
      va[j][1] = *(const float4*)(kp + j * 32 + 4);
    }
#pragma unroll
    for (int j = 0; j < 4; j++) {
      float f0[8] = {va[j][0].x, va[j][0].y, va[j][0].z, va[j][0].w,
                     va[j][1].x, va[j][1].y, va[j][1].z, va[j][1].w};
      uint4 pk;
      unsigned* pw = (unsigned*)&pk;
#pragma unroll
      for (int i = 0; i < 4; i++)
        pw[i] = (unsigned)bf16_rne(f0[2 * i]) | ((unsigned)bf16_rne(f0[2 * i + 1]) << 16);
      *(uint4*)&Bf[sbase + (j * 4 + sk) * BPAGE + scol * 8] = pk;
    }
  }
  __syncthreads();
#pragma unroll
  for (int ksl = 0; ksl < 4; ksl++) {
    short8 bh[4], ah[4], al[4];
#pragma unroll
    for (int nf = 0; nf < 4; nf++)
      bh[nf] = *(const short8*)(&Bf[wn * (16 * BPAGE) + (ksl * 4 + lq) * BPAGE + (nf * 16 + lrow) * 8]);
#pragma unroll
    for (int mf = 0; mf < 4; mf++) {
      size_t ab = ((size_t)((wm * 4 + mf) * 8 + ksl) * 64 + l) * 8;
      ah[mf] = *(const short8*)(ap_hi + ab);
      al[mf] = *(const short8*)(ap_lo + ab);
    }
#pragma unroll
    for (int mf = 0; mf < 4; mf++)
#pragma unroll
      for (int nf = 0; nf < 4; nf++) {
        acc[mf][nf] = __builtin_amdgcn_mfma_f32_16x16x32_bf16(al[mf], bh[nf], acc[mf][nf], 0, 0, 0);
        acc[mf][nf] = __builtin_amdgcn_mfma_f32_16x16x32_bf16(ah[mf], bh[nf], acc[mf][nf], 0, 0, 0);
      }
  }
  float4 vb[4][2];
#pragma unroll
  for (int j = 0; j < 4; j++) {
    vb[j][0] = *(const float4*)(kp + 128 + j * 32);
    vb[j][1] = *(const float4*)(kp + 128 + j * 32 + 4);
  }
  __syncthreads();
#pragma unroll
  for (int j = 0; j < 4; j++) {
    float f0[8] = {vb[j][0].x, vb[j][0].y, vb[j][0].z, vb[j][0].w,
                   vb[j][1].x, vb[j][1].y, vb[j][1].z, vb[j][1].w};
    uint4 pk;
    unsigned* pw = (unsigned*)&pk;
#pragma unroll
    for (int i = 0; i < 4; i++)
      pw[i] = (unsigned)bf16_rne(f0[2 * i]) | ((unsigned)bf16_rne(f0[2 * i + 1]) << 16);
    *(uint4*)&Bf[sbase + (j * 4 + sk) * BPAGE + scol * 8] = pk;
  }
  __syncthreads();
#pragma unroll
  for (int ksl = 0; ksl < 4; ksl++) {
    short8 bh[4], ah[4], al[4];
#pragma unroll
    for (int nf = 0; nf < 4; nf++)
      bh[nf] = *(const short8*)(&Bf[wn * (16 * BPAGE) + (ksl * 4 + lq) * BPAGE + (nf * 16 + lrow) * 8]);
#pragma unroll
    for (int mf = 0; mf < 4; mf++) {
      size_t ab = ((size_t)((wm * 4 + mf) * 8 + 4 + ksl) * 64 + l) * 8;
      ah[mf] = *(const short8*)(ap_hi + ab);
      al[mf] = *(const short8*)(ap_lo + ab);
    }
#pragma unroll
    for (int mf = 0; mf < 4; mf++)
#pragma unroll
      for (int nf = 0; nf < 4; nf++) {
        acc[mf][nf] = __builtin_amdgcn_mfma_f32_16x16x32_bf16(al[mf], bh[nf], acc[mf][nf], 0, 0, 0);
        acc[mf][nf] = __builtin_amdgcn_mfma_f32_16x16x32_bf16(ah[mf], bh[nf], acc[mf][nf], 0, 0, 0);
      }
  }

#pragma unroll
  for (int mf = 0; mf < 4; mf++)
#pragma unroll
    for (int j = 0; j < 4; j++) {
      float m = fmaxf(fmaxf(acc[mf][0][j], acc[mf][1][j]),
                      fmaxf(acc[mf][2][j], acc[mf][3][j]));
#pragma unroll
      for (int mk = 1; mk <= 8; mk <<= 1) m = fmaxf(m, __shfl_xor(m, mk));
      if ((l & 15) == 0) {
        int row = wm * 64 + mf * 16 + lq * 4 + j;
        rowmax[(size_t)row * 4096 + cb * 2 + wn] = bf16_floor(m);
      }
    }

  float* trb = (float*)smem;
#pragma unroll
  for (int rd = 0; rd < 2; rd++) {
    __syncthreads();
#pragma unroll
    for (int hh = 0; hh < 2; hh++) {
      int mf = rd * 2 + hh;
      float* tr2 = trb + (hh * 8 + w) * 1056;
#pragma unroll
      for (int nf = 0; nf < 4; nf++)
#pragma unroll
        for (int j = 0; j < 4; j++)
          tr2[(lq * 4 + j) * 66 + nf * 16 + lrow] = acc[mf][nf][j];
    }
    __syncthreads();
#pragma unroll
    for (int hh = 0; hh < 2; hh++) {
      int mf = rd * 2 + hh;
      float* tr2 = trb + (hh * 8 + w) * 1056;
#pragma unroll
      for (int it = 0; it < 4; it++) {
        float4 vv = *(float4*)&tr2[(it * 4 + lq) * 66 + 4 * lrow];
        size_t row = (size_t)(wm * 64 + mf * 16 + it * 4 + lq);
        nt_store4(vv, &scores[row * MEM_N + slot0 + wn * 64 + 4 * lrow]);
      }
    }
  }
}

// --- variant B (LARGE ws): scores to ws via direct NT scalar stores
//     (16-lane-contiguous 64B granules), + NT coalesced keys copy ---
__global__ __launch_bounds__(512, 4) void k_gemm_f(
    const u16* __restrict__ ap_hi, const u16* __restrict__ ap_lo,
    const float* __restrict__ keys, float* __restrict__ scores,
    u16* __restrict__ rowmax, float* __restrict__ keys_out) {
  __shared__ __align__(16) unsigned char smem[67584];
  u16* Bf = (u16*)smem;
  const int t = threadIdx.x;
  const int cb = blockIdx.x;
  const int slot0 = cb * 128;
  const int w = t >> 6, l = t & 63;
  const int wm = w & 3, wn = w >> 2;
  const int lrow = l & 15, lq = l >> 4;
  const int srow = t >> 2, sk = t & 3;
  const float* kp = keys + (size_t)(slot0 + srow) * DIM + sk * 8;
  const int sbase = (srow >> 6) * (16 * BPAGE);
  const int scol = srow & 63;

  f32x4 acc[4][4];
#pragma unroll
  for (int i = 0; i < 4; ++i)
#pragma unroll
    for (int j = 0; j < 4; ++j) acc[i][j] = f32x4{0.f, 0.f, 0.f, 0.f};

  {
    float4 va[4][2];
#pragma unroll
    for (int j = 0; j < 4; j++) {
      va[j][0] = *(const float4*)(kp + j * 32);
      va[j][1] = *(const float4*)(kp + j * 32 + 4);
    }
#pragma unroll
    for (int j = 0; j < 4; j++) {
      float f0[8] = {va[j][0].x, va[j][0].y, va[j][0].z, va[j][0].w,
                     va[j][1].x, va[j][1].y, va[j][1].z, va[j][1].w};
      uint4 pk;
      unsigned* pw = (unsigned*)&pk;
#pragma unroll
      for (int i = 0; i < 4; i++)
        pw[i] = (unsigned)bf16_rne(f0[2 * i]) | ((unsigned)bf16_rne(f0[2 * i + 1]) << 16);
      *(uint4*)&Bf[sbase + (j * 4 + sk) * BPAGE + scol * 8] = pk;
    }
  }
  __syncthreads();
#pragma unroll
  for (int ksl = 0; ksl < 4; ksl++) {
    short8 bh[4], ah[4], al[4];
#pragma unroll
    for (int nf = 0; nf < 4; nf++)
      bh[nf] = *(const short8*)(&Bf[wn * (16 * BPAGE) + (ksl * 4 + lq) * BPAGE + (nf * 16 + lrow) * 8]);
#pragma unroll
    for (int mf = 0; mf < 4; mf++) {
      size_t ab = ((size_t)((wm * 4 + mf) * 8 + ksl) * 64 + l) * 8;
      ah[mf] = *(const short8*)(ap_hi + ab);
      al[mf] = *(const short8*)(ap_lo + ab);
    }
#pragma unroll
    for (int mf = 0; mf < 4; mf++)
#pragma unroll
      for (int nf = 0; nf < 4; nf++) {
        acc[mf][nf] = __builtin_amdgcn_mfma_f32_16x16x32_bf16(al[mf], bh[nf], acc[mf][nf], 0, 0, 0);
        acc[mf][nf] = __builtin_amdgcn_mfma_f32_16x16x32_bf16(ah[mf], bh[nf], acc[mf][nf], 0, 0, 0);
      }
  }
  float4 vb[4][2];
#pragma unroll
  for (int j = 0; j < 4; j++) {
    vb[j][0] = *(const float4*)(kp + 128 + j * 32);
    vb[j][1] = *(const float4*)(kp + 128 + j * 32 + 4);
  }
  // aligned coalesced keys copy for this block's 128 rows (32768 floats,
  // L2-hot re-read; NT stores). Covers flat [cb*32768 - 1, cb*32768 + 32766];
  // element N-1 patched in k_topk2.
  {
    const long long bbase = (long long)cb * 32768 - 1;
    for (int i = t; i < 8192; i += 512) {
      long long k4 = bbase + 4LL * i;
      if (k4 >= 0) {
        float s0 = keys[k4];
        float4 v = *(const float4*)(keys + k4 + 1);
        float4 o;
        o.x = s0; o.y = v.x; o.z = v.y; o.w = v.z;
        nt_store4(o, keys_out + k4);
      } else {
        keys_out[0] = keys[0]; keys_out[1] = keys[1]; keys_out[2] = keys[2];
      }
    }
  }
  __syncthreads();
#pragma unroll
  for (int j = 0; j < 4; j++) {
    float f0[8] = {vb[j][0].x, vb[j][0].y, vb[j][0].z, vb[j][0].w,
                   vb[j][1].x, vb[j][1].y, vb[j][1].z, vb[j][1].w};
    uint4 pk;
    unsigned* pw = (unsigned*)&pk;
#pragma unroll
    for (int i = 0; i < 4; i++)
      pw[i] = (unsigned)bf16_rne(f0[2 * i]) | ((unsigned)bf16_rne(f0[2 * i + 1]) << 16);
    *(uint4*)&Bf[sbase + (j * 4 + sk) * BPAGE + scol * 8] = pk;
  }
  __syncthreads();
#pragma unroll
  for (int ksl = 0; ksl < 4; ksl++) {
    short8 bh[4], ah[4], al[4];
#pragma unroll
    for (int nf = 0; nf < 4; nf++)
      bh[nf] = *(const short8*)(&Bf[wn * (16 * BPAGE) + (ksl * 4 + lq) * BPAGE + (nf * 16 + lrow) * 8]);
#pragma unroll
    for (int mf = 0; mf < 4; mf++) {
      size_t ab = ((size_t)((wm * 4 + mf) * 8 + 4 + ksl) * 64 + l) * 8;
      ah[mf] = *(const short8*)(ap_hi + ab);
      al[mf] = *(const short8*)(ap_lo + ab);
    }
#pragma unroll
    for (int mf = 0; mf < 4; mf++)
#pragma unroll
      for (int nf = 0; nf < 4; nf++) {
        acc[mf][nf] = __builtin_amdgcn_mfma_f32_16x16x32_bf16(al[mf], bh[nf], acc[mf][nf], 0, 0, 0);
        acc[mf][nf] = __builtin_amdgcn_mfma_f32_16x16x32_bf16(ah[mf], bh[nf], acc[mf][nf], 0, 0, 0);
      }
  }

#pragma unroll
  for (int mf = 0; mf < 4; mf++)
#pragma unroll
    for (int j = 0; j < 4; j++) {
      float m = fmaxf(fmaxf(acc[mf][0][j], acc[mf][1][j]),
                      fmaxf(acc[mf][2][j], acc[mf][3][j]));
#pragma unroll
      for (int mk = 1; mk <= 8; mk <<= 1) m = fmaxf(m, __shfl_xor(m, mk));
      if ((l & 15) == 0) {
        int row = wm * 64 + mf * 16 + lq * 4 + j;
        rowmax[(size_t)row * 4096 + cb * 2 + wn] = bf16_floor(m);
      }
    }

  // direct NT scalar score stores: for each (mf,nf,j), the 16 lanes of a
  // quarter-wave write 16 consecutive floats (64B granule, fully covered).
  const int colb = slot0 + wn * 64 + lrow;
#pragma unroll
  for (int mf = 0; mf < 4; mf++) {
    size_t rb = (size_t)(wm * 64 + mf * 16 + lq * 4) * MEM_N + colb;
#pragma unroll
    for (int nf = 0; nf < 4; nf++)
#pragma unroll
      for (int j = 0; j < 4; j++)
        __builtin_nontemporal_store(acc[mf][nf][j],
                                    &scores[rb + (size_t)j * MEM_N + nf * 16]);
  }
}

// ---- cutoff = exact ksel-th largest of 4096 bf16 group-maxima (per block-row) ----
__global__ __launch_bounds__(256) void k_cut(
    const u16* __restrict__ rowmax, float* __restrict__ cut_row, int ksel) {
  __shared__ int h[256];
  __shared__ int Bsh, Lsh;
  const int r = blockIdx.x, t = threadIdx.x;
  const u16* rm = rowmax + (size_t)r * 4096;
  uint4 a0 = *(const uint4*)(rm + t * 16);
  uint4 a1 = *(const uint4*)(rm + t * 16 + 8);
  u16 f[16];
  unsigned aw[8] = {a0.x, a0.y, a0.z, a0.w, a1.x, a1.y, a1.z, a1.w};
#pragma unroll
  for (int i = 0; i < 8; i++) {
    f[2 * i] = flip16((u16)(aw[i] & 0xFFFFu));
    f[2 * i + 1] = flip16((u16)(aw[i] >> 16));
  }
  h[t] = 0;
  __syncthreads();
#pragma unroll
  for (int i = 0; i < 16; i++) atomicAdd(&h[f[i] >> 8], 1);
  __syncthreads();
  for (int off = 1; off < 256; off <<= 1) {
    int v = (t + off < 256) ? h[t + off] : 0;
    __syncthreads();
    h[t] += v;
    __syncthreads();
  }
  if (h[t] >= ksel && (t == 255 || h[t + 1] < ksel)) Bsh = t;
  __syncthreads();
  const int B = Bsh;
  const int above = (B == 255) ? 0 : h[B + 1];
  __syncthreads();
  h[t] = 0;
  __syncthreads();
#pragma unroll
  for (int i = 0; i < 16; i++)
    if ((f[i] >> 8) == B) atomicAdd(&h[f[i] & 255], 1);
  __syncthreads();
  for (int off = 1; off < 256; off <<= 1) {
    int v = (t + off < 256) ? h[t + off] : 0;
    __syncthreads();
    h[t] += v;
    __syncthreads();
  }
  if (above + h[t] >= ksel && (t == 255 || above + h[t + 1] < ksel)) Lsh = t;
  __syncthreads();
  if (t == 0) {
    u16 fs = (u16)((B << 8) | Lsh);
    cut_row[r] = bf16_f32(unflip16(fs));
  }
}

// ---------------- sort helper ----------------
__device__ void bitonic_desc(u64* a, int N, int t) {
  for (int k = 2; k <= N; k <<= 1) {
    for (int j = k >> 1; j > 0; j >>= 1) {
      for (int i = t; i < N; i += 256) {
        int p = i ^ j;
        if (p > i) {
          u64 xv = a[i], yv = a[p];
          bool up = ((i & k) == 0);
          if (up ? (xv < yv) : (xv > yv)) { a[i] = yv; a[p] = xv; }
        }
      }
      __syncthreads();
    }
  }
}

// ---- sweep (SMALL): rowmax-guided sparse filter + keys copy ----
__global__ __launch_bounds__(256) void k_sweep(
    const float* __restrict__ scores, const float* __restrict__ cut_row,
    const u16* __restrict__ rowmax, const float* __restrict__ keys,
    u64* __restrict__ cand_row, int* __restrict__ row_cnt,
    float* __restrict__ keys_out) {
  __shared__ u64 lbuf[2048];
  __shared__ u16 sblk[512];
  __shared__ int lcnt, nsb, gbase;
  const int seg = blockIdx.x, r = blockIdx.y, t = threadIdx.x;
  if (t == 0) { lcnt = 0; nsb = 0; }
  __syncthreads();
  const float cutval = cut_row[r];
  const float* p = scores + (size_t)r * MEM_N + (size_t)seg * SEG_SZ;

  const u16* rm = rowmax + (size_t)r * 4096 + seg * 512;
#pragma unroll
  for (int i2 = 0; i2 < 2; i2++) {
    int i = t * 2 + i2;
    if (bf16_f32(rm[i]) >= cutval) {
      int pz = atomicAdd(&nsb, 1);
      sblk[pz] = (u16)i;
    }
  }
  __syncthreads();
  const int ns = nsb;
  for (int i0 = 0; i0 < ns; i0 += 16) {
    int ib = i0 + (t >> 4);
    if (ib < ns) {
      int b = sblk[ib];
      int off = b * 64 + (t & 15) * 4;
      float4 v = *(const float4*)(p + off);
      float vv[4] = {v.x, v.y, v.z, v.w};
      int c0 = seg * SEG_SZ + off;
#pragma unroll
      for (int e = 0; e < 4; e++) {
        if (vv[e] >= cutval) {
          u64 key = (((u64)flip32(vv[e])) << 32) | (unsigned)(~(unsigned)(c0 + e));
          int pz = atomicAdd(&lcnt, 1);
          if (pz < 2048) lbuf[pz] = key;
        }
      }
    }
  }
  __syncthreads();
  int n = lcnt < 2048 ? lcnt : 2048;
  if (t == 0) gbase = atomicAdd(&row_cnt[r], n);
  __syncthreads();
  const int gb = gbase;
  u64* crow = cand_row + (size_t)r * ROWCAP;
  for (int i = t; i < n; i += 256) {
    int gp = gb + i;
    if (gp < ROWCAP) crow[gp] = lbuf[i];
  }

  const long long b = (long long)r * MEM_N + (long long)seg * SEG_SZ - 1;
  for (int i = t; i < 8192; i += 256) {
    long long k4 = b + 4LL * i;
    if (k4 < 0) continue;
    float s = keys[k4];
    float4 v = *(const float4*)(keys + k4 + 1);
    float4 o;
    o.x = s; o.y = v.x; o.z = v.y; o.w = v.z;
    *(float4*)(keys_out + k4) = o;
  }
  if (r == 0 && seg == 0 && t == 0) {
    keys_out[0] = keys[0]; keys_out[1] = keys[1]; keys_out[2] = keys[2];
  }
}

// ---- sweep (LARGE): sparse filter + fused age/vals init ----
__global__ __launch_bounds__(256) void k_sweep_s(
    const float* __restrict__ scores, const float* __restrict__ cut_row,
    const u16* __restrict__ rowmax, u64* __restrict__ cand_row,
    int* __restrict__ row_cnt, const float* __restrict__ age,
    const int* __restrict__ values, float* __restrict__ age_out,
    float* __restrict__ vals_out) {
  __shared__ u64 lbuf[2048];
  __shared__ u16 sblk[512];
  __shared__ int lcnt, nsb, gbase;
  const int seg = blockIdx.x, r = blockIdx.y, t = threadIdx.x;
  if (t == 0) { lcnt = 0; nsb = 0; }
  // fused age/vals init: block lid covers 128 elements
  {
    int lid = r * NSEG + seg;  // 0..2047
    if (t < 32) {
      int g = lid * 128 + t * 4;
      float4 a = *(const float4*)(age + g);
      int4 vvv = *(const int4*)(values + g);
      float4 ao = {a.x + 1.0f, a.y + 1.0f, a.z + 1.0f, a.w + 1.0f};
      float4 vo = {(float)vvv.x, (float)vvv.y, (float)vvv.z, (float)vvv.w};
      *(float4*)(age_out + g) = ao;
      *(float4*)(vals_out + g) = vo;
    }
  }
  __syncthreads();
  const float cutval = cut_row[r];
  const float* p = scores + (size_t)r * MEM_N + (size_t)seg * SEG_SZ;
  const u16* rm = rowmax + (size_t)r * 4096 + seg * 512;
#pragma unroll
  for (int i2 = 0; i2 < 2; i2++) {
    int i = t * 2 + i2;
    if (bf16_f32(rm[i]) >= cutval) {
      int pz = atomicAdd(&nsb, 1);
      sblk[pz] = (u16)i;
    }
  }
  __syncthreads();
  const int ns = nsb;
  for (int i0 = 0; i0 < ns; i0 += 16) {
    int ib = i0 + (t >> 4);
    if (ib < ns) {
      int b = sblk[ib];
      int off = b * 64 + (t & 15) * 4;
      float4 v = *(const float4*)(p + off);
      float vv[4] = {v.x, v.y, v.z, v.w};
      int c0 = seg * SEG_SZ + off;
#pragma unroll
      for (int e = 0; e < 4; e++) {
        if (vv[e] >= cutval) {
          u64 key = (((u64)flip32(vv[e])) << 32) | (unsigned)(~(unsigned)(c0 + e));
          int pz = atomicAdd(&lcnt, 1);
          if (pz < 2048) lbuf[pz] = key;
        }
      }
    }
  }
  __syncthreads();
  int n = lcnt < 2048 ? lcnt : 2048;
  if (t == 0) gbase = atomicAdd(&row_cnt[r], n);
  __syncthreads();
  const int gb = gbase;
  u64* crow = cand_row + (size_t)r * ROWCAP;
  for (int i = t; i < n; i += 256) {
    int gp = gb + i;
    if (gp < ROWCAP) crow[gp] = lbuf[i];
  }
}

// ---- top-k finalize: sort + softmax + loss + yhat + reset + correct-update ----
__global__ __launch_bounds__(256) void k_topk2(
    const u64* __restrict__ cand_row, const int* __restrict__ row_cnt,
    const int* __restrict__ values, const int* __restrict__ yv,
    const float* __restrict__ keys, const float* __restrict__ q,
    float* __restrict__ out, float* __restrict__ loss_arr,
    int* __restrict__ corr, float* __restrict__ age_out,
    float* __restrict__ keys_out) {
  __shared__ u64 buf[ROWCAP];
  __shared__ float red[256];
  __shared__ float wred[4][4];
  const int r = blockIdx.x, t = threadIdx.x;
  if (r == 255 && t == 32) {
    const long long N = (long long)MEM_N * DIM;
    keys_out[N - 1] = keys[N - 1];  // last element not covered by either copy path
  }
  int cnt = row_cnt[r];
  cnt = cnt < ROWCAP ? cnt : ROWCAP;
  int S = 256;
  while (S < cnt) S <<= 1;
  const u64* src = cand_row + (size_t)r * ROWCAP;
  for (int i = t; i < S; i += 256) buf[i] = (i < cnt) ? src[i] : 0ULL;
  __syncthreads();
  bitonic_desc(buf, S, t);

  u64 mykey = buf[t];
  int midx = (int)(~(unsigned)(mykey & 0xFFFFFFFFull));
  float msc = unflip32((unsigned)(mykey >> 32));
  int yr = yv[r];
  float mask = (values[midx] == yr) ? 1.0f : 0.0f;
  float mtop = unflip32((unsigned)(buf[0] >> 32));
  int i0 = (int)(~(unsigned)(buf[0] & 0xFFFFFFFFull));
  int vi0 = values[i0];
  bool correct = (vi0 == yr);

  // wave-parallel reductions: sum(e), max(msc*mask), max(msc*(1-mask)), sum(mask)
  float e = expf(msc - mtop);  // TEMP == 1.0
  float vsum = e, vpos = msc * mask, vneg = msc * (1.0f - mask), vmsk = mask;
#pragma unroll
  for (int off = 32; off > 0; off >>= 1) {
    vsum += __shfl_xor(vsum, off);
    vpos = fmaxf(vpos, __shfl_xor(vpos, off));
    vneg = fmaxf(vneg, __shfl_xor(vneg, off));
    vmsk += __shfl_xor(vmsk, off);
  }
  const int wv = t >> 6;
  if ((t & 63) == 0) {
    wred[wv][0] = vsum; wred[wv][1] = vpos; wred[wv][2] = vneg; wred[wv][3] = vmsk;
  }
  __syncthreads();
  float denom = wred[0][0] + wred[1][0] + wred[2][0] + wred[3][0];
  float posr = fmaxf(fmaxf(wred[0][1], wred[1][1]), fmaxf(wred[2][1], wred[3][1]));
  float negr = fmaxf(fmaxf(wred[0][2], wred[1][2]), fmaxf(wred[2][2], wred[3][2]));
  float hp = (wred[0][3] + wred[1][3] + wred[2][3] + wred[3][3]) > 0.0f ? 1.0f : 0.0f;
  out[256 + r * 256 + t] = e / denom;

  if (t == 0) {
    float pos = posr * hp;
    loss_arr[r] = fmaxf(negr - pos + 0.1f, 0.0f);
    out[r] = (float)vi0;
    corr[r] = correct ? 1 : 0;
  }
  if (correct) {
    if (t == 0) age_out[i0] = 0.0f;
    float v = keys[(size_t)i0 * DIM + t] + q[r * DIM + t];
    red[t] = v * v; __syncthreads();
    for (int s = 128; s > 0; s >>= 1) { if (t < s) red[t] += red[t + s]; __syncthreads(); }
    float nrm = fmaxf(sqrtf(red[0]), 1e-12f);
    keys_out[(size_t)i0 * DIM + t] = v / nrm;
  }
}

// ---------------- age/values init (SMALL path only) ----------------
__global__ __launch_bounds__(256) void k_age(
    const float* __restrict__ age, const int* __restrict__ values,
    float* __restrict__ age_out, float* __restrict__ vals_out) {
  int i = blockIdx.x * 256 + threadIdx.x;
  age_out[i] = age[i] + 1.0f;
  vals_out[i] = (float)values[i];
}

// ---- oldest path stage 1: 64-elt group maxima of age_noisy (bf16 floored) ----
__global__ __launch_bounds__(256) void k_oldmax(
    const float* __restrict__ age_out, const float* __restrict__ un,
    u16* __restrict__ old_max) {
  const int t = threadIdx.x, bid = blockIdx.x;
  int g = bid * 1024 + t * 4;
  float4 a = *(const float4*)(age_out + g);
  float4 n4 = *(const float4*)(un + g);
  float m = a.x + (2.0f * n4.x - 1.0f) * 8.0f;
  m = fmaxf(m, a.y + (2.0f * n4.y - 1.0f) * 8.0f);
  m = fmaxf(m, a.z + (2.0f * n4.z - 1.0f) * 8.0f);
  m = fmaxf(m, a.w + (2.0f * n4.w - 1.0f) * 8.0f);
#pragma unroll
  for (int mk = 1; mk <= 8; mk <<= 1) m = fmaxf(m, __shfl_xor(m, mk));
  if ((t & 15) == 0) old_max[bid * 16 + (t >> 4)] = bf16_floor(m);
}

// ---- oldest path stage 2: filtered sweep of age_noisy ----
__global__ __launch_bounds__(256) void k_oldsweep(
    const float* __restrict__ age_out, const float* __restrict__ un,
    const float* __restrict__ old_cut, u64* __restrict__ obuf,
    int* __restrict__ ocnt) {
  const int t = threadIdx.x, bid = blockIdx.x;
  int g = bid * 1024 + t * 4;
  const float cut = *old_cut;
  float4 a = *(const float4*)(age_out + g);
  float4 n4 = *(const float4*)(un + g);
  float av[4] = {a.x, a.y, a.z, a.w};
  float nv[4] = {n4.x, n4.y, n4.z, n4.w};
#pragma unroll
  for (int e = 0; e < 4; e++) {
    float v = av[e] + (2.0f * nv[e] - 1.0f) * 8.0f;
    if (v >= cut) {
      u64 k = (((u64)flip32(v)) << 32) | (unsigned)(~(unsigned)(g + e));
      int p = atomicAdd(ocnt, 1);
      if (p < OCAP) obuf[p] = k;
    }
  }
}

// ---- oldest path stage 3: sort survivors, dest assignment, loss mean ----
__global__ __launch_bounds__(256) void k_oldB(
    const u64* __restrict__ obuf, const int* __restrict__ ocnt,
    const int* __restrict__ corr, const float* __restrict__ loss_arr,
    int* __restrict__ dest, float* __restrict__ out_loss) {
  __shared__ u64 cand[OCAP];
  __shared__ int olds[256];
  __shared__ int pre[256];
  __shared__ float red[256];
  const int t = threadIdx.x;
  int n = *ocnt;
  n = n < OCAP ? n : OCAP;
  int S = 256;
  while (S < n) S <<= 1;
  for (int i = t; i < S; i += 256) cand[i] = (i < n) ? obuf[i] : 0ULL;
  __syncthreads();
  bitonic_desc(cand, S, t);
  olds[t] = (int)(~(unsigned)(cand[t] & 0xFFFFFFFFull));
  int inc = corr[t] ? 0 : 1;
  pre[t] = inc;
  __syncthreads();
  for (int off = 1; off < 256; off <<= 1) {
    int v = (t >= off) ? pre[t - off] : 0;
    __syncthreads();
    pre[t] += v;
    __syncthreads();
  }
  int rank = pre[t] - 1;
  dest[t] = inc ? olds[rank] : -1;
  red[t] = loss_arr[t]; __syncthreads();
  for (int s = 128; s > 0; s >>= 1) { if (t < s) red[t] += red[t + s]; __syncthreads(); }
  if (t == 0) *out_loss = red[0] * (1.0f / 256.0f);
}

// ---------------- incorrect-row scatter ----------------
__global__ __launch_bounds__(256) void k_incorrect(
    const int* __restrict__ dest, const float* __restrict__ q,
    const int* __restrict__ yv, float* __restrict__ keys_out,
    float* __restrict__ vals_out, float* __restrict__ age_out) {
  const int r = blockIdx.x;
  int d = dest[r];
  if (d < 0) return;
  const int t = threadIdx.x;
  keys_out[(size_t)d * DIM + t] = q[r * DIM + t];
  if (t == 0) {
    vals_out[d] = (float)yv[r];
    age_out[d] = 0.0f;
  }
}

extern "C" void kernel_launch(void* const* d_in, const int* in_sizes, int n_in,
                              void* d_out, int out_size, void* d_ws, size_t ws_size,
                              hipStream_t stream) {
  const float* x = (const float*)d_in[0];
  const int* y = (const int*)d_in[1];
  const float* W = (const float*)d_in[2];
  const float* b = (const float*)d_in[3];
  const float* keys = (const float*)d_in[4];
  const int* values = (const int*)d_in[5];
  const float* age = (const float*)d_in[6];
  const float* un = (const float*)d_in[7];
  float* out = (float*)d_out;

  char* ws = (char*)d_ws;
  float* q = (float*)ws;                             // 256 KB
  u16* ap_hi = (u16*)(ws + 262144);                  // 128 KB
  u16* ap_lo = (u16*)(ws + 393216);                  // 128 KB
  float* loss_arr = (float*)(ws + 524288);           // 1 KB
  int* corr = (int*)(ws + 525312);                   // 1 KB
  u64* obuf = (u64*)(ws + 527360);                   // 32 KB (OCAP u64)
  int* dest = (int*)(ws + 560128);                   // 1 KB
  int* row_cnt = (int*)(ws + 561152);                // 1 KB
  float* cut_row = (float*)(ws + 562176);            // 1 KB
  u16* old_max = (u16*)(ws + 563200);                // 8 KB (4096 u16)
  float* old_cut = (float*)(ws + 571392);            // 4 B
  int* ocnt = (int*)(ws + 571648);                   // 4 B
  u64* cand_row = (u64*)(ws + 1048576);              // 4 MB (256 x ROWCAP)

  // d_out layout (floats): yhat[256] | softmax[65536] | loss[1] | keys[67108864]
  //                        | values[262144] | age[262144]
  const size_t LOSS_OFF = 65792, KEYS_OFF = 65793, VALS_OFF = 67174657,
               AGE_OFF = 67436801;
  float* keys_out = out + KEYS_OFF;
  float* vals_out = out + VALS_OFF;
  float* age_out = out + AGE_OFF;

  const size_t NEED_LARGE = 8388608ull + 268435456ull;  // rowmax_ws + scores_ws
  const bool large = (ws_size >= NEED_LARGE);

  k_query<<<dim3(256), dim3(256), 0, stream>>>(x, W, b, q, ap_hi, ap_lo, row_cnt, ocnt);
  if (large) {
    u16* rowmax = (u16*)(ws + 6291456);      // 2 MB at ws+6MB
    float* scores = (float*)(ws + 8388608);  // 256 MB at ws+8MB
    k_gemm_f<<<dim3(2048), dim3(512), 0, stream>>>(ap_hi, ap_lo, keys, scores, rowmax, keys_out);
    k_cut<<<dim3(256), dim3(256), 0, stream>>>(rowmax, cut_row, KSEL_SCORES);
    k_sweep_s<<<dim3(NSEG, 256), dim3(256), 0, stream>>>(scores, cut_row, rowmax, cand_row, row_cnt,
                                                         age, values, age_out, vals_out);
  } else {
    float* scores = out + 65792;           // 256 MB scratch over loss+keys region
    u16* rowmax = (u16*)(out + 67174656);  // 2 MB over last-key+values+age
    k_gemm<<<dim3(2048), dim3(512), 0, stream>>>(ap_hi, ap_lo, keys, scores, rowmax);
    k_cut<<<dim3(256), dim3(256), 0, stream>>>(rowmax, cut_row, KSEL_SCORES);
    k_sweep<<<dim3(NSEG, 256), dim3(256), 0, stream>>>(scores, cut_row, rowmax, keys, cand_row, row_cnt, keys_out);
    k_age<<<dim3(1024), dim3(256), 0, stream>>>(age, values, age_out, vals_out);
  }
  k_topk2<<<dim3(256), dim3(256), 0, stream>>>(cand_row, row_cnt, values, y, keys, q,
                                               out, loss_arr, corr, age_out, keys_out);
  k_oldmax<<<dim3(256), dim3(256), 0, stream>>>(age_out, un, old_max);
  k_cut<<<dim3(1), dim3(256), 0, stream>>>(old_max, old_cut, 256);
  k_oldsweep<<<dim3(256), dim3(256), 0, stream>>>(age_out, un, old_cut, obuf, ocnt);
  k_oldB<<<dim3(1), dim3(256), 0, stream>>>(obuf, ocnt, corr, loss_arr, dest, out + LOSS_OFF);
  k_incorrect<<<dim3(256), dim3(256), 0, stream>>>(dest, q, y, keys_out, vals_out, age_out);
}